// Round 5
// baseline (1223.024 us; speedup 1.0000x reference)
//
#include <hip/hip_runtime.h>
#include <math.h>

#define C_DIM 512
#define WH    16384
#define CAP   17408      // 16384 + 8*128 worst-case padding
#define SEG_ALIGN 128
#define NCHUNK 64
#define CHUNK  256
#define NMAT 16
#define NSLICE 4
#define MSZ  (C_DIM*C_DIM)
#define ALPHA_C 0.8f
#define EPS_C   1e-6f
#define NIT 10

typedef __attribute__((ext_vector_type(8))) __bf16 bfrag;
typedef __attribute__((ext_vector_type(4))) float f32x4;

__device__ inline float bf2f(ushort h){ return __uint_as_float(((unsigned)h)<<16); }
__device__ inline void split2(float v, ushort& h, ushort& l){
    unsigned u = __float_as_uint(v);
    h = (ushort)(u >> 16);
    float r = v - __uint_as_float(u & 0xffff0000u);
    l = (ushort)(__float_as_uint(r) >> 16);
}

// XCD-contiguous chunk swizzle (requires nwg % 8 == 0)
__device__ __forceinline__ int xcd_swz(int bid, int nwg){
    int c = nwg >> 3;
    return (bid & 7)*c + (bid >> 3);
}

// shared MFMA inner block: 128x128 tile, K=64 step, split-3 products
#define MFMA_TILE_BLOCK(As0, As1, Bs0, Bs1) \
do { \
    _Pragma("unroll") \
    for (int kk = 0; kk < 64; kk += 32){ \
        bfrag ah[4], al[4], bh[4], bl[4]; \
        _Pragma("unroll") \
        for (int m_ = 0; m_ < 4; ++m_){ \
            int row_ = wm*64 + m_*16 + lr; \
            int off_ = (row_*64 + kk + lk*8) ^ ((row_&7)<<3); \
            ah[m_] = *(const bfrag*)&(As0)[off_]; \
            al[m_] = *(const bfrag*)&(As1)[off_]; \
        } \
        _Pragma("unroll") \
        for (int n_ = 0; n_ < 4; ++n_){ \
            int row_ = wn*64 + n_*16 + lr; \
            int off_ = (row_*64 + kk + lk*8) ^ ((row_&7)<<3); \
            bh[n_] = *(const bfrag*)&(Bs0)[off_]; \
            bl[n_] = *(const bfrag*)&(Bs1)[off_]; \
        } \
        _Pragma("unroll") \
        for (int m_ = 0; m_ < 4; ++m_) \
            _Pragma("unroll") \
            for (int n_ = 0; n_ < 4; ++n_){ \
                acc[m_][n_] = __builtin_amdgcn_mfma_f32_16x16x32_bf16(ah[m_], bh[n_], acc[m_][n_], 0,0,0); \
                acc[m_][n_] = __builtin_amdgcn_mfma_f32_16x16x32_bf16(ah[m_], bl[n_], acc[m_][n_], 0,0,0); \
                acc[m_][n_] = __builtin_amdgcn_mfma_f32_16x16x32_bf16(al[m_], bh[n_], acc[m_][n_], 0,0,0); \
            } \
    } \
} while(0)

// core K-loop for 512-K matmul on split planes with stride C_DIM
__device__ __forceinline__ void mm_core(const ushort* __restrict__ Am,
        const ushort* __restrict__ Bm, int i0, int j0,
        ushort (&As)[2][8192], ushort (&Bs)[2][8192], f32x4 (&acc)[4][4],
        int wm, int wn, int lr, int lk){
    int t = threadIdx.x;
    for (int kb = 0; kb < 8; ++kb){
        int k0 = kb*64;
        #pragma unroll
        for (int p = 0; p < 2; ++p){
            const ushort* Ap = Am + (size_t)p*MSZ;
            const ushort* Bp = Bm + (size_t)p*MSZ;
            #pragma unroll
            for (int i = 0; i < 4; ++i){
                int slot = t + i*256;
                int row = slot >> 3, c8 = slot & 7;
                int swz = (row*64 + c8*8) ^ ((row&7)<<3);
                *(uint4*)&As[p][swz] = *(const uint4*)&Ap[(size_t)(i0+row)*C_DIM + k0 + c8*8];
                *(uint4*)&Bs[p][swz] = *(const uint4*)&Bp[(size_t)(j0+row)*C_DIM + k0 + c8*8];
            }
        }
        __syncthreads();
        MFMA_TILE_BLOCK(As[0], As[1], Bs[0], Bs[1]);
        __syncthreads();
    }
}

// ---------- label bookkeeping (deterministic counting sort) ----------

__global__ __launch_bounds__(256) void k_chunk_hist(const int* __restrict__ labels,
                                                    int* __restrict__ chunkCnt){
    __shared__ int h[8];
    int t = threadIdx.x;
    if (t < 8) h[t] = 0;
    __syncthreads();
    int l = labels[blockIdx.x*CHUNK + t];
    atomicAdd(&h[l], 1);
    __syncthreads();
    if (t < 8) chunkCnt[blockIdx.x*8 + t] = h[t];
}

__global__ void k_scan(const int* __restrict__ chunkCnt, int* __restrict__ cnt,
                       int* __restrict__ offPad, int* __restrict__ base){
    if (threadIdx.x != 0) return;
    int c[8];
    for (int k=0;k<8;k++) c[k]=0;
    for (int ch=0; ch<NCHUNK; ch++)
        for (int k=0;k<8;k++) c[k] += chunkCnt[ch*8+k];
    int off = 0;
    for (int k=0;k<8;k++){
        cnt[k] = c[k];
        offPad[k] = off;
        off += ((c[k] + SEG_ALIGN - 1)/SEG_ALIGN)*SEG_ALIGN;
    }
    offPad[8] = off;
    for (int k=0;k<8;k++){
        int run = offPad[k];
        for (int ch=0; ch<NCHUNK; ch++){
            base[ch*8+k] = run;
            run += chunkCnt[ch*8+k];
        }
    }
}

__global__ void k_place(const int* __restrict__ labels, const int* __restrict__ base,
                        int* __restrict__ perm, int* __restrict__ inv){
    int t = threadIdx.x;
    if (t >= 8) return;
    int ch = blockIdx.x;
    int pos = base[ch*8+t];
    int s = ch*CHUNK;
    for (int i=0;i<CHUNK;i++){
        if (labels[s+i] == t){
            perm[pos] = s+i;
            if (inv) inv[s+i] = pos;
            pos++;
        }
    }
}

// ---------- gather into padded segments, split to bf16 hi/lo planes ----------

__global__ __launch_bounds__(256) void k_gather(const float* __restrict__ src,
        const int* __restrict__ perm, const int* __restrict__ offPad,
        const int* __restrict__ cnt, ushort* __restrict__ dstH,
        ushort* __restrict__ dstL){
    __shared__ int so[9], sc[8];
    int t = threadIdx.x;
    if (t < 9) so[t] = offPad[t];
    if (t < 8) sc[t] = cnt[t];
    __syncthreads();
    int c = blockIdx.y;
    int i = blockIdx.x*256 + t;
    float v = 0.0f;
    if (i < so[8]){
        int k = 0;
        while (k < 7 && i >= so[k+1]) k++;
        int rel = i - so[k];
        if (rel < sc[k]) v = src[(size_t)c*WH + perm[i]];
    }
    ushort h,l; split2(v,h,l);
    dstH[(size_t)c*CAP + i] = h;
    dstL[(size_t)c*CAP + i] = l;
}

// ---------- transpose plane: [512][CAP] -> [CAP][512] ----------

__global__ __launch_bounds__(256) void k_transpose(const ushort* __restrict__ S,
                                                   ushort* __restrict__ D){
    __shared__ ushort tile[64][72];
    int p = blockIdx.z;
    const ushort* Sp = S + (size_t)p*C_DIM*CAP;
    ushort* Dp = D + (size_t)p*CAP*C_DIM;
    int cb = blockIdx.x*64;   // pixel block
    int rb = blockIdx.y*64;   // channel block
    int t = threadIdx.x;
    int tr = t >> 3, tc = t & 7;
    #pragma unroll
    for (int i=0;i<2;i++){
        int r = tr + i*32;
        uint4 v = *(const uint4*)&Sp[(size_t)(rb+r)*CAP + cb + tc*8];
        ushort* u = (ushort*)&v;
        #pragma unroll
        for (int j=0;j<8;j++) tile[tc*8+j][r] = u[j];
    }
    __syncthreads();
    #pragma unroll
    for (int i=0;i<2;i++){
        int r = tr + i*32;
        uint4 v;
        ushort* u = (ushort*)&v;
        #pragma unroll
        for (int j=0;j<8;j++) u[j] = tile[r][tc*8+j];
        *(uint4*)&Dp[(size_t)(cb+r)*C_DIM + rb + tc*8] = v;
    }
}

// ---------- per-cluster sums / means (from split planes) ----------

template<bool DIV_N>
__global__ __launch_bounds__(256) void k_segsum(const ushort* __restrict__ XH,
        const ushort* __restrict__ XL, const int* __restrict__ offPad,
        const int* __restrict__ cnt, float* __restrict__ out){
    int k = blockIdx.x;
    int c = blockIdx.y*32 + (threadIdx.x >> 3);
    int s = threadIdx.x & 7;
    int off = offPad[k], n = cnt[k];
    const ushort* rh = XH + (size_t)c*CAP + off;
    const ushort* rl = XL + (size_t)c*CAP + off;
    float acc = 0.0f;
    for (int j=s; j<n; j+=8) acc += bf2f(rh[j]) + bf2f(rl[j]);
    for (int d=1; d<8; d<<=1) acc += __shfl_xor(acc, d);
    if (s == 0) out[k*C_DIM + c] = DIV_N ? acc/(float)n : acc;
}

__global__ __launch_bounds__(256) void k_style_mean(const float* __restrict__ scores,
        const int* __restrict__ cntS, const float* __restrict__ ssum,
        float* __restrict__ total, float* __restrict__ smean){
    int t = threadIdx.x;
    __shared__ float tot[8];
    if (t < 8){
        float s = 0.0f;
        for (int j=0;j<8;j++) s += scores[t*8+j]*(float)cntS[j];
        tot[t] = s; total[t] = s;
    }
    __syncthreads();
    for (int idx=t; idx<8*C_DIM; idx+=256){
        int k = idx / C_DIM, c = idx % C_DIM;
        float s = 0.0f;
        for (int j=0;j<8;j++) s += scores[k*8+j]*ssum[j*C_DIM+c];
        smean[idx] = s / tot[k];
    }
}

// ---------- MFMA SYRK: partial S2 = X X^T, triangular tiles, split-K ----------

__global__ __launch_bounds__(256,2) void k_syrk_mfma(
        const ushort* __restrict__ Xc, const ushort* __restrict__ Xs,
        const int* __restrict__ offC, const int* __restrict__ offS,
        float* __restrict__ Pf){
    __shared__ ushort As[2][8192];
    __shared__ ushort Bs[2][8192];
    int wg = xcd_swz(blockIdx.x, NMAT*NSLICE*10);
    int mat = wg / (NSLICE*10);
    int rem = wg % (NSLICE*10);
    int slice = rem / 10, tt = rem % 10;
    int ti, tj;
    if (tt < 4){ ti=0; tj=tt; }
    else if (tt < 7){ ti=1; tj=tt-3; }
    else if (tt < 9){ ti=2; tj=tt-5; }
    else { ti=3; tj=3; }
    const ushort* X = (mat < 8) ? Xc : Xs;
    const int* offP = (mat < 8) ? offC : offS;
    int cl = mat & 7;
    int off = offP[cl], npad = offP[cl+1] - off;
    int i0 = ti*128, j0 = tj*128;
    int L = ((npad + NSLICE*64 - 1)/(NSLICE*64))*64;
    int k_lo = slice*L;
    int k_hi = min(k_lo + L, npad);
    int t = threadIdx.x;
    int lane = t & 63, wave = t >> 6;
    int wm = wave >> 1, wn = wave & 1;
    int lr = lane & 15, lk = lane >> 4;
    f32x4 zero = {0.f,0.f,0.f,0.f};
    f32x4 acc[4][4];
    #pragma unroll
    for (int m=0;m<4;m++)
        #pragma unroll
        for (int n=0;n<4;n++) acc[m][n] = zero;
    for (int k0 = k_lo; k0 < k_hi; k0 += 64){
        #pragma unroll
        for (int p=0;p<2;p++){
            const ushort* Xp = X + (size_t)p*C_DIM*CAP + off + k0;
            #pragma unroll
            for (int i=0;i<4;i++){
                int slot = t + i*256;
                int row = slot >> 3, c8 = slot & 7;
                int swz = (row*64 + c8*8) ^ ((row&7)<<3);
                *(uint4*)&As[p][swz] = *(const uint4*)&Xp[(size_t)(i0+row)*CAP + c8*8];
                *(uint4*)&Bs[p][swz] = *(const uint4*)&Xp[(size_t)(j0+row)*CAP + c8*8];
            }
        }
        __syncthreads();
        MFMA_TILE_BLOCK(As[0], As[1], Bs[0], Bs[1]);
        __syncthreads();
    }
    float* O = Pf + ((size_t)(slice*16 + mat))*MSZ;
    #pragma unroll
    for (int m=0;m<4;m++)
        #pragma unroll
        for (int n=0;n<4;n++)
            #pragma unroll
            for (int j=0;j<4;j++){
                int gr = i0 + wm*64 + m*16 + lk*4 + j;
                int gc = j0 + wn*64 + n*16 + lr;
                O[(size_t)gr*C_DIM + gc] = acc[m][n][j];
            }
}

// ---------- assemble A (content: centered cov + eps; style: weighted cov) ----------
// folds the 4-way split-K reduction (reads all 4 slices at the mirrored index)

__global__ __launch_bounds__(256) void k_assemble(const float* __restrict__ P0,
        const float* __restrict__ scores, const float* __restrict__ total,
        const float* __restrict__ cmean, const float* __restrict__ smean,
        const int* __restrict__ cntC, float* __restrict__ Af){
    const size_t S = (size_t)NMAT*MSZ;
    int mat = blockIdx.y;
    int e = blockIdx.x*256 + threadIdx.x;
    int i = e >> 9, j = e & 511;
    int es = ((i>>7) > (j>>7)) ? (j*C_DIM + i) : e;   // mirror lower tiles from upper
    float v;
    if (mat < 8){
        float n = (float)cntC[mat];
        size_t b = (size_t)mat*MSZ + es;
        float s2 = P0[b] + P0[b+S] + P0[b+2*S] + P0[b+3*S];
        v = (s2 - n*cmean[mat*C_DIM+i]*cmean[mat*C_DIM+j])/(n - 1.0f);
        if (i == j) v += EPS_C;
    } else {
        int k = mat - 8;
        float s2 = 0.0f;
        #pragma unroll
        for (int jj=0;jj<8;jj++){
            size_t b = (size_t)(8+jj)*MSZ + es;
            s2 += scores[k*8+jj]*(P0[b] + P0[b+S] + P0[b+2*S] + P0[b+3*S]);
        }
        float tot = total[k];
        v = (s2 - tot*smean[k*C_DIM+i]*smean[k*C_DIM+j])/(tot - 1.0f);
    }
    Af[(size_t)mat*MSZ + e] = v;
}

// ---------- split fp32 A -> (hi,lo) bf16 planes (unnormalized) ----------

__global__ __launch_bounds__(256) void k_splitA(const float* __restrict__ A,
        ushort* __restrict__ P){
    int mat = blockIdx.y;
    int e = blockIdx.x*256 + threadIdx.x;
    float a = A[(size_t)mat*MSZ + e];
    ushort h,l; split2(a,h,l);
    P[(size_t)mat*2*MSZ + e] = h;
    P[(size_t)mat*2*MSZ + MSZ + e] = l;
}

// ---------- A^2 row abs-sums via MFMA (no C write): rowpart[mat][tj][row] ----------

__global__ __launch_bounds__(256,2) void k_mm_rowsum(
        const ushort* __restrict__ A, float* __restrict__ rowpart){
    __shared__ ushort As[2][8192];
    __shared__ ushort Bs[2][8192];
    __shared__ float rs[128][2];
    int wg = xcd_swz(blockIdx.x, NMAT*16);
    int mat = wg >> 4, tile = wg & 15;
    int ti = tile >> 2, tj = tile & 3;
    int i0 = ti*128, j0 = tj*128;
    const ushort* Am = A + (size_t)mat*2*MSZ;
    int t = threadIdx.x;
    int lane = t & 63, wave = t >> 6;
    int wm = wave >> 1, wn = wave & 1;
    int lr = lane & 15, lk = lane >> 4;
    f32x4 zero = {0.f,0.f,0.f,0.f};
    f32x4 acc[4][4];
    #pragma unroll
    for (int m=0;m<4;m++)
        #pragma unroll
        for (int n=0;n<4;n++) acc[m][n] = zero;
    mm_core(Am, Am, i0, j0, As, Bs, acc, wm, wn, lr, lk);
    #pragma unroll
    for (int m=0;m<4;m++)
        #pragma unroll
        for (int j=0;j<4;j++){
            float s = 0.0f;
            #pragma unroll
            for (int n=0;n<4;n++) s += fabsf(acc[m][n][j]);
            #pragma unroll
            for (int d=1; d<16; d<<=1) s += __shfl_xor(s, d);
            if (lr == 0) rs[wm*64 + m*16 + lk*4 + j][wn] = s;
        }
    __syncthreads();
    if (t < 128)
        rowpart[((size_t)mat*4 + tj)*512 + i0 + t] = rs[t][0] + rs[t][1];
}

// ---------- t = sqrt(max row sum of |A^2|) >= lambda_max, per matrix ----------

__global__ __launch_bounds__(256) void k_tmax(const float* __restrict__ rowpart,
                                              float* __restrict__ tvals){
    int mat = blockIdx.x, t = threadIdx.x;
    const float* rp = rowpart + (size_t)mat*4*512;
    float mx = 0.0f;
    for (int r = t; r < 512; r += 256){
        float s = rp[r] + rp[512+r] + rp[1024+r] + rp[1536+r];
        mx = fmaxf(mx, s);
    }
    __shared__ float red[256];
    red[t] = mx; __syncthreads();
    for (int s=128; s>0; s>>=1){ if (t<s) red[t]=fmaxf(red[t],red[t+s]); __syncthreads(); }
    if (t == 0) tvals[mat] = sqrtf(red[0]);
}

// ---------- split fp32 -> (hi,lo) bf16 planes scaled by 1/t; init Z = I ----------

__global__ __launch_bounds__(256) void k_split_init(const float* __restrict__ A,
        const float* __restrict__ tvals, ushort* __restrict__ Y,
        ushort* __restrict__ Z){
    int mat = blockIdx.y;
    int e = blockIdx.x*256 + threadIdx.x;
    float inv = 1.0f / tvals[mat];
    float a = A[(size_t)mat*MSZ + e] * inv;
    ushort h,l; split2(a,h,l);
    size_t base = (size_t)mat*2*MSZ;
    Y[base + e] = h;
    Y[base + MSZ + e] = l;
    int i = e >> 9, j = e & 511;
    Z[base + e] = (i==j) ? (ushort)0x3F80 : (ushort)0;
    Z[base + MSZ + e] = 0;
}

// ---------- batched 512^3 split-bf16 MFMA matmul: C = A * B^T (operands symmetric) ----------
// EPI 0: split write; EPI 1: q(X)=1.5I-0.5X then split write; EPI 2: fp32 write

template<int EPI>
__global__ __launch_bounds__(256,2) void k_mm_ns(
        const ushort* __restrict__ A, const ushort* __restrict__ B,
        ushort* __restrict__ Co, float* __restrict__ Cf, int nmat){
    __shared__ ushort As[2][8192];
    __shared__ ushort Bs[2][8192];
    int wg = xcd_swz(blockIdx.x, nmat*16);
    int mat = wg >> 4, tile = wg & 15;
    int i0 = (tile>>2)*128, j0 = (tile&3)*128;
    const ushort* Am = A + (size_t)mat*2*MSZ;
    const ushort* Bm = B + (size_t)mat*2*MSZ;
    int t = threadIdx.x;
    int lane = t & 63, wave = t >> 6;
    int wm = wave >> 1, wn = wave & 1;
    int lr = lane & 15, lk = lane >> 4;
    f32x4 zero = {0.f,0.f,0.f,0.f};
    f32x4 acc[4][4];
    #pragma unroll
    for (int m=0;m<4;m++)
        #pragma unroll
        for (int n=0;n<4;n++) acc[m][n] = zero;
    mm_core(Am, Bm, i0, j0, As, Bs, acc, wm, wn, lr, lk);
    if (EPI == 2){
        float* Cm = Cf + (size_t)mat*MSZ;
        #pragma unroll
        for (int m=0;m<4;m++)
            #pragma unroll
            for (int n=0;n<4;n++)
                #pragma unroll
                for (int j=0;j<4;j++){
                    int gr = i0 + wm*64 + m*16 + lk*4 + j;
                    int gc = j0 + wn*64 + n*16 + lr;
                    Cm[(size_t)gr*C_DIM + gc] = acc[m][n][j];
                }
    } else {
        ushort* Ch = Co + (size_t)mat*2*MSZ;
        ushort* Cl = Ch + MSZ;
        #pragma unroll
        for (int m=0;m<4;m++)
            #pragma unroll
            for (int n=0;n<4;n++)
                #pragma unroll
                for (int j=0;j<4;j++){
                    int gr = i0 + wm*64 + m*16 + lk*4 + j;
                    int gc = j0 + wn*64 + n*16 + lr;
                    float v = acc[m][n][j];
                    if (EPI == 1) v = ((gr==gc)?1.5f:0.0f) - 0.5f*v;
                    ushort h,l; split2(v,h,l);
                    size_t idx = (size_t)gr*C_DIM + gc;
                    Ch[idx] = h;
                    Cl[idx] = l;
                }
    }
}

// ---------- merged NS stage 2: fy = Y*qP, fz = qP*Z (one dispatch, 512 blocks) ----------

__global__ __launch_bounds__(256,2) void k_mm_ns2(
        const ushort* __restrict__ Y, const ushort* __restrict__ P,
        const ushort* __restrict__ Z, ushort* __restrict__ fy,
        ushort* __restrict__ fz){
    __shared__ ushort As[2][8192];
    __shared__ ushort Bs[2][8192];
    int wg = xcd_swz(blockIdx.x, NMAT*32);
    int mat = wg >> 5;
    int r = wg & 31;
    int op = r >> 4, tile = r & 15;
    int i0 = (tile>>2)*128, j0 = (tile&3)*128;
    const ushort* Am = (op ? P : Y) + (size_t)mat*2*MSZ;
    const ushort* Bm = (op ? Z : P) + (size_t)mat*2*MSZ;
    ushort* Ch = (op ? fz : fy) + (size_t)mat*2*MSZ;
    ushort* Cl = Ch + MSZ;
    int t = threadIdx.x;
    int lane = t & 63, wave = t >> 6;
    int wm = wave >> 1, wn = wave & 1;
    int lr = lane & 15, lk = lane >> 4;
    f32x4 zero = {0.f,0.f,0.f,0.f};
    f32x4 acc[4][4];
    #pragma unroll
    for (int m=0;m<4;m++)
        #pragma unroll
        for (int n=0;n<4;n++) acc[m][n] = zero;
    mm_core(Am, Bm, i0, j0, As, Bs, acc, wm, wn, lr, lk);
    #pragma unroll
    for (int m=0;m<4;m++)
        #pragma unroll
        for (int n=0;n<4;n++)
            #pragma unroll
            for (int j=0;j<4;j++){
                int gr = i0 + wm*64 + m*16 + lk*4 + j;
                int gc = j0 + wn*64 + n*16 + lr;
                ushort h,l; split2(acc[m][n][j],h,l);
                size_t idx = (size_t)gr*C_DIM + gc;
                Ch[idx] = h;
                Cl[idx] = l;
            }
}

// ---------- build split M = ascale*T + (1-alpha)I ----------

__global__ __launch_bounds__(256) void k_buildM(const float* __restrict__ T,
        const float* __restrict__ tvals, ushort* __restrict__ Msp){
    int k = blockIdx.y;
    int e = blockIdx.x*256 + threadIdx.x;
    float scale = ALPHA_C * sqrtf(tvals[8+k]/tvals[k]);
    float v = scale * T[(size_t)k*MSZ + e];
    if ((e>>9) == (e&511)) v += (1.0f - ALPHA_C);
    ushort h,l; split2(v,h,l);
    Msp[(size_t)k*2*MSZ + e] = h;
    Msp[(size_t)k*2*MSZ + MSZ + e] = l;
}

// ---------- bias vector: vvec = alpha*smean - ascale*(T cmean) ----------

__global__ __launch_bounds__(256) void k_buildV(const float* __restrict__ T,
        const float* __restrict__ tvals, const float* __restrict__ cmean,
        const float* __restrict__ smean, float* __restrict__ vvec){
    __shared__ float cm[512];
    int k = blockIdx.x, t = threadIdx.x;
    cm[t] = cmean[k*C_DIM + t];
    cm[t+256] = cmean[k*C_DIM + t + 256];
    __syncthreads();
    float scale = ALPHA_C * sqrtf(tvals[8+k]/tvals[k]);
    int c = blockIdx.y*256 + t;
    const float* row = T + (size_t)k*MSZ + (size_t)c*C_DIM;
    float s = 0.0f;
    for (int d=0; d<C_DIM; d++) s = fmaf(row[d], cm[d], s);
    vvec[k*C_DIM + c] = ALPHA_C*smean[k*C_DIM + c] - scale*s;
}

// ---------- MFMA apply: Sg = M*Xc + v in gathered order (coalesced) ----------

__global__ __launch_bounds__(256,2) void k_apply_mfma(
        const ushort* __restrict__ Msp, const ushort* __restrict__ XT,
        const float* __restrict__ vvec, const int* __restrict__ offPad,
        float* __restrict__ Sg){
    __shared__ ushort As[2][8192];
    __shared__ ushort Bs[2][8192];
    __shared__ int so[9];
    int t = threadIdx.x;
    if (t < 9) so[t] = offPad[t];
    __syncthreads();
    int wg = xcd_swz(blockIdx.x, (CAP/128)*4);
    int j0 = (wg>>2)*128;
    int i0 = (wg&3)*128;
    if (j0 >= so[8]) return;
    int cl = 0;
    while (cl < 7 && j0 >= so[cl+1]) cl++;
    const ushort* Am = Msp + (size_t)cl*2*MSZ;
    int lane = t & 63, wave = t >> 6;
    int wm = wave >> 1, wn = wave & 1;
    int lr = lane & 15, lk = lane >> 4;
    f32x4 zero = {0.f,0.f,0.f,0.f};
    f32x4 acc[4][4];
    #pragma unroll
    for (int m=0;m<4;m++)
        #pragma unroll
        for (int n=0;n<4;n++) acc[m][n] = zero;
    for (int kb = 0; kb < 8; ++kb){
        int k0 = kb*64;
        #pragma unroll
        for (int p = 0; p < 2; ++p){
            const ushort* Ap = Am + (size_t)p*MSZ;
            const ushort* Bp = XT + (size_t)p*CAP*C_DIM;
            #pragma unroll
            for (int i = 0; i < 4; ++i){
                int slot = t + i*256;
                int row = slot >> 3, c8 = slot & 7;
                int swz = (row*64 + c8*8) ^ ((row&7)<<3);
                *(uint4*)&As[p][swz] = *(const uint4*)&Ap[(size_t)(i0+row)*C_DIM + k0 + c8*8];
                *(uint4*)&Bs[p][swz] = *(const uint4*)&Bp[(size_t)(j0+row)*C_DIM + k0 + c8*8];
            }
        }
        __syncthreads();
        MFMA_TILE_BLOCK(As[0], As[1], Bs[0], Bs[1]);
        __syncthreads();
    }
    #pragma unroll
    for (int m=0;m<4;m++)
        #pragma unroll
        for (int nn=0;nn<4;nn++)
            #pragma unroll
            for (int j=0;j<4;j++){
                int gr = i0 + wm*64 + m*16 + lk*4 + j;
                int gc = j0 + wn*64 + nn*16 + lr;
                Sg[(size_t)gr*CAP + gc] = acc[m][nn][j] + vvec[cl*C_DIM + gr];
            }
}

// ---------- scatter: out[c][p] = Sg[c][ginv[p]] (coalesced writes) ----------

__global__ __launch_bounds__(256) void k_scatter(const float* __restrict__ Sg,
        const int* __restrict__ ginv, float* __restrict__ out){
    size_t idx = (size_t)blockIdx.x*256 + threadIdx.x;
    int p = (int)(idx & (WH-1));
    int c = (int)(idx >> 14);
    out[idx] = Sg[(size_t)c*CAP + ginv[p]];
}

// ---------- host ----------

extern "C" void kernel_launch(void* const* d_in, const int* in_sizes, int n_in,
                              void* d_out, int out_size, void* d_ws, size_t ws_size,
                              hipStream_t stream) {
    (void)in_sizes; (void)n_in;
    const float* cf     = (const float*)d_in[0];
    const float* sf     = (const float*)d_in[1];
    const float* scores = (const float*)d_in[2];
    const int*   cl     = (const int*)d_in[3];
    const int*   sl     = (const int*)d_in[4];
    float* out = (float*)d_out;
    float* ws  = (float*)d_ws;

    size_t o = 0;
    ushort* XcH = (ushort*)(ws + o);                           // 2 planes packed
    float*  Sg  = ws + o;       o += (size_t)C_DIM*CAP;        // aliased: apply staging
    ushort* XcL = XcH + (size_t)C_DIM*CAP;
    ushort* XsH = (ushort*)(ws + o); o += (size_t)C_DIM*CAP;   // reused as XcT planes
    float* Af  = ws + o; o += (size_t)NMAT*MSZ;                // fp32 A; NS slot 4
    float* NS0 = ws + o; o += (size_t)4*NMAT*MSZ;              // NS slots 0..3 / syrk partials
    float* cmean = ws + o; o += 8*C_DIM;
    float* ssum  = ws + o; o += 8*C_DIM;
    float* smean = ws + o; o += 8*C_DIM;
    float* vvec  = ws + o; o += 8*C_DIM;
    float* tvals = ws + o; o += 16;
    float* rowpart = ws + o; o += (size_t)NMAT*4*512;
    float* total = ws + o; o += 8;
    int* ip = (int*)(ws + o);
    int* permC    = ip; ip += CAP;
    int* permCinv = ip; ip += CAP;
    int* permS    = ip; ip += CAP;
    int* cntC  = ip; ip += 8;
    int* cntS  = ip; ip += 8;
    int* offC  = ip; ip += 9;
    int* offS  = ip; ip += 9;
    int* chC   = ip; ip += NCHUNK*8;
    int* chS   = ip; ip += NCHUNK*8;
    int* baseC = ip; ip += NCHUNK*8;
    int* baseS = ip; ip += NCHUNK*8;
    size_t need_bytes = (size_t)((char*)ip - (char*)d_ws);
    if (ws_size < need_bytes){
        hipMemcpyAsync(d_out, (const void*)cf, (size_t)out_size*sizeof(float),
                       hipMemcpyDeviceToDevice, stream);
        return;
    }
    float* Pf = NS0;                                   // SYRK partials (4 slices)
    // NS rotation slots (each NMAT*MSZ floats-worth):
    ushort* s0 = (ushort*)(NS0 + 0*(size_t)NMAT*MSZ);
    ushort* s1 = (ushort*)(NS0 + 1*(size_t)NMAT*MSZ);
    ushort* s2 = (ushort*)(NS0 + 2*(size_t)NMAT*MSZ);
    ushort* s3 = (ushort*)(NS0 + 3*(size_t)NMAT*MSZ);
    ushort* s4 = (ushort*)Af;

    k_chunk_hist<<<NCHUNK,256,0,stream>>>(cl, chC);
    k_chunk_hist<<<NCHUNK,256,0,stream>>>(sl, chS);
    k_scan<<<1,64,0,stream>>>(chC, cntC, offC, baseC);
    k_scan<<<1,64,0,stream>>>(chS, cntS, offS, baseS);
    k_place<<<NCHUNK,64,0,stream>>>(cl, baseC, permC, permCinv);
    k_place<<<NCHUNK,64,0,stream>>>(sl, baseS, permS, nullptr);

    dim3 gg(CAP/256, C_DIM);
    k_gather<<<gg,256,0,stream>>>(cf, permC, offC, cntC, XcH, XcL);
    k_gather<<<gg,256,0,stream>>>(sf, permS, offS, cntS, XsH, XsH + (size_t)C_DIM*CAP);

    k_segsum<true><<<dim3(8,16),256,0,stream>>>(XcH, XcL, offC, cntC, cmean);
    k_segsum<false><<<dim3(8,16),256,0,stream>>>(XsH, XsH + (size_t)C_DIM*CAP, offS, cntS, ssum);
    k_style_mean<<<1,256,0,stream>>>(scores, cntS, ssum, total, smean);

    // raw S2 for all 16 (cluster, src) pairs, triangular tiles, split-K=4
    k_syrk_mfma<<<NMAT*NSLICE*10,256,0,stream>>>(XcH, XsH, offC, offS, Pf);

    // transpose Xc planes into Xs region (Xs fully consumed above)
    k_transpose<<<dim3(CAP/64, C_DIM/64, 2),256,0,stream>>>(XcH, XsH);
    ushort* XT = XsH;

    // assemble A (folds split-K reduction)
    k_assemble<<<dim3(MSZ/256,16),256,0,stream>>>(Pf, scores, total, cmean, smean, cntC, Af);

    // t = sqrt(||A^2||_1): split A -> planes, A^2 row-sums via MFMA (no C write), max
    ushort* bA = s0;
    k_splitA<<<dim3(MSZ/256,NMAT),256,0,stream>>>(Af, bA);
    k_mm_rowsum<<<NMAT*16,256,0,stream>>>(bA, rowpart);
    k_tmax<<<NMAT,256,0,stream>>>(rowpart, tvals);

    ushort* bY = s0;  ushort* bZ = s1;  ushort* bP = s2;
    ushort* fy = s3;  ushort* fz = s4;
    k_split_init<<<dim3(MSZ/256,NMAT),256,0,stream>>>(Af, tvals, bY, bZ);

    for (int it=0; it<NIT; ++it){
        k_mm_ns<1><<<NMAT*16,256,0,stream>>>(bZ, bY, bP, nullptr, NMAT); // P = q(Z*Y)
        k_mm_ns2<<<NMAT*32,256,0,stream>>>(bY, bP, bZ, fy, fz);          // fy=Y*P, fz=P*Z
        ushort* t1;
        t1 = bY; bY = fy; fy = t1;
        t1 = bZ; bZ = fz; fz = t1;
    }
    // T[k] = Y_style[8+k] * Z_content[k], fp32 into free slot fy
    float* Tf = (float*)fy;
    k_mm_ns<2><<<8*16,256,0,stream>>>(bY + (size_t)8*2*MSZ, bZ, nullptr, Tf, 8);

    ushort* Msp = fz;  // other free slot
    k_buildM<<<dim3(MSZ/256,8),256,0,stream>>>(Tf, tvals, Msp);
    k_buildV<<<dim3(8,2),256,0,stream>>>(Tf, tvals, cmean, smean, vvec);

    k_apply_mfma<<<(CAP/128)*4,256,0,stream>>>(Msp, XT, vvec, offC, Sg);
    k_scatter<<<(C_DIM*WH)/256,256,0,stream>>>(Sg, permCinv, out);
}

// Round 6
// 886.333 us; speedup vs baseline: 1.3799x; 1.3799x over previous
//
#include <hip/hip_runtime.h>
#include <math.h>

#define C_DIM 512
#define WH    16384
#define CAP   17408      // 16384 + 8*128 worst-case padding
#define SEG_ALIGN 128
#define NCHUNK 64
#define CHUNK  256
#define NMAT 16
#define NSLICE 4
#define MSZ  (C_DIM*C_DIM)
#define ALPHA_C 0.8f
#define EPS_C   1e-6f
#define NIT 10

typedef __attribute__((ext_vector_type(8))) __bf16 bfrag;
typedef __attribute__((ext_vector_type(4))) float f32x4;

__device__ inline float bf2f(ushort h){ return __uint_as_float(((unsigned)h)<<16); }
__device__ inline void split2(float v, ushort& h, ushort& l){
    unsigned u = __float_as_uint(v);
    h = (ushort)(u >> 16);
    float r = v - __uint_as_float(u & 0xffff0000u);
    l = (ushort)(__float_as_uint(r) >> 16);
}

// XCD-contiguous chunk swizzle (requires nwg % 8 == 0)
__device__ __forceinline__ int xcd_swz(int bid, int nwg){
    int c = nwg >> 3;
    return (bid & 7)*c + (bid >> 3);
}

// async 16B global -> LDS (linear dest, per-lane source)
__device__ __forceinline__ void gload16(const void* g, void* l){
    __builtin_amdgcn_global_load_lds(
        (const __attribute__((address_space(1))) unsigned int*)g,
        (__attribute__((address_space(3))) unsigned int*)l, 16, 0, 0);
}

// stage one 128x64 bf16 panel: LDS linear, source pre-swizzled (rule 21)
__device__ __forceinline__ void stage_panel(const ushort* __restrict__ src,
        int stride, int i0, int k0, ushort* lds){
    int t = threadIdx.x;
    #pragma unroll
    for (int i = 0; i < 4; ++i){
        int slot = t + i*256;
        int row = slot >> 3, c8 = slot & 7;
        const ushort* g = src + (size_t)(i0+row)*stride + k0 + ((c8 ^ (row&7))<<3);
        gload16((const void*)g, (void*)&lds[(size_t)(i*256 + (t & 192))*8]);
    }
}

// shared MFMA inner block: 128x128 tile, K=64 step, split-3 products
#define MFMA_TILE_BLOCK(As0, As1, Bs0, Bs1) \
do { \
    _Pragma("unroll") \
    for (int kk = 0; kk < 64; kk += 32){ \
        bfrag ah[4], al[4], bh[4], bl[4]; \
        _Pragma("unroll") \
        for (int m_ = 0; m_ < 4; ++m_){ \
            int row_ = wm*64 + m_*16 + lr; \
            int off_ = (row_*64 + kk + lk*8) ^ ((row_&7)<<3); \
            ah[m_] = *(const bfrag*)&(As0)[off_]; \
            al[m_] = *(const bfrag*)&(As1)[off_]; \
        } \
        _Pragma("unroll") \
        for (int n_ = 0; n_ < 4; ++n_){ \
            int row_ = wn*64 + n_*16 + lr; \
            int off_ = (row_*64 + kk + lk*8) ^ ((row_&7)<<3); \
            bh[n_] = *(const bfrag*)&(Bs0)[off_]; \
            bl[n_] = *(const bfrag*)&(Bs1)[off_]; \
        } \
        _Pragma("unroll") \
        for (int m_ = 0; m_ < 4; ++m_) \
            _Pragma("unroll") \
            for (int n_ = 0; n_ < 4; ++n_){ \
                acc[m_][n_] = __builtin_amdgcn_mfma_f32_16x16x32_bf16(ah[m_], bh[n_], acc[m_][n_], 0,0,0); \
                acc[m_][n_] = __builtin_amdgcn_mfma_f32_16x16x32_bf16(ah[m_], bl[n_], acc[m_][n_], 0,0,0); \
                acc[m_][n_] = __builtin_amdgcn_mfma_f32_16x16x32_bf16(al[m_], bh[n_], acc[m_][n_], 0,0,0); \
            } \
    } \
} while(0)

// unified K-loop: C(128x128) += A[i0.., kLo..kHi] * B[j0.., kLo..kHi]^T on split planes
__device__ __forceinline__ void mm_core(const ushort* __restrict__ Am, size_t aPl, int aStr,
        const ushort* __restrict__ Bm, size_t bPl, int bStr,
        int i0, int j0, int kLo, int kHi,
        ushort (&As)[2][8192], ushort (&Bs)[2][8192], f32x4 (&acc)[4][4],
        int wm, int wn, int lr, int lk){
    for (int k0 = kLo; k0 < kHi; k0 += 64){
        stage_panel(Am,       aStr, i0, k0, As[0]);
        stage_panel(Am + aPl, aStr, i0, k0, As[1]);
        stage_panel(Bm,       bStr, j0, k0, Bs[0]);
        stage_panel(Bm + bPl, bStr, j0, k0, Bs[1]);
        __syncthreads();
        MFMA_TILE_BLOCK(As[0], As[1], Bs[0], Bs[1]);
        __syncthreads();
    }
}

// ---------- label bookkeeping (deterministic counting sort) ----------

__global__ __launch_bounds__(256) void k_chunk_hist(const int* __restrict__ labels,
                                                    int* __restrict__ chunkCnt){
    __shared__ int h[8];
    int t = threadIdx.x;
    if (t < 8) h[t] = 0;
    __syncthreads();
    int l = labels[blockIdx.x*CHUNK + t];
    atomicAdd(&h[l], 1);
    __syncthreads();
    if (t < 8) chunkCnt[blockIdx.x*8 + t] = h[t];
}

__global__ void k_scan(const int* __restrict__ chunkCnt, int* __restrict__ cnt,
                       int* __restrict__ offPad, int* __restrict__ base){
    if (threadIdx.x != 0) return;
    int c[8];
    for (int k=0;k<8;k++) c[k]=0;
    for (int ch=0; ch<NCHUNK; ch++)
        for (int k=0;k<8;k++) c[k] += chunkCnt[ch*8+k];
    int off = 0;
    for (int k=0;k<8;k++){
        cnt[k] = c[k];
        offPad[k] = off;
        off += ((c[k] + SEG_ALIGN - 1)/SEG_ALIGN)*SEG_ALIGN;
    }
    offPad[8] = off;
    for (int k=0;k<8;k++){
        int run = offPad[k];
        for (int ch=0; ch<NCHUNK; ch++){
            base[ch*8+k] = run;
            run += chunkCnt[ch*8+k];
        }
    }
}

__global__ void k_place(const int* __restrict__ labels, const int* __restrict__ base,
                        int* __restrict__ perm, int* __restrict__ inv){
    int t = threadIdx.x;
    if (t >= 8) return;
    int ch = blockIdx.x;
    int pos = base[ch*8+t];
    int s = ch*CHUNK;
    for (int i=0;i<CHUNK;i++){
        if (labels[s+i] == t){
            perm[pos] = s+i;
            if (inv) inv[s+i] = pos;
            pos++;
        }
    }
}

// ---------- gather into padded segments, split to bf16 hi/lo planes ----------

__global__ __launch_bounds__(256) void k_gather(const float* __restrict__ src,
        const int* __restrict__ perm, const int* __restrict__ offPad,
        const int* __restrict__ cnt, ushort* __restrict__ dstH,
        ushort* __restrict__ dstL){
    __shared__ int so[9], sc[8];
    int t = threadIdx.x;
    if (t < 9) so[t] = offPad[t];
    if (t < 8) sc[t] = cnt[t];
    __syncthreads();
    int c = blockIdx.y;
    int i = blockIdx.x*256 + t;
    float v = 0.0f;
    if (i < so[8]){
        int k = 0;
        while (k < 7 && i >= so[k+1]) k++;
        int rel = i - so[k];
        if (rel < sc[k]) v = src[(size_t)c*WH + perm[i]];
    }
    ushort h,l; split2(v,h,l);
    dstH[(size_t)c*CAP + i] = h;
    dstL[(size_t)c*CAP + i] = l;
}

// ---------- transpose plane: [512][CAP] -> [CAP][512] ----------

__global__ __launch_bounds__(256) void k_transpose(const ushort* __restrict__ S,
                                                   ushort* __restrict__ D){
    __shared__ ushort tile[64][72];
    int p = blockIdx.z;
    const ushort* Sp = S + (size_t)p*C_DIM*CAP;
    ushort* Dp = D + (size_t)p*CAP*C_DIM;
    int cb = blockIdx.x*64;   // pixel block
    int rb = blockIdx.y*64;   // channel block
    int t = threadIdx.x;
    int tr = t >> 3, tc = t & 7;
    #pragma unroll
    for (int i=0;i<2;i++){
        int r = tr + i*32;
        uint4 v = *(const uint4*)&Sp[(size_t)(rb+r)*CAP + cb + tc*8];
        ushort* u = (ushort*)&v;
        #pragma unroll
        for (int j=0;j<8;j++) tile[tc*8+j][r] = u[j];
    }
    __syncthreads();
    #pragma unroll
    for (int i=0;i<2;i++){
        int r = tr + i*32;
        uint4 v;
        ushort* u = (ushort*)&v;
        #pragma unroll
        for (int j=0;j<8;j++) u[j] = tile[r][tc*8+j];
        *(uint4*)&Dp[(size_t)(cb+r)*C_DIM + rb + tc*8] = v;
    }
}

// ---------- per-cluster sums / means (from split planes) ----------

template<bool DIV_N>
__global__ __launch_bounds__(256) void k_segsum(const ushort* __restrict__ XH,
        const ushort* __restrict__ XL, const int* __restrict__ offPad,
        const int* __restrict__ cnt, float* __restrict__ out){
    int k = blockIdx.x;
    int c = blockIdx.y*32 + (threadIdx.x >> 3);
    int s = threadIdx.x & 7;
    int off = offPad[k], n = cnt[k];
    const ushort* rh = XH + (size_t)c*CAP + off;
    const ushort* rl = XL + (size_t)c*CAP + off;
    float acc = 0.0f;
    for (int j=s; j<n; j+=8) acc += bf2f(rh[j]) + bf2f(rl[j]);
    for (int d=1; d<8; d<<=1) acc += __shfl_xor(acc, d);
    if (s == 0) out[k*C_DIM + c] = DIV_N ? acc/(float)n : acc;
}

__global__ __launch_bounds__(256) void k_style_mean(const float* __restrict__ scores,
        const int* __restrict__ cntS, const float* __restrict__ ssum,
        float* __restrict__ total, float* __restrict__ smean){
    int t = threadIdx.x;
    __shared__ float tot[8];
    if (t < 8){
        float s = 0.0f;
        for (int j=0;j<8;j++) s += scores[t*8+j]*(float)cntS[j];
        tot[t] = s; total[t] = s;
    }
    __syncthreads();
    for (int idx=t; idx<8*C_DIM; idx+=256){
        int k = idx / C_DIM, c = idx % C_DIM;
        float s = 0.0f;
        for (int j=0;j<8;j++) s += scores[k*8+j]*ssum[j*C_DIM+c];
        smean[idx] = s / tot[k];
    }
}

// ---------- MFMA SYRK: partial S2 = X X^T, triangular tiles, split-K ----------

__global__ __launch_bounds__(256,2) void k_syrk_mfma(
        const ushort* __restrict__ Xc, const ushort* __restrict__ Xs,
        const int* __restrict__ offC, const int* __restrict__ offS,
        float* __restrict__ Pf){
    __shared__ ushort As[2][8192];
    __shared__ ushort Bs[2][8192];
    int wg = xcd_swz(blockIdx.x, NMAT*NSLICE*10);
    int mat = wg / (NSLICE*10);
    int rem = wg % (NSLICE*10);
    int slice = rem / 10, tt = rem % 10;
    int ti, tj;
    if (tt < 4){ ti=0; tj=tt; }
    else if (tt < 7){ ti=1; tj=tt-3; }
    else if (tt < 9){ ti=2; tj=tt-5; }
    else { ti=3; tj=3; }
    const ushort* X = (mat < 8) ? Xc : Xs;
    const int* offP = (mat < 8) ? offC : offS;
    int cl = mat & 7;
    int off = offP[cl], npad = offP[cl+1] - off;
    int i0 = ti*128, j0 = tj*128;
    int L = ((npad + NSLICE*64 - 1)/(NSLICE*64))*64;
    int k_lo = slice*L;
    int k_hi = min(k_lo + L, npad);
    int t = threadIdx.x;
    int lane = t & 63, wave = t >> 6;
    int wm = wave >> 1, wn = wave & 1;
    int lr = lane & 15, lk = lane >> 4;
    f32x4 zero = {0.f,0.f,0.f,0.f};
    f32x4 acc[4][4];
    #pragma unroll
    for (int m=0;m<4;m++)
        #pragma unroll
        for (int n=0;n<4;n++) acc[m][n] = zero;
    mm_core(X + off, (size_t)C_DIM*CAP, CAP,
            X + off, (size_t)C_DIM*CAP, CAP,
            i0, j0, k_lo, k_hi, As, Bs, acc, wm, wn, lr, lk);
    float* O = Pf + ((size_t)(slice*16 + mat))*MSZ;
    #pragma unroll
    for (int m=0;m<4;m++)
        #pragma unroll
        for (int n=0;n<4;n++)
            #pragma unroll
            for (int j=0;j<4;j++){
                int gr = i0 + wm*64 + m*16 + lk*4 + j;
                int gc = j0 + wn*64 + n*16 + lr;
                O[(size_t)gr*C_DIM + gc] = acc[m][n][j];
            }
}

// ---------- assemble A: tile-based, coalesced reads, LDS-transpose mirror ----------
// writes split bf16 planes bA directly (both triangles)

__global__ __launch_bounds__(256) void k_assemble(const float* __restrict__ P0,
        const float* __restrict__ scores, const float* __restrict__ total,
        const float* __restrict__ cmean, const float* __restrict__ smean,
        const int* __restrict__ cntC, ushort* __restrict__ bA){
    const size_t S = (size_t)NMAT*MSZ;
    __shared__ ushort tH[64][136];
    __shared__ ushort tL[64][136];
    int mat = blockIdx.y;
    int tt = blockIdx.x;
    int ti, tj;
    if (tt < 4){ ti=0; tj=tt; }
    else if (tt < 7){ ti=1; tj=tt-3; }
    else if (tt < 9){ ti=2; tj=tt-5; }
    else { ti=3; tj=3; }
    int i0 = ti*128, j0 = tj*128;
    int t = threadIdx.x;
    ushort* bm = bA + (size_t)mat*2*MSZ;
    int k = mat - 8;
    float nOrTot = (mat < 8) ? (float)cntC[mat] : total[k];
    float inv_nm1 = 1.0f/(nOrTot - 1.0f);
    const float* mrow = (mat < 8) ? (cmean + mat*C_DIM) : (smean + k*C_DIM);
    for (int h = 0; h < 2; ++h){
        #pragma unroll
        for (int rep = 0; rep < 4; ++rep){
            int lin = rep*2048 + t*8;
            int r = lin >> 7;            // 0..63
            int c = lin & 127;           // multiple of 8
            int gr = i0 + h*64 + r;
            int gc = j0 + c;
            size_t e = (size_t)gr*C_DIM + gc;
            float s2[8];
            if (mat < 8){
                size_t b = (size_t)mat*MSZ + e;
                #pragma unroll
                for (int x=0;x<8;x++)
                    s2[x] = P0[b+x] + P0[b+S+x] + P0[b+2*S+x] + P0[b+3*S+x];
            } else {
                #pragma unroll
                for (int x=0;x<8;x++) s2[x] = 0.0f;
                #pragma unroll
                for (int jj=0;jj<8;jj++){
                    float sc = scores[k*8+jj];
                    size_t b = (size_t)(8+jj)*MSZ + e;
                    #pragma unroll
                    for (int x=0;x<8;x++)
                        s2[x] += sc*(P0[b+x] + P0[b+S+x] + P0[b+2*S+x] + P0[b+3*S+x]);
                }
            }
            float mi = mrow[gr];
            #pragma unroll
            for (int x=0;x<8;x++){
                float v = (s2[x] - nOrTot*mi*mrow[gc+x])*inv_nm1;
                if (mat < 8 && gr == gc+x) v += EPS_C;
                ushort hh,ll; split2(v,hh,ll);
                bm[e+x] = hh; bm[MSZ+e+x] = ll;
                tH[r][c+x] = hh; tL[r][c+x] = ll;
            }
        }
        if (ti != tj){
            __syncthreads();
            // mirror: bm[j0+rr][i0+h*64+cc] = tile[cc][rr]
            #pragma unroll
            for (int rep = 0; rep < 4; ++rep){
                int lin = rep*2048 + t*8;
                int rr = lin >> 6;       // 0..127
                int cc0 = lin & 63;      // multiple of 8
                size_t eo = (size_t)(j0+rr)*C_DIM + i0 + h*64 + cc0;
                #pragma unroll
                for (int x=0;x<8;x++){
                    bm[eo+x]     = tH[cc0+x][rr];
                    bm[MSZ+eo+x] = tL[cc0+x][rr];
                }
            }
            __syncthreads();
        }
    }
}

// ---------- A^2 row abs-sums via MFMA (no C write): rowpart[mat][tj][row] ----------

__global__ __launch_bounds__(256,2) void k_mm_rowsum(
        const ushort* __restrict__ A, float* __restrict__ rowpart){
    __shared__ ushort As[2][8192];
    __shared__ ushort Bs[2][8192];
    __shared__ float rs[128][2];
    int wg = xcd_swz(blockIdx.x, NMAT*16);
    int mat = wg >> 4, tile = wg & 15;
    int ti = tile >> 2, tj = tile & 3;
    int i0 = ti*128, j0 = tj*128;
    const ushort* Am = A + (size_t)mat*2*MSZ;
    int t = threadIdx.x;
    int lane = t & 63, wave = t >> 6;
    int wm = wave >> 1, wn = wave & 1;
    int lr = lane & 15, lk = lane >> 4;
    f32x4 zero = {0.f,0.f,0.f,0.f};
    f32x4 acc[4][4];
    #pragma unroll
    for (int m=0;m<4;m++)
        #pragma unroll
        for (int n=0;n<4;n++) acc[m][n] = zero;
    mm_core(Am, MSZ, C_DIM, Am, MSZ, C_DIM, i0, j0, 0, C_DIM,
            As, Bs, acc, wm, wn, lr, lk);
    #pragma unroll
    for (int m=0;m<4;m++)
        #pragma unroll
        for (int j=0;j<4;j++){
            float s = 0.0f;
            #pragma unroll
            for (int n=0;n<4;n++) s += fabsf(acc[m][n][j]);
            #pragma unroll
            for (int d=1; d<16; d<<=1) s += __shfl_xor(s, d);
            if (lr == 0) rs[wm*64 + m*16 + lk*4 + j][wn] = s;
        }
    __syncthreads();
    if (t < 128)
        rowpart[((size_t)mat*4 + tj)*512 + i0 + t] = rs[t][0] + rs[t][1];
}

// ---------- t = sqrt(max row sum of |A^2|) >= lambda_max, per matrix ----------

__global__ __launch_bounds__(256) void k_tmax(const float* __restrict__ rowpart,
                                              float* __restrict__ tvals){
    int mat = blockIdx.x, t = threadIdx.x;
    const float* rp = rowpart + (size_t)mat*4*512;
    float mx = 0.0f;
    for (int r = t; r < 512; r += 256){
        float s = rp[r] + rp[512+r] + rp[1024+r] + rp[1536+r];
        mx = fmaxf(mx, s);
    }
    __shared__ float red[256];
    red[t] = mx; __syncthreads();
    for (int s=128; s>0; s>>=1){ if (t<s) red[t]=fmaxf(red[t],red[t+s]); __syncthreads(); }
    if (t == 0) tvals[mat] = sqrtf(red[0]);
}

// ---------- Y = A/t (from planes), Z = I ----------

__global__ __launch_bounds__(256) void k_split_init(const ushort* __restrict__ bA,
        const float* __restrict__ tvals, ushort* __restrict__ Y,
        ushort* __restrict__ Z){
    int mat = blockIdx.y;
    int e = blockIdx.x*256 + threadIdx.x;
    size_t base = (size_t)mat*2*MSZ;
    float inv = 1.0f / tvals[mat];
    float a = (bf2f(bA[base+e]) + bf2f(bA[base+MSZ+e])) * inv;
    ushort h,l; split2(a,h,l);
    Y[base + e] = h;
    Y[base + MSZ + e] = l;
    int i = e >> 9, j = e & 511;
    Z[base + e] = (i==j) ? (ushort)0x3F80 : (ushort)0;
    Z[base + MSZ + e] = 0;
}

// ---------- batched 512^3 split-bf16 MFMA matmul: C = A * B^T (operands symmetric) ----------
// EPI 0: split write; EPI 1: q(X)=1.5I-0.5X then split write; EPI 2: fp32 write

template<int EPI>
__global__ __launch_bounds__(256,2) void k_mm_ns(
        const ushort* __restrict__ A, const ushort* __restrict__ B,
        ushort* __restrict__ Co, float* __restrict__ Cf, int nmat){
    __shared__ ushort As[2][8192];
    __shared__ ushort Bs[2][8192];
    int wg = xcd_swz(blockIdx.x, nmat*16);
    int mat = wg >> 4, tile = wg & 15;
    int i0 = (tile>>2)*128, j0 = (tile&3)*128;
    const ushort* Am = A + (size_t)mat*2*MSZ;
    const ushort* Bm = B + (size_t)mat*2*MSZ;
    int t = threadIdx.x;
    int lane = t & 63, wave = t >> 6;
    int wm = wave >> 1, wn = wave & 1;
    int lr = lane & 15, lk = lane >> 4;
    f32x4 zero = {0.f,0.f,0.f,0.f};
    f32x4 acc[4][4];
    #pragma unroll
    for (int m=0;m<4;m++)
        #pragma unroll
        for (int n=0;n<4;n++) acc[m][n] = zero;
    mm_core(Am, MSZ, C_DIM, Bm, MSZ, C_DIM, i0, j0, 0, C_DIM,
            As, Bs, acc, wm, wn, lr, lk);
    if (EPI == 2){
        float* Cm = Cf + (size_t)mat*MSZ;
        #pragma unroll
        for (int m=0;m<4;m++)
            #pragma unroll
            for (int n=0;n<4;n++)
                #pragma unroll
                for (int j=0;j<4;j++){
                    int gr = i0 + wm*64 + m*16 + lk*4 + j;
                    int gc = j0 + wn*64 + n*16 + lr;
                    Cm[(size_t)gr*C_DIM + gc] = acc[m][n][j];
                }
    } else {
        ushort* Ch = Co + (size_t)mat*2*MSZ;
        ushort* Cl = Ch + MSZ;
        #pragma unroll
        for (int m=0;m<4;m++)
            #pragma unroll
            for (int n=0;n<4;n++)
                #pragma unroll
                for (int j=0;j<4;j++){
                    int gr = i0 + wm*64 + m*16 + lk*4 + j;
                    int gc = j0 + wn*64 + n*16 + lr;
                    float v = acc[m][n][j];
                    if (EPI == 1) v = ((gr==gc)?1.5f:0.0f) - 0.5f*v;
                    ushort h,l; split2(v,h,l);
                    size_t idx = (size_t)gr*C_DIM + gc;
                    Ch[idx] = h;
                    Cl[idx] = l;
                }
    }
}

// ---------- merged NS stage 2: fy = Y*qP, fz = qP*Z (one dispatch, 512 blocks) ----------

__global__ __launch_bounds__(256,2) void k_mm_ns2(
        const ushort* __restrict__ Y, const ushort* __restrict__ P,
        const ushort* __restrict__ Z, ushort* __restrict__ fy,
        ushort* __restrict__ fz){
    __shared__ ushort As[2][8192];
    __shared__ ushort Bs[2][8192];
    int wg = xcd_swz(blockIdx.x, NMAT*32);
    int mat = wg >> 5;
    int r = wg & 31;
    int op = r >> 4, tile = r & 15;
    int i0 = (tile>>2)*128, j0 = (tile&3)*128;
    const ushort* Am = (op ? P : Y) + (size_t)mat*2*MSZ;
    const ushort* Bm = (op ? Z : P) + (size_t)mat*2*MSZ;
    ushort* Ch = (op ? fz : fy) + (size_t)mat*2*MSZ;
    ushort* Cl = Ch + MSZ;
    int t = threadIdx.x;
    int lane = t & 63, wave = t >> 6;
    int wm = wave >> 1, wn = wave & 1;
    int lr = lane & 15, lk = lane >> 4;
    f32x4 zero = {0.f,0.f,0.f,0.f};
    f32x4 acc[4][4];
    #pragma unroll
    for (int m=0;m<4;m++)
        #pragma unroll
        for (int n=0;n<4;n++) acc[m][n] = zero;
    mm_core(Am, MSZ, C_DIM, Bm, MSZ, C_DIM, i0, j0, 0, C_DIM,
            As, Bs, acc, wm, wn, lr, lk);
    #pragma unroll
    for (int m=0;m<4;m++)
        #pragma unroll
        for (int n=0;n<4;n++)
            #pragma unroll
            for (int j=0;j<4;j++){
                int gr = i0 + wm*64 + m*16 + lk*4 + j;
                int gc = j0 + wn*64 + n*16 + lr;
                ushort h,l; split2(acc[m][n][j],h,l);
                size_t idx = (size_t)gr*C_DIM + gc;
                Ch[idx] = h;
                Cl[idx] = l;
            }
}

// ---------- build split M = ascale*T + (1-alpha)I ----------

__global__ __launch_bounds__(256) void k_buildM(const float* __restrict__ T,
        const float* __restrict__ tvals, ushort* __restrict__ Msp){
    int k = blockIdx.y;
    int e = blockIdx.x*256 + threadIdx.x;
    float scale = ALPHA_C * sqrtf(tvals[8+k]/tvals[k]);
    float v = scale * T[(size_t)k*MSZ + e];
    if ((e>>9) == (e&511)) v += (1.0f - ALPHA_C);
    ushort h,l; split2(v,h,l);
    Msp[(size_t)k*2*MSZ + e] = h;
    Msp[(size_t)k*2*MSZ + MSZ + e] = l;
}

// ---------- bias vector: vvec = alpha*smean - ascale*(T cmean) ----------

__global__ __launch_bounds__(256) void k_buildV(const float* __restrict__ T,
        const float* __restrict__ tvals, const float* __restrict__ cmean,
        const float* __restrict__ smean, float* __restrict__ vvec){
    __shared__ float cm[512];
    int k = blockIdx.x, t = threadIdx.x;
    cm[t] = cmean[k*C_DIM + t];
    cm[t+256] = cmean[k*C_DIM + t + 256];
    __syncthreads();
    float scale = ALPHA_C * sqrtf(tvals[8+k]/tvals[k]);
    int c = blockIdx.y*256 + t;
    const float* row = T + (size_t)k*MSZ + (size_t)c*C_DIM;
    float s = 0.0f;
    for (int d=0; d<C_DIM; d++) s = fmaf(row[d], cm[d], s);
    vvec[k*C_DIM + c] = ALPHA_C*smean[k*C_DIM + c] - scale*s;
}

// ---------- MFMA apply: Sg = M*Xc + v in gathered order (coalesced) ----------

__global__ __launch_bounds__(256,2) void k_apply_mfma(
        const ushort* __restrict__ Msp, const ushort* __restrict__ XT,
        const float* __restrict__ vvec, const int* __restrict__ offPad,
        float* __restrict__ Sg){
    __shared__ ushort As[2][8192];
    __shared__ ushort Bs[2][8192];
    __shared__ int so[9];
    int t = threadIdx.x;
    if (t < 9) so[t] = offPad[t];
    __syncthreads();
    int wg = xcd_swz(blockIdx.x, (CAP/128)*4);
    int j0 = (wg>>2)*128;
    int i0 = (wg&3)*128;
    if (j0 >= so[8]) return;
    int cl = 0;
    while (cl < 7 && j0 >= so[cl+1]) cl++;
    const ushort* Am = Msp + (size_t)cl*2*MSZ;
    int lane = t & 63, wave = t >> 6;
    int wm = wave >> 1, wn = wave & 1;
    int lr = lane & 15, lk = lane >> 4;
    f32x4 zero = {0.f,0.f,0.f,0.f};
    f32x4 acc[4][4];
    #pragma unroll
    for (int m=0;m<4;m++)
        #pragma unroll
        for (int n=0;n<4;n++) acc[m][n] = zero;
    mm_core(Am, MSZ, C_DIM, XT, (size_t)CAP*C_DIM, C_DIM, i0, j0, 0, C_DIM,
            As, Bs, acc, wm, wn, lr, lk);
    #pragma unroll
    for (int m=0;m<4;m++)
        #pragma unroll
        for (int nn=0;nn<4;nn++)
            #pragma unroll
            for (int j=0;j<4;j++){
                int gr = i0 + wm*64 + m*16 + lk*4 + j;
                int gc = j0 + wn*64 + nn*16 + lr;
                Sg[(size_t)gr*CAP + gc] = acc[m][nn][j] + vvec[cl*C_DIM + gr];
            }
}

// ---------- scatter: out[c][p] = Sg[c][ginv[p]] (coalesced writes) ----------

__global__ __launch_bounds__(256) void k_scatter(const float* __restrict__ Sg,
        const int* __restrict__ ginv, float* __restrict__ out){
    size_t idx = (size_t)blockIdx.x*256 + threadIdx.x;
    int p = (int)(idx & (WH-1));
    int c = (int)(idx >> 14);
    out[idx] = Sg[(size_t)c*CAP + ginv[p]];
}

// ---------- host ----------

extern "C" void kernel_launch(void* const* d_in, const int* in_sizes, int n_in,
                              void* d_out, int out_size, void* d_ws, size_t ws_size,
                              hipStream_t stream) {
    (void)in_sizes; (void)n_in;
    const float* cf     = (const float*)d_in[0];
    const float* sf     = (const float*)d_in[1];
    const float* scores = (const float*)d_in[2];
    const int*   cl     = (const int*)d_in[3];
    const int*   sl     = (const int*)d_in[4];
    float* out = (float*)d_out;
    float* ws  = (float*)d_ws;

    size_t o = 0;
    ushort* XcH = (ushort*)(ws + o);                           // 2 planes packed
    float*  Sg  = ws + o;       o += (size_t)C_DIM*CAP;        // aliased: apply staging
    ushort* XcL = XcH + (size_t)C_DIM*CAP;
    ushort* XsH = (ushort*)(ws + o); o += (size_t)C_DIM*CAP;   // reused as XcT planes
    float* S4  = ws + o; o += (size_t)NMAT*MSZ;                // NS slot 4 / bA planes
    float* NS0 = ws + o; o += (size_t)4*NMAT*MSZ;              // NS slots 0..3 / syrk partials
    float* cmean = ws + o; o += 8*C_DIM;
    float* ssum  = ws + o; o += 8*C_DIM;
    float* smean = ws + o; o += 8*C_DIM;
    float* vvec  = ws + o; o += 8*C_DIM;
    float* tvals = ws + o; o += 16;
    float* rowpart = ws + o; o += (size_t)NMAT*4*512;
    float* total = ws + o; o += 8;
    int* ip = (int*)(ws + o);
    int* permC    = ip; ip += CAP;
    int* permCinv = ip; ip += CAP;
    int* permS    = ip; ip += CAP;
    int* cntC  = ip; ip += 8;
    int* cntS  = ip; ip += 8;
    int* offC  = ip; ip += 9;
    int* offS  = ip; ip += 9;
    int* chC   = ip; ip += NCHUNK*8;
    int* chS   = ip; ip += NCHUNK*8;
    int* baseC = ip; ip += NCHUNK*8;
    int* baseS = ip; ip += NCHUNK*8;
    size_t need_bytes = (size_t)((char*)ip - (char*)d_ws);
    if (ws_size < need_bytes){
        hipMemcpyAsync(d_out, (const void*)cf, (size_t)out_size*sizeof(float),
                       hipMemcpyDeviceToDevice, stream);
        return;
    }
    float* Pf = NS0;                                   // SYRK partials (4 slices)
    ushort* s0 = (ushort*)(NS0 + 0*(size_t)NMAT*MSZ);
    ushort* s1 = (ushort*)(NS0 + 1*(size_t)NMAT*MSZ);
    ushort* s2 = (ushort*)(NS0 + 2*(size_t)NMAT*MSZ);
    ushort* s3 = (ushort*)(NS0 + 3*(size_t)NMAT*MSZ);
    ushort* s4 = (ushort*)S4;

    k_chunk_hist<<<NCHUNK,256,0,stream>>>(cl, chC);
    k_chunk_hist<<<NCHUNK,256,0,stream>>>(sl, chS);
    k_scan<<<1,64,0,stream>>>(chC, cntC, offC, baseC);
    k_scan<<<1,64,0,stream>>>(chS, cntS, offS, baseS);
    k_place<<<NCHUNK,64,0,stream>>>(cl, baseC, permC, permCinv);
    k_place<<<NCHUNK,64,0,stream>>>(sl, baseS, permS, nullptr);

    dim3 gg(CAP/256, C_DIM);
    k_gather<<<gg,256,0,stream>>>(cf, permC, offC, cntC, XcH, XcL);
    k_gather<<<gg,256,0,stream>>>(sf, permS, offS, cntS, XsH, XsH + (size_t)C_DIM*CAP);

    k_segsum<true><<<dim3(8,16),256,0,stream>>>(XcH, XcL, offC, cntC, cmean);
    k_segsum<false><<<dim3(8,16),256,0,stream>>>(XsH, XsH + (size_t)C_DIM*CAP, offS, cntS, ssum);
    k_style_mean<<<1,256,0,stream>>>(scores, cntS, ssum, total, smean);

    // raw S2 for all 16 (cluster, src) pairs, triangular tiles, split-K=4
    k_syrk_mfma<<<NMAT*NSLICE*10,256,0,stream>>>(XcH, XsH, offC, offS, Pf);

    // transpose Xc planes into Xs region (Xs fully consumed above)
    k_transpose<<<dim3(CAP/64, C_DIM/64, 2),256,0,stream>>>(XcH, XsH);
    ushort* XT = XsH;

    // assemble A (folds split-K reduction; coalesced; writes split planes both triangles)
    ushort* bA = s4;
    k_assemble<<<dim3(10,16),256,0,stream>>>(Pf, scores, total, cmean, smean, cntC, bA);

    // t = sqrt(||A^2||_1) via MFMA row-sums (no C write)
    k_mm_rowsum<<<NMAT*16,256,0,stream>>>(bA, rowpart);
    k_tmax<<<NMAT,256,0,stream>>>(rowpart, tvals);

    ushort* bY = s0;  ushort* bZ = s1;  ushort* bP = s2;
    ushort* fy = s3;  ushort* fz = s4;   // fz reuses bA slot (consumed by split_init)
    k_split_init<<<dim3(MSZ/256,NMAT),256,0,stream>>>(bA, tvals, bY, bZ);

    for (int it=0; it<NIT; ++it){
        k_mm_ns<1><<<NMAT*16,256,0,stream>>>(bZ, bY, bP, nullptr, NMAT); // P = q(Z*Y)
        k_mm_ns2<<<NMAT*32,256,0,stream>>>(bY, bP, bZ, fy, fz);          // fy=Y*P, fz=P*Z
        ushort* t1;
        t1 = bY; bY = fy; fy = t1;
        t1 = bZ; bZ = fz; fz = t1;
    }
    // T[k] = Y_style[8+k] * Z_content[k], fp32 into free slot fy
    float* Tf = (float*)fy;
    k_mm_ns<2><<<8*16,256,0,stream>>>(bY + (size_t)8*2*MSZ, bZ, nullptr, Tf, 8);

    ushort* Msp = fz;  // other free slot
    k_buildM<<<dim3(MSZ/256,8),256,0,stream>>>(Tf, tvals, Msp);
    k_buildV<<<dim3(8,2),256,0,stream>>>(Tf, tvals, cmean, smean, vvec);

    k_apply_mfma<<<(CAP/128)*4,256,0,stream>>>(Msp, XT, vvec, offC, Sg);
    k_scatter<<<(C_DIM*WH)/256,256,0,stream>>>(Sg, permCinv, out);
}

// Round 7
// 798.267 us; speedup vs baseline: 1.5321x; 1.1103x over previous
//
#include <hip/hip_runtime.h>
#include <math.h>

#define C_DIM 512
#define WH    16384
#define CAP   17408      // 16384 + 8*128 worst-case padding
#define NBX   136        // CAP/128
#define SEG_ALIGN 128
#define NCHUNK 64
#define CHUNK  256
#define NMAT 16
#define NSLICE 4
#define MSZ  (C_DIM*C_DIM)
#define ALPHA_C 0.8f
#define EPS_C   1e-6f
#define NIT 9

typedef __attribute__((ext_vector_type(8))) __bf16 bfrag;
typedef __attribute__((ext_vector_type(4))) float f32x4;

__device__ inline float bf2f(ushort h){ return __uint_as_float(((unsigned)h)<<16); }
__device__ inline void split2(float v, ushort& h, ushort& l){
    unsigned u = __float_as_uint(v);
    h = (ushort)(u >> 16);
    float r = v - __uint_as_float(u & 0xffff0000u);
    l = (ushort)(__float_as_uint(r) >> 16);
}

// XCD-contiguous chunk swizzle (requires nwg % 8 == 0)
__device__ __forceinline__ int xcd_swz(int bid, int nwg){
    int c = nwg >> 3;
    return (bid & 7)*c + (bid >> 3);
}

// async 16B global -> LDS (linear dest, per-lane source)
__device__ __forceinline__ void gload16(const void* g, void* l){
    __builtin_amdgcn_global_load_lds(
        (const __attribute__((address_space(1))) unsigned int*)g,
        (__attribute__((address_space(3))) unsigned int*)l, 16, 0, 0);
}

// stage one 128x64 bf16 panel: LDS linear, source pre-swizzled (rule 21)
__device__ __forceinline__ void stage_panel(const ushort* __restrict__ src,
        int stride, int i0, int k0, ushort* lds){
    int t = threadIdx.x;
    #pragma unroll
    for (int i = 0; i < 4; ++i){
        int slot = t + i*256;
        int row = slot >> 3, c8 = slot & 7;
        const ushort* g = src + (size_t)(i0+row)*stride + k0 + ((c8 ^ (row&7))<<3);
        gload16((const void*)g, (void*)&lds[(size_t)(i*256 + (t & 192))*8]);
    }
}

// shared MFMA inner block: 128x128 tile, K=64 step, split-3 products
#define MFMA_TILE_BLOCK(As0, As1, Bs0, Bs1) \
do { \
    _Pragma("unroll") \
    for (int kk = 0; kk < 64; kk += 32){ \
        bfrag ah[4], al[4], bh[4], bl[4]; \
        _Pragma("unroll") \
        for (int m_ = 0; m_ < 4; ++m_){ \
            int row_ = wm*64 + m_*16 + lr; \
            int off_ = (row_*64 + kk + lk*8) ^ ((row_&7)<<3); \
            ah[m_] = *(const bfrag*)&(As0)[off_]; \
            al[m_] = *(const bfrag*)&(As1)[off_]; \
        } \
        _Pragma("unroll") \
        for (int n_ = 0; n_ < 4; ++n_){ \
            int row_ = wn*64 + n_*16 + lr; \
            int off_ = (row_*64 + kk + lk*8) ^ ((row_&7)<<3); \
            bh[n_] = *(const bfrag*)&(Bs0)[off_]; \
            bl[n_] = *(const bfrag*)&(Bs1)[off_]; \
        } \
        _Pragma("unroll") \
        for (int m_ = 0; m_ < 4; ++m_) \
            _Pragma("unroll") \
            for (int n_ = 0; n_ < 4; ++n_){ \
                acc[m_][n_] = __builtin_amdgcn_mfma_f32_16x16x32_bf16(ah[m_], bh[n_], acc[m_][n_], 0,0,0); \
                acc[m_][n_] = __builtin_amdgcn_mfma_f32_16x16x32_bf16(ah[m_], bl[n_], acc[m_][n_], 0,0,0); \
                acc[m_][n_] = __builtin_amdgcn_mfma_f32_16x16x32_bf16(al[m_], bh[n_], acc[m_][n_], 0,0,0); \
            } \
    } \
} while(0)

// unified K-loop: C(128x128) += A[i0.., kLo..kHi] * B[j0.., kLo..kHi]^T on split planes
__device__ __forceinline__ void mm_core(const ushort* __restrict__ Am, size_t aPl, int aStr,
        const ushort* __restrict__ Bm, size_t bPl, int bStr,
        int i0, int j0, int kLo, int kHi,
        ushort (&As)[2][8192], ushort (&Bs)[2][8192], f32x4 (&acc)[4][4],
        int wm, int wn, int lr, int lk){
    for (int k0 = kLo; k0 < kHi; k0 += 64){
        stage_panel(Am,       aStr, i0, k0, As[0]);
        stage_panel(Am + aPl, aStr, i0, k0, As[1]);
        stage_panel(Bm,       bStr, j0, k0, Bs[0]);
        stage_panel(Bm + bPl, bStr, j0, k0, Bs[1]);
        __syncthreads();
        MFMA_TILE_BLOCK(As[0], As[1], Bs[0], Bs[1]);
        __syncthreads();
    }
}

// ---------- label bookkeeping (deterministic counting sort) ----------

__global__ __launch_bounds__(256) void k_chunk_hist(const int* __restrict__ labels,
                                                    int* __restrict__ chunkCnt){
    __shared__ int h[8];
    int t = threadIdx.x;
    if (t < 8) h[t] = 0;
    __syncthreads();
    int l = labels[blockIdx.x*CHUNK + t];
    atomicAdd(&h[l], 1);
    __syncthreads();
    if (t < 8) chunkCnt[blockIdx.x*8 + t] = h[t];
}

__global__ void k_scan(const int* __restrict__ chunkCnt, int* __restrict__ cnt,
                       int* __restrict__ offPad, int* __restrict__ base){
    if (threadIdx.x != 0) return;
    int c[8];
    for (int k=0;k<8;k++) c[k]=0;
    for (int ch=0; ch<NCHUNK; ch++)
        for (int k=0;k<8;k++) c[k] += chunkCnt[ch*8+k];
    int off = 0;
    for (int k=0;k<8;k++){
        cnt[k] = c[k];
        offPad[k] = off;
        off += ((c[k] + SEG_ALIGN - 1)/SEG_ALIGN)*SEG_ALIGN;
    }
    offPad[8] = off;
    for (int k=0;k<8;k++){
        int run = offPad[k];
        for (int ch=0; ch<NCHUNK; ch++){
            base[ch*8+k] = run;
            run += chunkCnt[ch*8+k];
        }
    }
}

__global__ void k_place(const int* __restrict__ labels, const int* __restrict__ base,
                        int* __restrict__ perm, int* __restrict__ inv){
    int t = threadIdx.x;
    if (t >= 8) return;
    int ch = blockIdx.x;
    int pos = base[ch*8+t];
    int s = ch*CHUNK;
    for (int i=0;i<CHUNK;i++){
        if (labels[s+i] == t){
            perm[pos] = s+i;
            if (inv) inv[s+i] = pos;
            pos++;
        }
    }
}

// ---------- gather + split + fused per-cluster partial sums ----------
// block: 16 channels x 128-pixel window (128-aligned => single segment per block)

__global__ __launch_bounds__(256) void k_gather2(const float* __restrict__ src,
        const int* __restrict__ perm, const int* __restrict__ offPad,
        const int* __restrict__ cnt, ushort* __restrict__ dstH,
        ushort* __restrict__ dstL, float* __restrict__ psum,
        int* __restrict__ segOf){
    __shared__ int so[9], sc[8];
    __shared__ int pcache[128];
    int t = threadIdx.x;
    if (t < 9) so[t] = offPad[t];
    if (t < 8) sc[t] = cnt[t];
    __syncthreads();
    int bx = blockIdx.x;                 // 0..NBX-1
    int i0 = bx*128;
    if (t < 128) pcache[t] = (i0 + t < so[8]) ? perm[i0 + t] : 0;
    __syncthreads();
    int k = 0;
    while (k < 7 && i0 >= so[k+1]) k++;
    int n = sc[k], s0 = so[k];
    int ch = t >> 4, px0 = (t & 15)*8;
    int c  = blockIdx.y*16 + ch;
    const float* row = src + (size_t)c*WH;
    float v[8];
    #pragma unroll
    for (int x=0;x<8;x++){
        int i = i0 + px0 + x;
        v[x] = (i - s0 < n) ? row[pcache[px0+x]] : 0.0f;
    }
    float s = 0.0f;
    ushort hv[8], lv[8];
    #pragma unroll
    for (int x=0;x<8;x++){
        s += v[x];
        split2(v[x], hv[x], lv[x]);
    }
    *(uint4*)&dstH[(size_t)c*CAP + i0 + px0] = *(uint4*)hv;
    *(uint4*)&dstL[(size_t)c*CAP + i0 + px0] = *(uint4*)lv;
    #pragma unroll
    for (int d=1; d<16; d<<=1) s += __shfl_xor(s, d, 16);
    if ((t & 15) == 0) psum[(size_t)c*NBX + bx] = s;
    if (t == 0) segOf[bx] = k;
}

// ---------- reduce partials -> per-cluster sums/means (deterministic fixed order) ----------

template<bool DIV_N>
__global__ __launch_bounds__(256) void k_meanred(const float* __restrict__ psum,
        const int* __restrict__ segOf, const int* __restrict__ cnt,
        float* __restrict__ out){
    int k = blockIdx.x;
    int c = blockIdx.y*256 + threadIdx.x;
    float s = 0.0f;
    for (int bx=0; bx<NBX; bx++)
        if (segOf[bx] == k) s += psum[(size_t)c*NBX + bx];
    out[k*C_DIM + c] = DIV_N ? s/(float)cnt[k] : s;
}

// ---------- transpose plane: [512][CAP] -> [CAP][512] ----------

__global__ __launch_bounds__(256) void k_transpose(const ushort* __restrict__ S,
                                                   ushort* __restrict__ D){
    __shared__ ushort tile[64][72];
    int p = blockIdx.z;
    const ushort* Sp = S + (size_t)p*C_DIM*CAP;
    ushort* Dp = D + (size_t)p*CAP*C_DIM;
    int cb = blockIdx.x*64;   // pixel block
    int rb = blockIdx.y*64;   // channel block
    int t = threadIdx.x;
    int tr = t >> 3, tc = t & 7;
    #pragma unroll
    for (int i=0;i<2;i++){
        int r = tr + i*32;
        uint4 v = *(const uint4*)&Sp[(size_t)(rb+r)*CAP + cb + tc*8];
        ushort* u = (ushort*)&v;
        #pragma unroll
        for (int j=0;j<8;j++) tile[tc*8+j][r] = u[j];
    }
    __syncthreads();
    #pragma unroll
    for (int i=0;i<2;i++){
        int r = tr + i*32;
        uint4 v;
        ushort* u = (ushort*)&v;
        #pragma unroll
        for (int j=0;j<8;j++) u[j] = tile[r][tc*8+j];
        *(uint4*)&Dp[(size_t)(cb+r)*C_DIM + rb + tc*8] = v;
    }
}

__global__ __launch_bounds__(256) void k_style_mean(const float* __restrict__ scores,
        const int* __restrict__ cntS, const float* __restrict__ ssum,
        float* __restrict__ total, float* __restrict__ smean){
    int t = threadIdx.x;
    __shared__ float tot[8];
    if (t < 8){
        float s = 0.0f;
        for (int j=0;j<8;j++) s += scores[t*8+j]*(float)cntS[j];
        tot[t] = s; total[t] = s;
    }
    __syncthreads();
    for (int idx=t; idx<8*C_DIM; idx+=256){
        int k = idx / C_DIM, c = idx % C_DIM;
        float s = 0.0f;
        for (int j=0;j<8;j++) s += scores[k*8+j]*ssum[j*C_DIM+c];
        smean[idx] = s / tot[k];
    }
}

// ---------- MFMA SYRK: partial S2 = X X^T, triangular tiles, split-K ----------

__global__ __launch_bounds__(256,2) void k_syrk_mfma(
        const ushort* __restrict__ Xc, const ushort* __restrict__ Xs,
        const int* __restrict__ offC, const int* __restrict__ offS,
        float* __restrict__ Pf){
    __shared__ ushort As[2][8192];
    __shared__ ushort Bs[2][8192];
    int wg = xcd_swz(blockIdx.x, NMAT*NSLICE*10);
    int mat = wg / (NSLICE*10);
    int rem = wg % (NSLICE*10);
    int slice = rem / 10, tt = rem % 10;
    int ti, tj;
    if (tt < 4){ ti=0; tj=tt; }
    else if (tt < 7){ ti=1; tj=tt-3; }
    else if (tt < 9){ ti=2; tj=tt-5; }
    else { ti=3; tj=3; }
    const ushort* X = (mat < 8) ? Xc : Xs;
    const int* offP = (mat < 8) ? offC : offS;
    int cl = mat & 7;
    int off = offP[cl], npad = offP[cl+1] - off;
    int i0 = ti*128, j0 = tj*128;
    int L = ((npad + NSLICE*64 - 1)/(NSLICE*64))*64;
    int k_lo = slice*L;
    int k_hi = min(k_lo + L, npad);
    int t = threadIdx.x;
    int lane = t & 63, wave = t >> 6;
    int wm = wave >> 1, wn = wave & 1;
    int lr = lane & 15, lk = lane >> 4;
    f32x4 zero = {0.f,0.f,0.f,0.f};
    f32x4 acc[4][4];
    #pragma unroll
    for (int m=0;m<4;m++)
        #pragma unroll
        for (int n=0;n<4;n++) acc[m][n] = zero;
    mm_core(X + off, (size_t)C_DIM*CAP, CAP,
            X + off, (size_t)C_DIM*CAP, CAP,
            i0, j0, k_lo, k_hi, As, Bs, acc, wm, wn, lr, lk);
    float* O = Pf + ((size_t)(slice*16 + mat))*MSZ;
    #pragma unroll
    for (int m=0;m<4;m++)
        #pragma unroll
        for (int n=0;n<4;n++)
            #pragma unroll
            for (int j=0;j<4;j++){
                int gr = i0 + wm*64 + m*16 + lk*4 + j;
                int gc = j0 + wn*64 + n*16 + lr;
                O[(size_t)gr*C_DIM + gc] = acc[m][n][j];
            }
}

// ---------- assemble A: tile-based, coalesced reads, LDS-transpose mirror ----------
// writes split bf16 planes bA directly (both triangles)

__global__ __launch_bounds__(256) void k_assemble(const float* __restrict__ P0,
        const float* __restrict__ scores, const float* __restrict__ total,
        const float* __restrict__ cmean, const float* __restrict__ smean,
        const int* __restrict__ cntC, ushort* __restrict__ bA){
    const size_t S = (size_t)NMAT*MSZ;
    __shared__ ushort tH[64][136];
    __shared__ ushort tL[64][136];
    int mat = blockIdx.y;
    int tt = blockIdx.x;
    int ti, tj;
    if (tt < 4){ ti=0; tj=tt; }
    else if (tt < 7){ ti=1; tj=tt-3; }
    else if (tt < 9){ ti=2; tj=tt-5; }
    else { ti=3; tj=3; }
    int i0 = ti*128, j0 = tj*128;
    int t = threadIdx.x;
    ushort* bm = bA + (size_t)mat*2*MSZ;
    int k = mat - 8;
    float nOrTot = (mat < 8) ? (float)cntC[mat] : total[k];
    float inv_nm1 = 1.0f/(nOrTot - 1.0f);
    const float* mrow = (mat < 8) ? (cmean + mat*C_DIM) : (smean + k*C_DIM);
    for (int h = 0; h < 2; ++h){
        #pragma unroll
        for (int rep = 0; rep < 4; ++rep){
            int lin = rep*2048 + t*8;
            int r = lin >> 7;            // 0..63
            int c = lin & 127;           // multiple of 8
            int gr = i0 + h*64 + r;
            int gc = j0 + c;
            size_t e = (size_t)gr*C_DIM + gc;
            float s2[8];
            if (mat < 8){
                size_t b = (size_t)mat*MSZ + e;
                #pragma unroll
                for (int x=0;x<8;x++)
                    s2[x] = P0[b+x] + P0[b+S+x] + P0[b+2*S+x] + P0[b+3*S+x];
            } else {
                #pragma unroll
                for (int x=0;x<8;x++) s2[x] = 0.0f;
                #pragma unroll
                for (int jj=0;jj<8;jj++){
                    float sc = scores[k*8+jj];
                    size_t b = (size_t)(8+jj)*MSZ + e;
                    #pragma unroll
                    for (int x=0;x<8;x++)
                        s2[x] += sc*(P0[b+x] + P0[b+S+x] + P0[b+2*S+x] + P0[b+3*S+x]);
                }
            }
            float mi = mrow[gr];
            #pragma unroll
            for (int x=0;x<8;x++){
                float v = (s2[x] - nOrTot*mi*mrow[gc+x])*inv_nm1;
                if (mat < 8 && gr == gc+x) v += EPS_C;
                ushort hh,ll; split2(v,hh,ll);
                bm[e+x] = hh; bm[MSZ+e+x] = ll;
                tH[r][c+x] = hh; tL[r][c+x] = ll;
            }
        }
        if (ti != tj){
            __syncthreads();
            #pragma unroll
            for (int rep = 0; rep < 4; ++rep){
                int lin = rep*2048 + t*8;
                int rr = lin >> 6;       // 0..127
                int cc0 = lin & 63;      // multiple of 8
                size_t eo = (size_t)(j0+rr)*C_DIM + i0 + h*64 + cc0;
                #pragma unroll
                for (int x=0;x<8;x++){
                    bm[eo+x]     = tH[cc0+x][rr];
                    bm[MSZ+eo+x] = tL[cc0+x][rr];
                }
            }
            __syncthreads();
        }
    }
}

// ---------- A^2 row abs-sums via MFMA (no C write): rowpart[mat][tj][row] ----------

__global__ __launch_bounds__(256,2) void k_mm_rowsum(
        const ushort* __restrict__ A, float* __restrict__ rowpart){
    __shared__ ushort As[2][8192];
    __shared__ ushort Bs[2][8192];
    __shared__ float rs[128][2];
    int wg = xcd_swz(blockIdx.x, NMAT*16);
    int mat = wg >> 4, tile = wg & 15;
    int ti = tile >> 2, tj = tile & 3;
    int i0 = ti*128, j0 = tj*128;
    const ushort* Am = A + (size_t)mat*2*MSZ;
    int t = threadIdx.x;
    int lane = t & 63, wave = t >> 6;
    int wm = wave >> 1, wn = wave & 1;
    int lr = lane & 15, lk = lane >> 4;
    f32x4 zero = {0.f,0.f,0.f,0.f};
    f32x4 acc[4][4];
    #pragma unroll
    for (int m=0;m<4;m++)
        #pragma unroll
        for (int n=0;n<4;n++) acc[m][n] = zero;
    mm_core(Am, MSZ, C_DIM, Am, MSZ, C_DIM, i0, j0, 0, C_DIM,
            As, Bs, acc, wm, wn, lr, lk);
    #pragma unroll
    for (int m=0;m<4;m++)
        #pragma unroll
        for (int j=0;j<4;j++){
            float s = 0.0f;
            #pragma unroll
            for (int n=0;n<4;n++) s += fabsf(acc[m][n][j]);
            #pragma unroll
            for (int d=1; d<16; d<<=1) s += __shfl_xor(s, d);
            if (lr == 0) rs[wm*64 + m*16 + lk*4 + j][wn] = s;
        }
    __syncthreads();
    if (t < 128)
        rowpart[((size_t)mat*4 + tj)*512 + i0 + t] = rs[t][0] + rs[t][1];
}

// ---------- t = sqrt(max row sum of |A^2|) >= lambda_max, per matrix ----------

__global__ __launch_bounds__(256) void k_tmax(const float* __restrict__ rowpart,
                                              float* __restrict__ tvals){
    int mat = blockIdx.x, t = threadIdx.x;
    const float* rp = rowpart + (size_t)mat*4*512;
    float mx = 0.0f;
    for (int r = t; r < 512; r += 256){
        float s = rp[r] + rp[512+r] + rp[1024+r] + rp[1536+r];
        mx = fmaxf(mx, s);
    }
    __shared__ float red[256];
    red[t] = mx; __syncthreads();
    for (int s=128; s>0; s>>=1){ if (t<s) red[t]=fmaxf(red[t],red[t+s]); __syncthreads(); }
    if (t == 0) tvals[mat] = sqrtf(red[0]);
}

// ---------- Y = A/t (from planes), Z = I ----------

__global__ __launch_bounds__(256) void k_split_init(const ushort* __restrict__ bA,
        const float* __restrict__ tvals, ushort* __restrict__ Y,
        ushort* __restrict__ Z){
    int mat = blockIdx.y;
    int e = blockIdx.x*256 + threadIdx.x;
    size_t base = (size_t)mat*2*MSZ;
    float inv = 1.0f / tvals[mat];
    float a = (bf2f(bA[base+e]) + bf2f(bA[base+MSZ+e])) * inv;
    ushort h,l; split2(a,h,l);
    Y[base + e] = h;
    Y[base + MSZ + e] = l;
    int i = e >> 9, j = e & 511;
    Z[base + e] = (i==j) ? (ushort)0x3F80 : (ushort)0;
    Z[base + MSZ + e] = 0;
}

// ---------- batched 512^3 split-bf16 MFMA matmul: C = A * B^T (operands symmetric) ----------
// EPI 0: split write; EPI 1: q(X)=1.5I-0.5X then split write; EPI 2: fp32 write

template<int EPI>
__global__ __launch_bounds__(256,2) void k_mm_ns(
        const ushort* __restrict__ A, const ushort* __restrict__ B,
        ushort* __restrict__ Co, float* __restrict__ Cf, int nmat){
    __shared__ ushort As[2][8192];
    __shared__ ushort Bs[2][8192];
    int wg = xcd_swz(blockIdx.x, nmat*16);
    int mat = wg >> 4, tile = wg & 15;
    int i0 = (tile>>2)*128, j0 = (tile&3)*128;
    const ushort* Am = A + (size_t)mat*2*MSZ;
    const ushort* Bm = B + (size_t)mat*2*MSZ;
    int t = threadIdx.x;
    int lane = t & 63, wave = t >> 6;
    int wm = wave >> 1, wn = wave & 1;
    int lr = lane & 15, lk = lane >> 4;
    f32x4 zero = {0.f,0.f,0.f,0.f};
    f32x4 acc[4][4];
    #pragma unroll
    for (int m=0;m<4;m++)
        #pragma unroll
        for (int n=0;n<4;n++) acc[m][n] = zero;
    mm_core(Am, MSZ, C_DIM, Bm, MSZ, C_DIM, i0, j0, 0, C_DIM,
            As, Bs, acc, wm, wn, lr, lk);
    if (EPI == 2){
        float* Cm = Cf + (size_t)mat*MSZ;
        #pragma unroll
        for (int m=0;m<4;m++)
            #pragma unroll
            for (int n=0;n<4;n++)
                #pragma unroll
                for (int j=0;j<4;j++){
                    int gr = i0 + wm*64 + m*16 + lk*4 + j;
                    int gc = j0 + wn*64 + n*16 + lr;
                    Cm[(size_t)gr*C_DIM + gc] = acc[m][n][j];
                }
    } else {
        ushort* Ch = Co + (size_t)mat*2*MSZ;
        ushort* Cl = Ch + MSZ;
        #pragma unroll
        for (int m=0;m<4;m++)
            #pragma unroll
            for (int n=0;n<4;n++)
                #pragma unroll
                for (int j=0;j<4;j++){
                    int gr = i0 + wm*64 + m*16 + lk*4 + j;
                    int gc = j0 + wn*64 + n*16 + lr;
                    float v = acc[m][n][j];
                    if (EPI == 1) v = ((gr==gc)?1.5f:0.0f) - 0.5f*v;
                    ushort h,l; split2(v,h,l);
                    size_t idx = (size_t)gr*C_DIM + gc;
                    Ch[idx] = h;
                    Cl[idx] = l;
                }
    }
}

// ---------- merged NS stage 2: fy = Y*qP, fz = qP*Z ----------

__global__ __launch_bounds__(256,2) void k_mm_ns2(
        const ushort* __restrict__ Y, const ushort* __restrict__ P,
        const ushort* __restrict__ Z, ushort* __restrict__ fy,
        ushort* __restrict__ fz){
    __shared__ ushort As[2][8192];
    __shared__ ushort Bs[2][8192];
    int wg = xcd_swz(blockIdx.x, NMAT*32);
    int mat = wg >> 5;
    int r = wg & 31;
    int op = r >> 4, tile = r & 15;
    int i0 = (tile>>2)*128, j0 = (tile&3)*128;
    const ushort* Am = (op ? P : Y) + (size_t)mat*2*MSZ;
    const ushort* Bm = (op ? Z : P) + (size_t)mat*2*MSZ;
    ushort* Ch = (op ? fz : fy) + (size_t)mat*2*MSZ;
    ushort* Cl = Ch + MSZ;
    int t = threadIdx.x;
    int lane = t & 63, wave = t >> 6;
    int wm = wave >> 1, wn = wave & 1;
    int lr = lane & 15, lk = lane >> 4;
    f32x4 zero = {0.f,0.f,0.f,0.f};
    f32x4 acc[4][4];
    #pragma unroll
    for (int m=0;m<4;m++)
        #pragma unroll
        for (int n=0;n<4;n++) acc[m][n] = zero;
    mm_core(Am, MSZ, C_DIM, Bm, MSZ, C_DIM, i0, j0, 0, C_DIM,
            As, Bs, acc, wm, wn, lr, lk);
    #pragma unroll
    for (int m=0;m<4;m++)
        #pragma unroll
        for (int n=0;n<4;n++)
            #pragma unroll
            for (int j=0;j<4;j++){
                int gr = i0 + wm*64 + m*16 + lk*4 + j;
                int gc = j0 + wn*64 + n*16 + lr;
                ushort h,l; split2(acc[m][n][j],h,l);
                size_t idx = (size_t)gr*C_DIM + gc;
                Ch[idx] = h;
                Cl[idx] = l;
            }
}

// ---------- last NS stage 2: only consumed halves (fz for content, fy for style) ----------

__global__ __launch_bounds__(256,2) void k_mm_ns2_last(
        const ushort* __restrict__ Y, const ushort* __restrict__ P,
        const ushort* __restrict__ Z, ushort* __restrict__ fy,
        ushort* __restrict__ fz){
    __shared__ ushort As[2][8192];
    __shared__ ushort Bs[2][8192];
    int wg = xcd_swz(blockIdx.x, NMAT*16);
    int mat = wg >> 4, tile = wg & 15;
    int op = (mat < 8) ? 1 : 0;         // content: fz = P*Z ; style: fy = Y*P
    int i0 = (tile>>2)*128, j0 = (tile&3)*128;
    const ushort* Am = (op ? P : Y) + (size_t)mat*2*MSZ;
    const ushort* Bm = (op ? Z : P) + (size_t)mat*2*MSZ;
    ushort* Ch = (op ? fz : fy) + (size_t)mat*2*MSZ;
    ushort* Cl = Ch + MSZ;
    int t = threadIdx.x;
    int lane = t & 63, wave = t >> 6;
    int wm = wave >> 1, wn = wave & 1;
    int lr = lane & 15, lk = lane >> 4;
    f32x4 zero = {0.f,0.f,0.f,0.f};
    f32x4 acc[4][4];
    #pragma unroll
    for (int m=0;m<4;m++)
        #pragma unroll
        for (int n=0;n<4;n++) acc[m][n] = zero;
    mm_core(Am, MSZ, C_DIM, Bm, MSZ, C_DIM, i0, j0, 0, C_DIM,
            As, Bs, acc, wm, wn, lr, lk);
    #pragma unroll
    for (int m=0;m<4;m++)
        #pragma unroll
        for (int n=0;n<4;n++)
            #pragma unroll
            for (int j=0;j<4;j++){
                int gr = i0 + wm*64 + m*16 + lk*4 + j;
                int gc = j0 + wn*64 + n*16 + lr;
                ushort h,l; split2(acc[m][n][j],h,l);
                size_t idx = (size_t)gr*C_DIM + gc;
                Ch[idx] = h;
                Cl[idx] = l;
            }
}

// ---------- build split M = ascale*T + (1-alpha)I ----------

__global__ __launch_bounds__(256) void k_buildM(const float* __restrict__ T,
        const float* __restrict__ tvals, ushort* __restrict__ Msp){
    int k = blockIdx.y;
    int e = blockIdx.x*256 + threadIdx.x;
    float scale = ALPHA_C * sqrtf(tvals[8+k]/tvals[k]);
    float v = scale * T[(size_t)k*MSZ + e];
    if ((e>>9) == (e&511)) v += (1.0f - ALPHA_C);
    ushort h,l; split2(v,h,l);
    Msp[(size_t)k*2*MSZ + e] = h;
    Msp[(size_t)k*2*MSZ + MSZ + e] = l;
}

// ---------- bias vector: vvec = alpha*smean - ascale*(T cmean) ----------

__global__ __launch_bounds__(256) void k_buildV(const float* __restrict__ T,
        const float* __restrict__ tvals, const float* __restrict__ cmean,
        const float* __restrict__ smean, float* __restrict__ vvec){
    __shared__ float cm[512];
    int k = blockIdx.x, t = threadIdx.x;
    cm[t] = cmean[k*C_DIM + t];
    cm[t+256] = cmean[k*C_DIM + t + 256];
    __syncthreads();
    float scale = ALPHA_C * sqrtf(tvals[8+k]/tvals[k]);
    int c = blockIdx.y*256 + t;
    const float* row = T + (size_t)k*MSZ + (size_t)c*C_DIM;
    float s = 0.0f;
    for (int d=0; d<C_DIM; d++) s = fmaf(row[d], cm[d], s);
    vvec[k*C_DIM + c] = ALPHA_C*smean[k*C_DIM + c] - scale*s;
}

// ---------- MFMA apply: Sg = M*Xc + v in gathered order (coalesced) ----------

__global__ __launch_bounds__(256,2) void k_apply_mfma(
        const ushort* __restrict__ Msp, const ushort* __restrict__ XT,
        const float* __restrict__ vvec, const int* __restrict__ offPad,
        float* __restrict__ Sg){
    __shared__ ushort As[2][8192];
    __shared__ ushort Bs[2][8192];
    __shared__ int so[9];
    int t = threadIdx.x;
    if (t < 9) so[t] = offPad[t];
    __syncthreads();
    int wg = xcd_swz(blockIdx.x, (CAP/128)*4);
    int j0 = (wg>>2)*128;
    int i0 = (wg&3)*128;
    if (j0 >= so[8]) return;
    int cl = 0;
    while (cl < 7 && j0 >= so[cl+1]) cl++;
    const ushort* Am = Msp + (size_t)cl*2*MSZ;
    int lane = t & 63, wave = t >> 6;
    int wm = wave >> 1, wn = wave & 1;
    int lr = lane & 15, lk = lane >> 4;
    f32x4 zero = {0.f,0.f,0.f,0.f};
    f32x4 acc[4][4];
    #pragma unroll
    for (int m=0;m<4;m++)
        #pragma unroll
        for (int n=0;n<4;n++) acc[m][n] = zero;
    mm_core(Am, MSZ, C_DIM, XT, (size_t)CAP*C_DIM, C_DIM, i0, j0, 0, C_DIM,
            As, Bs, acc, wm, wn, lr, lk);
    #pragma unroll
    for (int m=0;m<4;m++)
        #pragma unroll
        for (int nn=0;nn<4;nn++)
            #pragma unroll
            for (int j=0;j<4;j++){
                int gr = i0 + wm*64 + m*16 + lk*4 + j;
                int gc = j0 + wn*64 + nn*16 + lr;
                Sg[(size_t)gr*CAP + gc] = acc[m][nn][j] + vvec[cl*C_DIM + gr];
            }
}

// ---------- scatter: out[c][p] = Sg[c][ginv[p]] (coalesced writes) ----------

__global__ __launch_bounds__(256) void k_scatter(const float* __restrict__ Sg,
        const int* __restrict__ ginv, float* __restrict__ out){
    size_t idx = (size_t)blockIdx.x*256 + threadIdx.x;
    int p = (int)(idx & (WH-1));
    int c = (int)(idx >> 14);
    out[idx] = Sg[(size_t)c*CAP + ginv[p]];
}

// ---------- host ----------

extern "C" void kernel_launch(void* const* d_in, const int* in_sizes, int n_in,
                              void* d_out, int out_size, void* d_ws, size_t ws_size,
                              hipStream_t stream) {
    (void)in_sizes; (void)n_in;
    const float* cf     = (const float*)d_in[0];
    const float* sf     = (const float*)d_in[1];
    const float* scores = (const float*)d_in[2];
    const int*   cl     = (const int*)d_in[3];
    const int*   sl     = (const int*)d_in[4];
    float* out = (float*)d_out;
    float* ws  = (float*)d_ws;

    size_t o = 0;
    ushort* XcH = (ushort*)(ws + o);                           // 2 planes packed
    float*  Sg  = ws + o;       o += (size_t)C_DIM*CAP;        // aliased: apply staging
    ushort* XcL = XcH + (size_t)C_DIM*CAP;
    ushort* XsH = (ushort*)(ws + o); o += (size_t)C_DIM*CAP;   // reused as XcT planes
    float* S4  = ws + o; o += (size_t)NMAT*MSZ;                // NS slot 4 / bA planes
    float* NS0 = ws + o; o += (size_t)4*NMAT*MSZ;              // NS slots 0..3 / syrk partials
    float* cmean = ws + o; o += 8*C_DIM;
    float* ssum  = ws + o; o += 8*C_DIM;
    float* smean = ws + o; o += 8*C_DIM;
    float* vvec  = ws + o; o += 8*C_DIM;
    float* tvals = ws + o; o += 16;
    float* rowpart = ws + o; o += (size_t)NMAT*4*512;
    float* total = ws + o; o += 8;
    float* psumC = ws + o; o += (size_t)C_DIM*NBX;
    float* psumS = ws + o; o += (size_t)C_DIM*NBX;
    int* ip = (int*)(ws + o);
    int* permC    = ip; ip += CAP;
    int* permCinv = ip; ip += CAP;
    int* permS    = ip; ip += CAP;
    int* segOfC = ip; ip += NBX;
    int* segOfS = ip; ip += NBX;
    int* cntC  = ip; ip += 8;
    int* cntS  = ip; ip += 8;
    int* offC  = ip; ip += 9;
    int* offS  = ip; ip += 9;
    int* chC   = ip; ip += NCHUNK*8;
    int* chS   = ip; ip += NCHUNK*8;
    int* baseC = ip; ip += NCHUNK*8;
    int* baseS = ip; ip += NCHUNK*8;
    size_t need_bytes = (size_t)((char*)ip - (char*)d_ws);
    if (ws_size < need_bytes){
        hipMemcpyAsync(d_out, (const void*)cf, (size_t)out_size*sizeof(float),
                       hipMemcpyDeviceToDevice, stream);
        return;
    }
    float* Pf = NS0;                                   // SYRK partials (4 slices)
    ushort* s0 = (ushort*)(NS0 + 0*(size_t)NMAT*MSZ);
    ushort* s1 = (ushort*)(NS0 + 1*(size_t)NMAT*MSZ);
    ushort* s2 = (ushort*)(NS0 + 2*(size_t)NMAT*MSZ);
    ushort* s3 = (ushort*)(NS0 + 3*(size_t)NMAT*MSZ);
    ushort* s4 = (ushort*)S4;

    k_chunk_hist<<<NCHUNK,256,0,stream>>>(cl, chC);
    k_chunk_hist<<<NCHUNK,256,0,stream>>>(sl, chS);
    k_scan<<<1,64,0,stream>>>(chC, cntC, offC, baseC);
    k_scan<<<1,64,0,stream>>>(chS, cntS, offS, baseS);
    k_place<<<NCHUNK,64,0,stream>>>(cl, baseC, permC, permCinv);
    k_place<<<NCHUNK,64,0,stream>>>(sl, baseS, permS, nullptr);

    // gather + split + fused cluster partial sums
    dim3 gg(NBX, C_DIM/16);
    k_gather2<<<gg,256,0,stream>>>(cf, permC, offC, cntC, XcH, XcL, psumC, segOfC);
    k_gather2<<<gg,256,0,stream>>>(sf, permS, offS, cntS,
                                   XsH, XsH + (size_t)C_DIM*CAP, psumS, segOfS);

    k_meanred<true><<<dim3(8,2),256,0,stream>>>(psumC, segOfC, cntC, cmean);
    k_meanred<false><<<dim3(8,2),256,0,stream>>>(psumS, segOfS, cntS, ssum);
    k_style_mean<<<1,256,0,stream>>>(scores, cntS, ssum, total, smean);

    // raw S2 for all 16 (cluster, src) pairs, triangular tiles, split-K=4
    k_syrk_mfma<<<NMAT*NSLICE*10,256,0,stream>>>(XcH, XsH, offC, offS, Pf);

    // transpose Xc planes into Xs region (Xs fully consumed above)
    k_transpose<<<dim3(CAP/64, C_DIM/64, 2),256,0,stream>>>(XcH, XsH);
    ushort* XT = XsH;

    // assemble A (folds split-K reduction; coalesced; writes split planes both triangles)
    ushort* bA = s4;
    k_assemble<<<dim3(10,16),256,0,stream>>>(Pf, scores, total, cmean, smean, cntC, bA);

    // t = sqrt(||A^2||_1) via MFMA row-sums (no C write)
    k_mm_rowsum<<<NMAT*16,256,0,stream>>>(bA, rowpart);
    k_tmax<<<NMAT,256,0,stream>>>(rowpart, tvals);

    ushort* bY = s0;  ushort* bZ = s1;  ushort* bP = s2;
    ushort* fy = s3;  ushort* fz = s4;   // fz reuses bA slot (consumed by split_init)
    k_split_init<<<dim3(MSZ/256,NMAT),256,0,stream>>>(bA, tvals, bY, bZ);

    for (int it=0; it<NIT; ++it){
        k_mm_ns<1><<<NMAT*16,256,0,stream>>>(bZ, bY, bP, nullptr, NMAT); // P = q(Z*Y)
        if (it < NIT-1)
            k_mm_ns2<<<NMAT*32,256,0,stream>>>(bY, bP, bZ, fy, fz);      // fy=Y*P, fz=P*Z
        else
            k_mm_ns2_last<<<NMAT*16,256,0,stream>>>(bY, bP, bZ, fy, fz); // only needed halves
        ushort* t1;
        t1 = bY; bY = fy; fy = t1;
        t1 = bZ; bZ = fz; fz = t1;
    }
    // T[k] = Y_style[8+k] * Z_content[k], fp32 into free slot fy
    float* Tf = (float*)fy;
    k_mm_ns<2><<<8*16,256,0,stream>>>(bY + (size_t)8*2*MSZ, bZ, nullptr, Tf, 8);

    ushort* Msp = fz;  // other free slot
    k_buildM<<<dim3(MSZ/256,8),256,0,stream>>>(Tf, tvals, Msp);
    k_buildV<<<dim3(8,2),256,0,stream>>>(Tf, tvals, cmean, smean, vvec);

    k_apply_mfma<<<(CAP/128)*4,256,0,stream>>>(Msp, XT, vvec, offC, Sg);
    k_scatter<<<(C_DIM*WH)/256,256,0,stream>>>(Sg, permCinv, out);
}

// Round 8
// 737.177 us; speedup vs baseline: 1.6591x; 1.0829x over previous
//
#include <hip/hip_runtime.h>
#include <math.h>

#define C_DIM 512
#define WH    16384
#define CAP   17408      // 16384 + 8*128 worst-case padding
#define NBX   136        // CAP/128
#define SEG_ALIGN 128
#define NCHUNK 64
#define CHUNK  256
#define NMAT 16
#define NSLICE 4
#define MSZ  (C_DIM*C_DIM)
#define ALPHA_C 0.8f
#define EPS_C   1e-6f
#define NIT 9            // 1 collapsed + 8 full

typedef __attribute__((ext_vector_type(8))) __bf16 bfrag;
typedef __attribute__((ext_vector_type(4))) float f32x4;

__device__ inline float bf2f(ushort h){ return __uint_as_float(((unsigned)h)<<16); }
__device__ inline void split2(float v, ushort& h, ushort& l){
    unsigned u = __float_as_uint(v);
    h = (ushort)(u >> 16);
    float r = v - __uint_as_float(u & 0xffff0000u);
    l = (ushort)(__float_as_uint(r) >> 16);
}

__device__ __forceinline__ int xcd_swz(int bid, int nwg){
    int c = nwg >> 3;
    return (bid & 7)*c + (bid >> 3);
}

__device__ __forceinline__ void gload16(const void* g, void* l){
    __builtin_amdgcn_global_load_lds(
        (const __attribute__((address_space(1))) unsigned int*)g,
        (__attribute__((address_space(3))) unsigned int*)l, 16, 0, 0);
}

// stage one R x 64 bf16 panel (R = 64 or 128): LDS linear, source pre-swizzled
template<int R>
__device__ __forceinline__ void stage_panelR(const ushort* __restrict__ src,
        int stride, int i0, int k0, ushort* lds){
    int t = threadIdx.x;
    #pragma unroll
    for (int i = 0; i < R/32; ++i){
        int slot = t + i*256;
        int row = slot >> 3, c8 = slot & 7;
        const ushort* g = src + (size_t)(i0+row)*stride + k0 + ((c8 ^ (row&7))<<3);
        gload16((const void*)g, (void*)&lds[(size_t)(i*256 + (t & 192))*8]);
    }
}

// MFMA inner block: (2*MFR*16) x 128 tile, K=64 step, split-3 products
template<int MFR>
__device__ __forceinline__ void mfma_block(const ushort* As0, const ushort* As1,
        const ushort* Bs0, const ushort* Bs1, f32x4 (&acc)[MFR][4],
        int wm, int wn, int lr, int lk){
    #pragma unroll
    for (int kk = 0; kk < 64; kk += 32){
        bfrag ah[MFR], al[MFR], bh[4], bl[4];
        #pragma unroll
        for (int m = 0; m < MFR; ++m){
            int row = wm*(MFR*16) + m*16 + lr;
            int off = (row*64 + kk + lk*8) ^ ((row&7)<<3);
            ah[m] = *(const bfrag*)&As0[off];
            al[m] = *(const bfrag*)&As1[off];
        }
        #pragma unroll
        for (int n = 0; n < 4; ++n){
            int row = wn*64 + n*16 + lr;
            int off = (row*64 + kk + lk*8) ^ ((row&7)<<3);
            bh[n] = *(const bfrag*)&Bs0[off];
            bl[n] = *(const bfrag*)&Bs1[off];
        }
        #pragma unroll
        for (int m = 0; m < MFR; ++m)
            #pragma unroll
            for (int n = 0; n < 4; ++n){
                acc[m][n] = __builtin_amdgcn_mfma_f32_16x16x32_bf16(ah[m], bh[n], acc[m][n], 0,0,0);
                acc[m][n] = __builtin_amdgcn_mfma_f32_16x16x32_bf16(ah[m], bl[n], acc[m][n], 0,0,0);
                acc[m][n] = __builtin_amdgcn_mfma_f32_16x16x32_bf16(al[m], bh[n], acc[m][n], 0,0,0);
            }
    }
}

// unified K-loop: C((2*MFR*16)x128) += A * B^T on split planes
template<int MFR>
__device__ __forceinline__ void mm_coreT(const ushort* __restrict__ Am, size_t aPl, int aStr,
        const ushort* __restrict__ Bm, size_t bPl, int bStr,
        int i0, int j0, int kLo, int kHi,
        ushort (&As)[2][MFR*2048], ushort (&Bs)[2][8192], f32x4 (&acc)[MFR][4],
        int wm, int wn, int lr, int lk){
    for (int k0 = kLo; k0 < kHi; k0 += 64){
        stage_panelR<MFR*32>(Am,       aStr, i0, k0, As[0]);
        stage_panelR<MFR*32>(Am + aPl, aStr, i0, k0, As[1]);
        stage_panelR<128>(Bm,       bStr, j0, k0, Bs[0]);
        stage_panelR<128>(Bm + bPl, bStr, j0, k0, Bs[1]);
        __syncthreads();
        mfma_block<MFR>(As[0], As[1], Bs[0], Bs[1], acc, wm, wn, lr, lk);
        __syncthreads();
    }
}

// ---------- label bookkeeping (deterministic counting sort) ----------

__global__ __launch_bounds__(256) void k_chunk_hist(const int* __restrict__ labels,
                                                    int* __restrict__ chunkCnt){
    __shared__ int h[8];
    int t = threadIdx.x;
    if (t < 8) h[t] = 0;
    __syncthreads();
    int l = labels[blockIdx.x*CHUNK + t];
    atomicAdd(&h[l], 1);
    __syncthreads();
    if (t < 8) chunkCnt[blockIdx.x*8 + t] = h[t];
}

__global__ void k_scan(const int* __restrict__ chunkCnt, int* __restrict__ cnt,
                       int* __restrict__ offPad, int* __restrict__ base){
    if (threadIdx.x != 0) return;
    int c[8];
    for (int k=0;k<8;k++) c[k]=0;
    for (int ch=0; ch<NCHUNK; ch++)
        for (int k=0;k<8;k++) c[k] += chunkCnt[ch*8+k];
    int off = 0;
    for (int k=0;k<8;k++){
        cnt[k] = c[k];
        offPad[k] = off;
        off += ((c[k] + SEG_ALIGN - 1)/SEG_ALIGN)*SEG_ALIGN;
    }
    offPad[8] = off;
    for (int k=0;k<8;k++){
        int run = offPad[k];
        for (int ch=0; ch<NCHUNK; ch++){
            base[ch*8+k] = run;
            run += chunkCnt[ch*8+k];
        }
    }
}

__global__ void k_place(const int* __restrict__ labels, const int* __restrict__ base,
                        int* __restrict__ perm, int* __restrict__ inv){
    int t = threadIdx.x;
    if (t >= 8) return;
    int ch = blockIdx.x;
    int pos = base[ch*8+t];
    int s = ch*CHUNK;
    for (int i=0;i<CHUNK;i++){
        if (labels[s+i] == t){
            perm[pos] = s+i;
            if (inv) inv[s+i] = pos;
            pos++;
        }
    }
}

// ---------- gather + split + fused per-cluster partial sums ----------

__global__ __launch_bounds__(256) void k_gather2(const float* __restrict__ src,
        const int* __restrict__ perm, const int* __restrict__ offPad,
        const int* __restrict__ cnt, ushort* __restrict__ dstH,
        ushort* __restrict__ dstL, float* __restrict__ psum,
        int* __restrict__ segOf){
    __shared__ int so[9], sc[8];
    __shared__ int pcache[128];
    int t = threadIdx.x;
    if (t < 9) so[t] = offPad[t];
    if (t < 8) sc[t] = cnt[t];
    __syncthreads();
    int bx = blockIdx.x;
    int i0 = bx*128;
    if (t < 128) pcache[t] = (i0 + t < so[8]) ? perm[i0 + t] : 0;
    __syncthreads();
    int k = 0;
    while (k < 7 && i0 >= so[k+1]) k++;
    int n = sc[k], s0 = so[k];
    int ch = t >> 4, px0 = (t & 15)*8;
    int c  = blockIdx.y*16 + ch;
    const float* row = src + (size_t)c*WH;
    float v[8];
    #pragma unroll
    for (int x=0;x<8;x++){
        int i = i0 + px0 + x;
        v[x] = (i - s0 < n) ? row[pcache[px0+x]] : 0.0f;
    }
    float s = 0.0f;
    ushort hv[8], lv[8];
    #pragma unroll
    for (int x=0;x<8;x++){
        s += v[x];
        split2(v[x], hv[x], lv[x]);
    }
    *(uint4*)&dstH[(size_t)c*CAP + i0 + px0] = *(uint4*)hv;
    *(uint4*)&dstL[(size_t)c*CAP + i0 + px0] = *(uint4*)lv;
    #pragma unroll
    for (int d=1; d<16; d<<=1) s += __shfl_xor(s, d, 16);
    if ((t & 15) == 0) psum[(size_t)c*NBX + bx] = s;
    if (t == 0) segOf[bx] = k;
}

template<bool DIV_N>
__global__ __launch_bounds__(256) void k_meanred(const float* __restrict__ psum,
        const int* __restrict__ segOf, const int* __restrict__ cnt,
        float* __restrict__ out){
    int k = blockIdx.x;
    int c = blockIdx.y*256 + threadIdx.x;
    float s = 0.0f;
    for (int bx=0; bx<NBX; bx++)
        if (segOf[bx] == k) s += psum[(size_t)c*NBX + bx];
    out[k*C_DIM + c] = DIV_N ? s/(float)cnt[k] : s;
}

// ---------- transpose plane: [512][CAP] -> [CAP][512] ----------

__global__ __launch_bounds__(256) void k_transpose(const ushort* __restrict__ S,
                                                   ushort* __restrict__ D){
    __shared__ ushort tile[64][72];
    int p = blockIdx.z;
    const ushort* Sp = S + (size_t)p*C_DIM*CAP;
    ushort* Dp = D + (size_t)p*CAP*C_DIM;
    int cb = blockIdx.x*64;
    int rb = blockIdx.y*64;
    int t = threadIdx.x;
    int tr = t >> 3, tc = t & 7;
    #pragma unroll
    for (int i=0;i<2;i++){
        int r = tr + i*32;
        uint4 v = *(const uint4*)&Sp[(size_t)(rb+r)*CAP + cb + tc*8];
        ushort* u = (ushort*)&v;
        #pragma unroll
        for (int j=0;j<8;j++) tile[tc*8+j][r] = u[j];
    }
    __syncthreads();
    #pragma unroll
    for (int i=0;i<2;i++){
        int r = tr + i*32;
        uint4 v;
        ushort* u = (ushort*)&v;
        #pragma unroll
        for (int j=0;j<8;j++) u[j] = tile[r][tc*8+j];
        *(uint4*)&Dp[(size_t)(cb+r)*C_DIM + rb + tc*8] = v;
    }
}

__global__ __launch_bounds__(256) void k_style_mean(const float* __restrict__ scores,
        const int* __restrict__ cntS, const float* __restrict__ ssum,
        float* __restrict__ total, float* __restrict__ smean){
    int t = threadIdx.x;
    __shared__ float tot[8];
    if (t < 8){
        float s = 0.0f;
        for (int j=0;j<8;j++) s += scores[t*8+j]*(float)cntS[j];
        tot[t] = s; total[t] = s;
    }
    __syncthreads();
    for (int idx=t; idx<8*C_DIM; idx+=256){
        int k = idx / C_DIM, c = idx % C_DIM;
        float s = 0.0f;
        for (int j=0;j<8;j++) s += scores[k*8+j]*ssum[j*C_DIM+c];
        smean[idx] = s / tot[k];
    }
}

// ---------- MFMA SYRK: partial S2 = X X^T, triangular tiles, split-K ----------

__global__ __launch_bounds__(256,2) void k_syrk_mfma(
        const ushort* __restrict__ Xc, const ushort* __restrict__ Xs,
        const int* __restrict__ offC, const int* __restrict__ offS,
        float* __restrict__ Pf){
    __shared__ ushort As[2][8192];
    __shared__ ushort Bs[2][8192];
    int wg = xcd_swz(blockIdx.x, NMAT*NSLICE*10);
    int mat = wg / (NSLICE*10);
    int rem = wg % (NSLICE*10);
    int slice = rem / 10, tt = rem % 10;
    int ti, tj;
    if (tt < 4){ ti=0; tj=tt; }
    else if (tt < 7){ ti=1; tj=tt-3; }
    else if (tt < 9){ ti=2; tj=tt-5; }
    else { ti=3; tj=3; }
    const ushort* X = (mat < 8) ? Xc : Xs;
    const int* offP = (mat < 8) ? offC : offS;
    int cl = mat & 7;
    int off = offP[cl], npad = offP[cl+1] - off;
    int i0 = ti*128, j0 = tj*128;
    int L = ((npad + NSLICE*64 - 1)/(NSLICE*64))*64;
    int k_lo = slice*L;
    int k_hi = min(k_lo + L, npad);
    int t = threadIdx.x;
    int lane = t & 63, wave = t >> 6;
    int wm = wave >> 1, wn = wave & 1;
    int lr = lane & 15, lk = lane >> 4;
    f32x4 zero = {0.f,0.f,0.f,0.f};
    f32x4 acc[4][4];
    #pragma unroll
    for (int m=0;m<4;m++)
        #pragma unroll
        for (int n=0;n<4;n++) acc[m][n] = zero;
    mm_coreT<4>(X + off, (size_t)C_DIM*CAP, CAP,
                X + off, (size_t)C_DIM*CAP, CAP,
                i0, j0, k_lo, k_hi, As, Bs, acc, wm, wn, lr, lk);
    float* O = Pf + ((size_t)(slice*16 + mat))*MSZ;
    #pragma unroll
    for (int m=0;m<4;m++)
        #pragma unroll
        for (int n=0;n<4;n++)
            #pragma unroll
            for (int j=0;j<4;j++){
                int gr = i0 + wm*64 + m*16 + lk*4 + j;
                int gc = j0 + wn*64 + n*16 + lr;
                O[(size_t)gr*C_DIM + gc] = acc[m][n][j];
            }
}

// ---------- assemble A (tile-based, coalesced, LDS mirror) -> split planes ----------

__global__ __launch_bounds__(256) void k_assemble(const float* __restrict__ P0,
        const float* __restrict__ scores, const float* __restrict__ total,
        const float* __restrict__ cmean, const float* __restrict__ smean,
        const int* __restrict__ cntC, ushort* __restrict__ bA){
    const size_t S = (size_t)NMAT*MSZ;
    __shared__ ushort tH[64][136];
    __shared__ ushort tL[64][136];
    int mat = blockIdx.y;
    int tt = blockIdx.x;
    int ti, tj;
    if (tt < 4){ ti=0; tj=tt; }
    else if (tt < 7){ ti=1; tj=tt-3; }
    else if (tt < 9){ ti=2; tj=tt-5; }
    else { ti=3; tj=3; }
    int i0 = ti*128, j0 = tj*128;
    int t = threadIdx.x;
    ushort* bm = bA + (size_t)mat*2*MSZ;
    int k = mat - 8;
    float nOrTot = (mat < 8) ? (float)cntC[mat] : total[k];
    float inv_nm1 = 1.0f/(nOrTot - 1.0f);
    const float* mrow = (mat < 8) ? (cmean + mat*C_DIM) : (smean + k*C_DIM);
    for (int h = 0; h < 2; ++h){
        #pragma unroll
        for (int rep = 0; rep < 4; ++rep){
            int lin = rep*2048 + t*8;
            int r = lin >> 7;
            int c = lin & 127;
            int gr = i0 + h*64 + r;
            int gc = j0 + c;
            size_t e = (size_t)gr*C_DIM + gc;
            float s2[8];
            if (mat < 8){
                size_t b = (size_t)mat*MSZ + e;
                #pragma unroll
                for (int x=0;x<8;x++)
                    s2[x] = P0[b+x] + P0[b+S+x] + P0[b+2*S+x] + P0[b+3*S+x];
            } else {
                #pragma unroll
                for (int x=0;x<8;x++) s2[x] = 0.0f;
                #pragma unroll
                for (int jj=0;jj<8;jj++){
                    float sc = scores[k*8+jj];
                    size_t b = (size_t)(8+jj)*MSZ + e;
                    #pragma unroll
                    for (int x=0;x<8;x++)
                        s2[x] += sc*(P0[b+x] + P0[b+S+x] + P0[b+2*S+x] + P0[b+3*S+x]);
                }
            }
            float mi = mrow[gr];
            #pragma unroll
            for (int x=0;x<8;x++){
                float v = (s2[x] - nOrTot*mi*mrow[gc+x])*inv_nm1;
                if (mat < 8 && gr == gc+x) v += EPS_C;
                ushort hh,ll; split2(v,hh,ll);
                bm[e+x] = hh; bm[MSZ+e+x] = ll;
                tH[r][c+x] = hh; tL[r][c+x] = ll;
            }
        }
        if (ti != tj){
            __syncthreads();
            #pragma unroll
            for (int rep = 0; rep < 4; ++rep){
                int lin = rep*2048 + t*8;
                int rr = lin >> 6;
                int cc0 = lin & 63;
                size_t eo = (size_t)(j0+rr)*C_DIM + i0 + h*64 + cc0;
                #pragma unroll
                for (int x=0;x<8;x++){
                    bm[eo+x]     = tH[cc0+x][rr];
                    bm[MSZ+eo+x] = tL[cc0+x][rr];
                }
            }
            __syncthreads();
        }
    }
}

// ---------- A^2 row abs-sums via MFMA (no C write), 64x128 tiles ----------

__global__ __launch_bounds__(256) void k_mm_rowsum(
        const ushort* __restrict__ A, float* __restrict__ rowpart){
    __shared__ ushort As[2][4096];
    __shared__ ushort Bs[2][8192];
    __shared__ float rs[64][2];
    int wg = xcd_swz(blockIdx.x, NMAT*32);
    int mat = wg >> 5, tile = wg & 31;
    int ti = tile >> 2, tj = tile & 3;
    int i0 = ti*64, j0 = tj*128;
    const ushort* Am = A + (size_t)mat*2*MSZ;
    int t = threadIdx.x;
    int lane = t & 63, wave = t >> 6;
    int wm = wave >> 1, wn = wave & 1;
    int lr = lane & 15, lk = lane >> 4;
    f32x4 zero = {0.f,0.f,0.f,0.f};
    f32x4 acc[2][4];
    #pragma unroll
    for (int m=0;m<2;m++)
        #pragma unroll
        for (int n=0;n<4;n++) acc[m][n] = zero;
    mm_coreT<2>(Am, MSZ, C_DIM, Am, MSZ, C_DIM, i0, j0, 0, C_DIM,
                As, Bs, acc, wm, wn, lr, lk);
    #pragma unroll
    for (int m=0;m<2;m++)
        #pragma unroll
        for (int j=0;j<4;j++){
            float s = 0.0f;
            #pragma unroll
            for (int n=0;n<4;n++) s += fabsf(acc[m][n][j]);
            #pragma unroll
            for (int d=1; d<16; d<<=1) s += __shfl_xor(s, d);
            if (lr == 0) rs[wm*32 + m*16 + lk*4 + j][wn] = s;
        }
    __syncthreads();
    if (t < 64)
        rowpart[((size_t)mat*4 + tj)*512 + i0 + t] = rs[t][0] + rs[t][1];
}

__global__ __launch_bounds__(256) void k_tmax(const float* __restrict__ rowpart,
                                              float* __restrict__ tvals){
    int mat = blockIdx.x, t = threadIdx.x;
    const float* rp = rowpart + (size_t)mat*4*512;
    float mx = 0.0f;
    for (int r = t; r < 512; r += 256){
        float s = rp[r] + rp[512+r] + rp[1024+r] + rp[1536+r];
        mx = fmaxf(mx, s);
    }
    __shared__ float red[256];
    red[t] = mx; __syncthreads();
    for (int s=128; s>0; s>>=1){ if (t<s) red[t]=fmaxf(red[t],red[t+s]); __syncthreads(); }
    if (t == 0) tvals[mat] = sqrtf(red[0]);
}

// ---------- Y0 = A/t, P0 = q(Y0) = 1.5I - 0.5*Y0 (iteration-0 collapse) ----------

__global__ __launch_bounds__(256) void k_split_initP(const ushort* __restrict__ bA,
        const float* __restrict__ tvals, ushort* __restrict__ Y,
        ushort* __restrict__ P){
    int mat = blockIdx.y;
    int e = blockIdx.x*256 + threadIdx.x;
    size_t base = (size_t)mat*2*MSZ;
    float inv = 1.0f / tvals[mat];
    float a = (bf2f(bA[base+e]) + bf2f(bA[base+MSZ+e])) * inv;
    ushort h,l; split2(a,h,l);
    Y[base + e] = h;
    Y[base + MSZ + e] = l;
    int i = e >> 9, j = e & 511;
    float p = ((i==j)?1.5f:0.0f) - 0.5f*a;
    split2(p,h,l);
    P[base + e] = h;
    P[base + MSZ + e] = l;
}

// ---------- generic 64x128-tile batched mm on split planes ----------
// EPI 0: split write; EPI 1: q(X) then split write; EPI 3: fp32 T + split M(ascale,diag)

template<int EPI>
__global__ __launch_bounds__(256) void k_mm_ns64(
        const ushort* __restrict__ A, const ushort* __restrict__ B,
        ushort* __restrict__ Co, float* __restrict__ Cf,
        const float* __restrict__ tvals, int nmat){
    __shared__ ushort As[2][4096];
    __shared__ ushort Bs[2][8192];
    int wg = xcd_swz(blockIdx.x, nmat*32);
    int mat = wg >> 5, tile = wg & 31;
    int i0 = (tile>>2)*64, j0 = (tile&3)*128;
    const ushort* Am = A + (size_t)mat*2*MSZ;
    const ushort* Bm = B + (size_t)mat*2*MSZ;
    int t = threadIdx.x;
    int lane = t & 63, wave = t >> 6;
    int wm = wave >> 1, wn = wave & 1;
    int lr = lane & 15, lk = lane >> 4;
    f32x4 zero = {0.f,0.f,0.f,0.f};
    f32x4 acc[2][4];
    #pragma unroll
    for (int m=0;m<2;m++)
        #pragma unroll
        for (int n=0;n<4;n++) acc[m][n] = zero;
    mm_coreT<2>(Am, MSZ, C_DIM, Bm, MSZ, C_DIM, i0, j0, 0, C_DIM,
                As, Bs, acc, wm, wn, lr, lk);
    if (EPI == 3){
        float* Cm = Cf + (size_t)mat*MSZ;
        ushort* Mh = Co + (size_t)mat*2*MSZ;
        ushort* Ml = Mh + MSZ;
        float ascale = ALPHA_C * sqrtf(tvals[8+mat]/tvals[mat]);
        #pragma unroll
        for (int m=0;m<2;m++)
            #pragma unroll
            for (int n=0;n<4;n++)
                #pragma unroll
                for (int j=0;j<4;j++){
                    int gr = i0 + wm*32 + m*16 + lk*4 + j;
                    int gc = j0 + wn*64 + n*16 + lr;
                    float v = acc[m][n][j];
                    size_t idx = (size_t)gr*C_DIM + gc;
                    Cm[idx] = v;
                    float mv = ascale*v + ((gr==gc)?(1.0f-ALPHA_C):0.0f);
                    ushort h,l; split2(mv,h,l);
                    Mh[idx] = h; Ml[idx] = l;
                }
    } else {
        ushort* Ch = Co + (size_t)mat*2*MSZ;
        ushort* Cl = Ch + MSZ;
        #pragma unroll
        for (int m=0;m<2;m++)
            #pragma unroll
            for (int n=0;n<4;n++)
                #pragma unroll
                for (int j=0;j<4;j++){
                    int gr = i0 + wm*32 + m*16 + lk*4 + j;
                    int gc = j0 + wn*64 + n*16 + lr;
                    float v = acc[m][n][j];
                    if (EPI == 1) v = ((gr==gc)?1.5f:0.0f) - 0.5f*v;
                    ushort h,l; split2(v,h,l);
                    size_t idx = (size_t)gr*C_DIM + gc;
                    Ch[idx] = h;
                    Cl[idx] = l;
                }
    }
}

// ---------- merged NS stage 2 (128x128 tiles, full chip): fy = Y*qP, fz = qP*Z ----------

__global__ __launch_bounds__(256,2) void k_mm_ns2(
        const ushort* __restrict__ Y, const ushort* __restrict__ P,
        const ushort* __restrict__ Z, ushort* __restrict__ fy,
        ushort* __restrict__ fz){
    __shared__ ushort As[2][8192];
    __shared__ ushort Bs[2][8192];
    int wg = xcd_swz(blockIdx.x, NMAT*32);
    int mat = wg >> 5;
    int r = wg & 31;
    int op = r >> 4, tile = r & 15;
    int i0 = (tile>>2)*128, j0 = (tile&3)*128;
    const ushort* Am = (op ? P : Y) + (size_t)mat*2*MSZ;
    const ushort* Bm = (op ? Z : P) + (size_t)mat*2*MSZ;
    ushort* Ch = (op ? fz : fy) + (size_t)mat*2*MSZ;
    ushort* Cl = Ch + MSZ;
    int t = threadIdx.x;
    int lane = t & 63, wave = t >> 6;
    int wm = wave >> 1, wn = wave & 1;
    int lr = lane & 15, lk = lane >> 4;
    f32x4 zero = {0.f,0.f,0.f,0.f};
    f32x4 acc[4][4];
    #pragma unroll
    for (int m=0;m<4;m++)
        #pragma unroll
        for (int n=0;n<4;n++) acc[m][n] = zero;
    mm_coreT<4>(Am, MSZ, C_DIM, Bm, MSZ, C_DIM, i0, j0, 0, C_DIM,
                As, Bs, acc, wm, wn, lr, lk);
    #pragma unroll
    for (int m=0;m<4;m++)
        #pragma unroll
        for (int n=0;n<4;n++)
            #pragma unroll
            for (int j=0;j<4;j++){
                int gr = i0 + wm*64 + m*16 + lk*4 + j;
                int gc = j0 + wn*64 + n*16 + lr;
                ushort h,l; split2(acc[m][n][j],h,l);
                size_t idx = (size_t)gr*C_DIM + gc;
                Ch[idx] = h;
                Cl[idx] = l;
            }
}

// ---------- last NS stage 2 (64x128 tiles): only consumed halves ----------

__global__ __launch_bounds__(256) void k_mm_ns2_last(
        const ushort* __restrict__ Y, const ushort* __restrict__ P,
        const ushort* __restrict__ Z, ushort* __restrict__ fy,
        ushort* __restrict__ fz){
    __shared__ ushort As[2][4096];
    __shared__ ushort Bs[2][8192];
    int wg = xcd_swz(blockIdx.x, NMAT*32);
    int mat = wg >> 5, tile = wg & 31;
    int op = (mat < 8) ? 1 : 0;         // content: fz = P*Z ; style: fy = Y*P
    int i0 = (tile>>2)*64, j0 = (tile&3)*128;
    const ushort* Am = (op ? P : Y) + (size_t)mat*2*MSZ;
    const ushort* Bm = (op ? Z : P) + (size_t)mat*2*MSZ;
    ushort* Ch = (op ? fz : fy) + (size_t)mat*2*MSZ;
    ushort* Cl = Ch + MSZ;
    int t = threadIdx.x;
    int lane = t & 63, wave = t >> 6;
    int wm = wave >> 1, wn = wave & 1;
    int lr = lane & 15, lk = lane >> 4;
    f32x4 zero = {0.f,0.f,0.f,0.f};
    f32x4 acc[2][4];
    #pragma unroll
    for (int m=0;m<2;m++)
        #pragma unroll
        for (int n=0;n<4;n++) acc[m][n] = zero;
    mm_coreT<2>(Am, MSZ, C_DIM, Bm, MSZ, C_DIM, i0, j0, 0, C_DIM,
                As, Bs, acc, wm, wn, lr, lk);
    #pragma unroll
    for (int m=0;m<2;m++)
        #pragma unroll
        for (int n=0;n<4;n++)
            #pragma unroll
            for (int j=0;j<4;j++){
                int gr = i0 + wm*32 + m*16 + lk*4 + j;
                int gc = j0 + wn*64 + n*16 + lr;
                ushort h,l; split2(acc[m][n][j],h,l);
                size_t idx = (size_t)gr*C_DIM + gc;
                Ch[idx] = h;
                Cl[idx] = l;
            }
}

// ---------- bias vector: vvec = alpha*smean - ascale*(T cmean) ----------

__global__ __launch_bounds__(256) void k_buildV(const float* __restrict__ T,
        const float* __restrict__ tvals, const float* __restrict__ cmean,
        const float* __restrict__ smean, float* __restrict__ vvec){
    __shared__ float cm[512];
    int k = blockIdx.x, t = threadIdx.x;
    cm[t] = cmean[k*C_DIM + t];
    cm[t+256] = cmean[k*C_DIM + t + 256];
    __syncthreads();
    float scale = ALPHA_C * sqrtf(tvals[8+k]/tvals[k]);
    int c = blockIdx.y*256 + t;
    const float* row = T + (size_t)k*MSZ + (size_t)c*C_DIM;
    float s = 0.0f;
    for (int d=0; d<C_DIM; d++) s = fmaf(row[d], cm[d], s);
    vvec[k*C_DIM + c] = ALPHA_C*smean[k*C_DIM + c] - scale*s;
}

// ---------- MFMA apply: Sg = M*Xc + v in gathered order (coalesced) ----------

__global__ __launch_bounds__(256,2) void k_apply_mfma(
        const ushort* __restrict__ Msp, const ushort* __restrict__ XT,
        const float* __restrict__ vvec, const int* __restrict__ offPad,
        float* __restrict__ Sg){
    __shared__ ushort As[2][8192];
    __shared__ ushort Bs[2][8192];
    __shared__ int so[9];
    int t = threadIdx.x;
    if (t < 9) so[t] = offPad[t];
    __syncthreads();
    int wg = xcd_swz(blockIdx.x, (CAP/128)*4);
    int j0 = (wg>>2)*128;
    int i0 = (wg&3)*128;
    if (j0 >= so[8]) return;
    int cl = 0;
    while (cl < 7 && j0 >= so[cl+1]) cl++;
    const ushort* Am = Msp + (size_t)cl*2*MSZ;
    int lane = t & 63, wave = t >> 6;
    int wm = wave >> 1, wn = wave & 1;
    int lr = lane & 15, lk = lane >> 4;
    f32x4 zero = {0.f,0.f,0.f,0.f};
    f32x4 acc[4][4];
    #pragma unroll
    for (int m=0;m<4;m++)
        #pragma unroll
        for (int n=0;n<4;n++) acc[m][n] = zero;
    mm_coreT<4>(Am, MSZ, C_DIM, XT, (size_t)CAP*C_DIM, C_DIM, i0, j0, 0, C_DIM,
                As, Bs, acc, wm, wn, lr, lk);
    #pragma unroll
    for (int m=0;m<4;m++)
        #pragma unroll
        for (int nn=0;nn<4;nn++)
            #pragma unroll
            for (int j=0;j<4;j++){
                int gr = i0 + wm*64 + m*16 + lk*4 + j;
                int gc = j0 + wn*64 + nn*16 + lr;
                Sg[(size_t)gr*CAP + gc] = acc[m][nn][j] + vvec[cl*C_DIM + gr];
            }
}

// ---------- scatter: out[c][p] = Sg[c][ginv[p]] (coalesced writes) ----------

__global__ __launch_bounds__(256) void k_scatter(const float* __restrict__ Sg,
        const int* __restrict__ ginv, float* __restrict__ out){
    size_t idx = (size_t)blockIdx.x*256 + threadIdx.x;
    int p = (int)(idx & (WH-1));
    int c = (int)(idx >> 14);
    out[idx] = Sg[(size_t)c*CAP + ginv[p]];
}

// ---------- host ----------

extern "C" void kernel_launch(void* const* d_in, const int* in_sizes, int n_in,
                              void* d_out, int out_size, void* d_ws, size_t ws_size,
                              hipStream_t stream) {
    (void)in_sizes; (void)n_in;
    const float* cf     = (const float*)d_in[0];
    const float* sf     = (const float*)d_in[1];
    const float* scores = (const float*)d_in[2];
    const int*   cl     = (const int*)d_in[3];
    const int*   sl     = (const int*)d_in[4];
    float* out = (float*)d_out;
    float* ws  = (float*)d_ws;

    size_t o = 0;
    ushort* XcH = (ushort*)(ws + o);
    float*  Sg  = ws + o;       o += (size_t)C_DIM*CAP;
    ushort* XcL = XcH + (size_t)C_DIM*CAP;
    ushort* XsH = (ushort*)(ws + o); o += (size_t)C_DIM*CAP;
    float* S4  = ws + o; o += (size_t)NMAT*MSZ;
    float* NS0 = ws + o; o += (size_t)4*NMAT*MSZ;
    float* cmean = ws + o; o += 8*C_DIM;
    float* ssum  = ws + o; o += 8*C_DIM;
    float* smean = ws + o; o += 8*C_DIM;
    float* vvec  = ws + o; o += 8*C_DIM;
    float* tvals = ws + o; o += 16;
    float* rowpart = ws + o; o += (size_t)NMAT*4*512;
    float* total = ws + o; o += 8;
    float* psumC = ws + o; o += (size_t)C_DIM*NBX;
    float* psumS = ws + o; o += (size_t)C_DIM*NBX;
    int* ip = (int*)(ws + o);
    int* permC    = ip; ip += CAP;
    int* permCinv = ip; ip += CAP;
    int* permS    = ip; ip += CAP;
    int* segOfC = ip; ip += NBX;
    int* segOfS = ip; ip += NBX;
    int* cntC  = ip; ip += 8;
    int* cntS  = ip; ip += 8;
    int* offC  = ip; ip += 9;
    int* offS  = ip; ip += 9;
    int* chC   = ip; ip += NCHUNK*8;
    int* chS   = ip; ip += NCHUNK*8;
    int* baseC = ip; ip += NCHUNK*8;
    int* baseS = ip; ip += NCHUNK*8;
    size_t need_bytes = (size_t)((char*)ip - (char*)d_ws);
    if (ws_size < need_bytes){
        hipMemcpyAsync(d_out, (const void*)cf, (size_t)out_size*sizeof(float),
                       hipMemcpyDeviceToDevice, stream);
        return;
    }
    float* Pf = NS0;
    ushort* s0 = (ushort*)(NS0 + 0*(size_t)NMAT*MSZ);
    ushort* s1 = (ushort*)(NS0 + 1*(size_t)NMAT*MSZ);
    ushort* s2 = (ushort*)(NS0 + 2*(size_t)NMAT*MSZ);
    ushort* s3 = (ushort*)(NS0 + 3*(size_t)NMAT*MSZ);
    ushort* s4 = (ushort*)S4;

    k_chunk_hist<<<NCHUNK,256,0,stream>>>(cl, chC);
    k_chunk_hist<<<NCHUNK,256,0,stream>>>(sl, chS);
    k_scan<<<1,64,0,stream>>>(chC, cntC, offC, baseC);
    k_scan<<<1,64,0,stream>>>(chS, cntS, offS, baseS);
    k_place<<<NCHUNK,64,0,stream>>>(cl, baseC, permC, permCinv);
    k_place<<<NCHUNK,64,0,stream>>>(sl, baseS, permS, nullptr);

    dim3 gg(NBX, C_DIM/16);
    k_gather2<<<gg,256,0,stream>>>(cf, permC, offC, cntC, XcH, XcL, psumC, segOfC);
    k_gather2<<<gg,256,0,stream>>>(sf, permS, offS, cntS,
                                   XsH, XsH + (size_t)C_DIM*CAP, psumS, segOfS);

    k_meanred<true><<<dim3(8,2),256,0,stream>>>(psumC, segOfC, cntC, cmean);
    k_meanred<false><<<dim3(8,2),256,0,stream>>>(psumS, segOfS, cntS, ssum);
    k_style_mean<<<1,256,0,stream>>>(scores, cntS, ssum, total, smean);

    k_syrk_mfma<<<NMAT*NSLICE*10,256,0,stream>>>(XcH, XsH, offC, offS, Pf);

    k_transpose<<<dim3(CAP/64, C_DIM/64, 2),256,0,stream>>>(XcH, XsH);
    ushort* XT = XsH;

    ushort* bA = s4;
    k_assemble<<<dim3(10,16),256,0,stream>>>(Pf, scores, total, cmean, smean, cntC, bA);

    k_mm_rowsum<<<NMAT*32,256,0,stream>>>(bA, rowpart);
    k_tmax<<<NMAT,256,0,stream>>>(rowpart, tvals);

    // iteration 0 (collapsed): Y0=A/t, P0=q(Y0) elementwise; Y1=Y0*P0; Z1=P0 (alias)
    k_split_initP<<<dim3(MSZ/256,NMAT),256,0,stream>>>(bA, tvals, s0, s1);
    k_mm_ns64<0><<<NMAT*32,256,0,stream>>>(s0, s1, s2, nullptr, nullptr, NMAT);

    ushort* bY = s2;  ushort* bZ = s1;  ushort* bP = s3;
    ushort* fy = s4;  ushort* fz = s0;   // s4 = bA slot (consumed), s0 = Y0 (consumed)
    for (int it=0; it<NIT-1; ++it){
        k_mm_ns64<1><<<NMAT*32,256,0,stream>>>(bZ, bY, bP, nullptr, nullptr, NMAT); // P=q(Z*Y)
        if (it < NIT-2)
            k_mm_ns2<<<NMAT*32,256,0,stream>>>(bY, bP, bZ, fy, fz);
        else
            k_mm_ns2_last<<<NMAT*32,256,0,stream>>>(bY, bP, bZ, fy, fz);
        ushort* t1;
        t1 = bY; bY = fy; fy = t1;
        t1 = bZ; bZ = fz; fz = t1;
    }
    // T[k] = Y_style[8+k] * Z_content[k]: fp32 T + split M in one pass
    float* Tf = (float*)fy;
    ushort* Msp = fz;
    k_mm_ns64<3><<<8*32,256,0,stream>>>(bY + (size_t)8*2*MSZ, bZ, Msp, Tf, tvals, 8);

    k_buildV<<<dim3(8,2),256,0,stream>>>(Tf, tvals, cmean, smean, vvec);

    k_apply_mfma<<<(CAP/128)*4,256,0,stream>>>(Msp, XT, vvec, offC, Sg);
    k_scatter<<<(C_DIM*WH)/256,256,0,stream>>>(Sg, permCinv, out);
}

// Round 9
// 650.107 us; speedup vs baseline: 1.8813x; 1.1339x over previous
//
#include <hip/hip_runtime.h>
#include <math.h>

#define C_DIM 512
#define WH    16384
#define CAP   17408      // 16384 + 8*128 worst-case padding
#define NBX   136        // CAP/128
#define SEG_ALIGN 128
#define NCHUNK 64
#define CHUNK  256
#define NMAT 16
#define NSLICE 4
#define MSZ  (C_DIM*C_DIM)
#define ALPHA_C 0.8f
#define EPS_C   1e-6f
#define NIT 8            // total q-applications: 1 collapsed + 7 full

typedef __attribute__((ext_vector_type(8))) __bf16 bfrag;
typedef __attribute__((ext_vector_type(4))) float f32x4;

__device__ inline float bf2f(ushort h){ return __uint_as_float(((unsigned)h)<<16); }
__device__ inline void split2(float v, ushort& h, ushort& l){
    unsigned u = __float_as_uint(v);
    h = (ushort)(u >> 16);
    float r = v - __uint_as_float(u & 0xffff0000u);
    l = (ushort)(__float_as_uint(r) >> 16);
}

__device__ __forceinline__ int xcd_swz(int bid, int nwg){
    int c = nwg >> 3;
    return (bid & 7)*c + (bid >> 3);
}

__device__ __forceinline__ void gload16(const void* g, void* l){
    __builtin_amdgcn_global_load_lds(
        (const __attribute__((address_space(1))) unsigned int*)g,
        (__attribute__((address_space(3))) unsigned int*)l, 16, 0, 0);
}

// stage one R x 64 bf16 panel (R = 64 or 128): LDS linear, source pre-swizzled
template<int R>
__device__ __forceinline__ void stage_panelR(const ushort* __restrict__ src,
        int stride, int i0, int k0, ushort* lds){
    int t = threadIdx.x;
    #pragma unroll
    for (int i = 0; i < R/32; ++i){
        int slot = t + i*256;
        int row = slot >> 3, c8 = slot & 7;
        const ushort* g = src + (size_t)(i0+row)*stride + k0 + ((c8 ^ (row&7))<<3);
        gload16((const void*)g, (void*)&lds[(size_t)(i*256 + (t & 192))*8]);
    }
}

// MFMA inner block: (2*MFR*16) x 128 tile, K=64 step, split-3 products
template<int MFR>
__device__ __forceinline__ void mfma_block(const ushort* As0, const ushort* As1,
        const ushort* Bs0, const ushort* Bs1, f32x4 (&acc)[MFR][4],
        int wm, int wn, int lr, int lk){
    #pragma unroll
    for (int kk = 0; kk < 64; kk += 32){
        bfrag ah[MFR], al[MFR], bh[4], bl[4];
        #pragma unroll
        for (int m = 0; m < MFR; ++m){
            int row = wm*(MFR*16) + m*16 + lr;
            int off = (row*64 + kk + lk*8) ^ ((row&7)<<3);
            ah[m] = *(const bfrag*)&As0[off];
            al[m] = *(const bfrag*)&As1[off];
        }
        #pragma unroll
        for (int n = 0; n < 4; ++n){
            int row = wn*64 + n*16 + lr;
            int off = (row*64 + kk + lk*8) ^ ((row&7)<<3);
            bh[n] = *(const bfrag*)&Bs0[off];
            bl[n] = *(const bfrag*)&Bs1[off];
        }
        #pragma unroll
        for (int m = 0; m < MFR; ++m)
            #pragma unroll
            for (int n = 0; n < 4; ++n){
                acc[m][n] = __builtin_amdgcn_mfma_f32_16x16x32_bf16(ah[m], bh[n], acc[m][n], 0,0,0);
                acc[m][n] = __builtin_amdgcn_mfma_f32_16x16x32_bf16(ah[m], bl[n], acc[m][n], 0,0,0);
                acc[m][n] = __builtin_amdgcn_mfma_f32_16x16x32_bf16(al[m], bh[n], acc[m][n], 0,0,0);
            }
    }
}

// unified K-loop: C((2*MFR*16)x128) += A * B^T on split planes
template<int MFR>
__device__ __forceinline__ void mm_coreT(const ushort* __restrict__ Am, size_t aPl, int aStr,
        const ushort* __restrict__ Bm, size_t bPl, int bStr,
        int i0, int j0, int kLo, int kHi,
        ushort (&As)[2][MFR*2048], ushort (&Bs)[2][8192], f32x4 (&acc)[MFR][4],
        int wm, int wn, int lr, int lk){
    for (int k0 = kLo; k0 < kHi; k0 += 64){
        stage_panelR<MFR*32>(Am,       aStr, i0, k0, As[0]);
        stage_panelR<MFR*32>(Am + aPl, aStr, i0, k0, As[1]);
        stage_panelR<128>(Bm,       bStr, j0, k0, Bs[0]);
        stage_panelR<128>(Bm + bPl, bStr, j0, k0, Bs[1]);
        __syncthreads();
        mfma_block<MFR>(As[0], As[1], Bs[0], Bs[1], acc, wm, wn, lr, lk);
        __syncthreads();
    }
}

// ---------- label bookkeeping (deterministic counting sort), content+style merged ----------

__global__ __launch_bounds__(256) void k_chunk_hist(const int* __restrict__ lab0,
        const int* __restrict__ lab1, int* __restrict__ ch0, int* __restrict__ ch1){
    __shared__ int h[8];
    int t = threadIdx.x;
    const int* labels = blockIdx.y ? lab1 : lab0;
    int* chunkCnt = blockIdx.y ? ch1 : ch0;
    if (t < 8) h[t] = 0;
    __syncthreads();
    int l = labels[blockIdx.x*CHUNK + t];
    atomicAdd(&h[l], 1);
    __syncthreads();
    if (t < 8) chunkCnt[blockIdx.x*8 + t] = h[t];
}

__global__ void k_scan(const int* __restrict__ ch0, const int* __restrict__ ch1,
                       int* __restrict__ cnt0, int* __restrict__ cnt1,
                       int* __restrict__ off0, int* __restrict__ off1,
                       int* __restrict__ base0, int* __restrict__ base1){
    int which = threadIdx.x;
    if (which >= 2) return;
    const int* chunkCnt = which ? ch1 : ch0;
    int* cnt = which ? cnt1 : cnt0;
    int* offPad = which ? off1 : off0;
    int* base = which ? base1 : base0;
    int c[8];
    for (int k=0;k<8;k++) c[k]=0;
    for (int ch=0; ch<NCHUNK; ch++)
        for (int k=0;k<8;k++) c[k] += chunkCnt[ch*8+k];
    int off = 0;
    for (int k=0;k<8;k++){
        cnt[k] = c[k];
        offPad[k] = off;
        off += ((c[k] + SEG_ALIGN - 1)/SEG_ALIGN)*SEG_ALIGN;
    }
    offPad[8] = off;
    for (int k=0;k<8;k++){
        int run = offPad[k];
        for (int ch=0; ch<NCHUNK; ch++){
            base[ch*8+k] = run;
            run += chunkCnt[ch*8+k];
        }
    }
}

__global__ void k_place(const int* __restrict__ lab0, const int* __restrict__ lab1,
        const int* __restrict__ base0, const int* __restrict__ base1,
        int* __restrict__ perm0, int* __restrict__ perm1, int* __restrict__ inv0){
    int t = threadIdx.x;
    if (t >= 8) return;
    const int* labels = blockIdx.y ? lab1 : lab0;
    const int* base = blockIdx.y ? base1 : base0;
    int* perm = blockIdx.y ? perm1 : perm0;
    int* inv = blockIdx.y ? nullptr : inv0;
    int ch = blockIdx.x;
    int pos = base[ch*8+t];
    int s = ch*CHUNK;
    for (int i=0;i<CHUNK;i++){
        if (labels[s+i] == t){
            perm[pos] = s+i;
            if (inv) inv[s+i] = pos;
            pos++;
        }
    }
}

// ---------- gather + split + fused per-cluster partial sums (content & style via z) ----------

__global__ __launch_bounds__(256) void k_gather2(const float* __restrict__ src0,
        const float* __restrict__ src1,
        const int* __restrict__ perm0, const int* __restrict__ perm1,
        const int* __restrict__ off0, const int* __restrict__ off1,
        const int* __restrict__ cnt0, const int* __restrict__ cnt1,
        ushort* __restrict__ dH0, ushort* __restrict__ dL0,
        ushort* __restrict__ dH1, ushort* __restrict__ dL1,
        float* __restrict__ ps0, float* __restrict__ ps1,
        int* __restrict__ sg0, int* __restrict__ sg1){
    int z = blockIdx.z;
    const float* src = z ? src1 : src0;
    const int* perm = z ? perm1 : perm0;
    const int* offPad = z ? off1 : off0;
    const int* cnt = z ? cnt1 : cnt0;
    ushort* dstH = z ? dH1 : dH0;
    ushort* dstL = z ? dL1 : dL0;
    float* psum = z ? ps1 : ps0;
    int* segOf = z ? sg1 : sg0;
    __shared__ int so[9], sc[8];
    __shared__ int pcache[128];
    int t = threadIdx.x;
    if (t < 9) so[t] = offPad[t];
    if (t < 8) sc[t] = cnt[t];
    __syncthreads();
    int bx = blockIdx.x;
    int i0 = bx*128;
    if (t < 128) pcache[t] = (i0 + t < so[8]) ? perm[i0 + t] : 0;
    __syncthreads();
    int k = 0;
    while (k < 7 && i0 >= so[k+1]) k++;
    int n = sc[k], s0 = so[k];
    int ch = t >> 4, px0 = (t & 15)*8;
    int c  = blockIdx.y*16 + ch;
    const float* row = src + (size_t)c*WH;
    float v[8];
    #pragma unroll
    for (int x=0;x<8;x++){
        int i = i0 + px0 + x;
        v[x] = (i - s0 < n) ? row[pcache[px0+x]] : 0.0f;
    }
    float s = 0.0f;
    ushort hv[8], lv[8];
    #pragma unroll
    for (int x=0;x<8;x++){
        s += v[x];
        split2(v[x], hv[x], lv[x]);
    }
    *(uint4*)&dstH[(size_t)c*CAP + i0 + px0] = *(uint4*)hv;
    *(uint4*)&dstL[(size_t)c*CAP + i0 + px0] = *(uint4*)lv;
    #pragma unroll
    for (int d=1; d<16; d<<=1) s += __shfl_xor(s, d, 16);
    if ((t & 15) == 0) psum[(size_t)c*NBX + bx] = s;
    if (t == 0) segOf[bx] = k;
}

// ---------- reduce partials -> per-cluster sums/means (z: 0=content mean, 1=style sum) ----------

__global__ __launch_bounds__(256) void k_meanred(const float* __restrict__ ps0,
        const float* __restrict__ ps1, const int* __restrict__ sg0,
        const int* __restrict__ sg1, const int* __restrict__ cnt0,
        float* __restrict__ out0, float* __restrict__ out1){
    int z = blockIdx.z;
    const float* psum = z ? ps1 : ps0;
    const int* segOf = z ? sg1 : sg0;
    float* out = z ? out1 : out0;
    int k = blockIdx.x;
    int c = blockIdx.y*256 + threadIdx.x;
    float s = 0.0f;
    for (int bx=0; bx<NBX; bx++)
        if (segOf[bx] == k) s += psum[(size_t)c*NBX + bx];
    out[k*C_DIM + c] = z ? s : s/(float)cnt0[k];
}

// ---------- transpose plane: [512][CAP] -> [CAP][512] ----------

__global__ __launch_bounds__(256) void k_transpose(const ushort* __restrict__ S,
                                                   ushort* __restrict__ D){
    __shared__ ushort tile[64][72];
    int p = blockIdx.z;
    const ushort* Sp = S + (size_t)p*C_DIM*CAP;
    ushort* Dp = D + (size_t)p*CAP*C_DIM;
    int cb = blockIdx.x*64;
    int rb = blockIdx.y*64;
    int t = threadIdx.x;
    int tr = t >> 3, tc = t & 7;
    #pragma unroll
    for (int i=0;i<2;i++){
        int r = tr + i*32;
        uint4 v = *(const uint4*)&Sp[(size_t)(rb+r)*CAP + cb + tc*8];
        ushort* u = (ushort*)&v;
        #pragma unroll
        for (int j=0;j<8;j++) tile[tc*8+j][r] = u[j];
    }
    __syncthreads();
    #pragma unroll
    for (int i=0;i<2;i++){
        int r = tr + i*32;
        uint4 v;
        ushort* u = (ushort*)&v;
        #pragma unroll
        for (int j=0;j<8;j++) u[j] = tile[r][tc*8+j];
        *(uint4*)&Dp[(size_t)(cb+r)*C_DIM + rb + tc*8] = v;
    }
}

__global__ __launch_bounds__(256) void k_style_mean(const float* __restrict__ scores,
        const int* __restrict__ cntS, const float* __restrict__ ssum,
        float* __restrict__ total, float* __restrict__ smean){
    int t = threadIdx.x;
    __shared__ float tot[8];
    if (t < 8){
        float s = 0.0f;
        for (int j=0;j<8;j++) s += scores[t*8+j]*(float)cntS[j];
        tot[t] = s; total[t] = s;
    }
    __syncthreads();
    for (int idx=t; idx<8*C_DIM; idx+=256){
        int k = idx / C_DIM, c = idx % C_DIM;
        float s = 0.0f;
        for (int j=0;j<8;j++) s += scores[k*8+j]*ssum[j*C_DIM+c];
        smean[idx] = s / tot[k];
    }
}

// ---------- MFMA SYRK: partial S2 = X X^T, triangular tiles, split-K ----------

__global__ __launch_bounds__(256,2) void k_syrk_mfma(
        const ushort* __restrict__ Xc, const ushort* __restrict__ Xs,
        const int* __restrict__ offC, const int* __restrict__ offS,
        float* __restrict__ Pf){
    __shared__ ushort As[2][8192];
    __shared__ ushort Bs[2][8192];
    int wg = xcd_swz(blockIdx.x, NMAT*NSLICE*10);
    int mat = wg / (NSLICE*10);
    int rem = wg % (NSLICE*10);
    int slice = rem / 10, tt = rem % 10;
    int ti, tj;
    if (tt < 4){ ti=0; tj=tt; }
    else if (tt < 7){ ti=1; tj=tt-3; }
    else if (tt < 9){ ti=2; tj=tt-5; }
    else { ti=3; tj=3; }
    const ushort* X = (mat < 8) ? Xc : Xs;
    const int* offP = (mat < 8) ? offC : offS;
    int cl = mat & 7;
    int off = offP[cl], npad = offP[cl+1] - off;
    int i0 = ti*128, j0 = tj*128;
    int L = ((npad + NSLICE*64 - 1)/(NSLICE*64))*64;
    int k_lo = slice*L;
    int k_hi = min(k_lo + L, npad);
    int t = threadIdx.x;
    int lane = t & 63, wave = t >> 6;
    int wm = wave >> 1, wn = wave & 1;
    int lr = lane & 15, lk = lane >> 4;
    f32x4 zero = {0.f,0.f,0.f,0.f};
    f32x4 acc[4][4];
    #pragma unroll
    for (int m=0;m<4;m++)
        #pragma unroll
        for (int n=0;n<4;n++) acc[m][n] = zero;
    mm_coreT<4>(X + off, (size_t)C_DIM*CAP, CAP,
                X + off, (size_t)C_DIM*CAP, CAP,
                i0, j0, k_lo, k_hi, As, Bs, acc, wm, wn, lr, lk);
    float* O = Pf + ((size_t)(slice*16 + mat))*MSZ;
    #pragma unroll
    for (int m=0;m<4;m++)
        #pragma unroll
        for (int n=0;n<4;n++)
            #pragma unroll
            for (int j=0;j<4;j++){
                int gr = i0 + wm*64 + m*16 + lk*4 + j;
                int gc = j0 + wn*64 + n*16 + lr;
                O[(size_t)gr*C_DIM + gc] = acc[m][n][j];
            }
}

// ---------- assemble A (tile-based, coalesced, LDS mirror) -> split planes ----------

__global__ __launch_bounds__(256) void k_assemble(const float* __restrict__ P0,
        const float* __restrict__ scores, const float* __restrict__ total,
        const float* __restrict__ cmean, const float* __restrict__ smean,
        const int* __restrict__ cntC, ushort* __restrict__ bA){
    const size_t S = (size_t)NMAT*MSZ;
    __shared__ ushort tH[64][136];
    __shared__ ushort tL[64][136];
    int mat = blockIdx.y;
    int tt = blockIdx.x;
    int ti, tj;
    if (tt < 4){ ti=0; tj=tt; }
    else if (tt < 7){ ti=1; tj=tt-3; }
    else if (tt < 9){ ti=2; tj=tt-5; }
    else { ti=3; tj=3; }
    int i0 = ti*128, j0 = tj*128;
    int t = threadIdx.x;
    ushort* bm = bA + (size_t)mat*2*MSZ;
    int k = mat - 8;
    float nOrTot = (mat < 8) ? (float)cntC[mat] : total[k];
    float inv_nm1 = 1.0f/(nOrTot - 1.0f);
    const float* mrow = (mat < 8) ? (cmean + mat*C_DIM) : (smean + k*C_DIM);
    for (int h = 0; h < 2; ++h){
        #pragma unroll
        for (int rep = 0; rep < 4; ++rep){
            int lin = rep*2048 + t*8;
            int r = lin >> 7;
            int c = lin & 127;
            int gr = i0 + h*64 + r;
            int gc = j0 + c;
            size_t e = (size_t)gr*C_DIM + gc;
            float s2[8];
            if (mat < 8){
                size_t b = (size_t)mat*MSZ + e;
                #pragma unroll
                for (int x=0;x<8;x++)
                    s2[x] = P0[b+x] + P0[b+S+x] + P0[b+2*S+x] + P0[b+3*S+x];
            } else {
                #pragma unroll
                for (int x=0;x<8;x++) s2[x] = 0.0f;
                #pragma unroll
                for (int jj=0;jj<8;jj++){
                    float sc = scores[k*8+jj];
                    size_t b = (size_t)(8+jj)*MSZ + e;
                    #pragma unroll
                    for (int x=0;x<8;x++)
                        s2[x] += sc*(P0[b+x] + P0[b+S+x] + P0[b+2*S+x] + P0[b+3*S+x]);
                }
            }
            float mi = mrow[gr];
            #pragma unroll
            for (int x=0;x<8;x++){
                float v = (s2[x] - nOrTot*mi*mrow[gc+x])*inv_nm1;
                if (mat < 8 && gr == gc+x) v += EPS_C;
                ushort hh,ll; split2(v,hh,ll);
                bm[e+x] = hh; bm[MSZ+e+x] = ll;
                tH[r][c+x] = hh; tL[r][c+x] = ll;
            }
        }
        if (ti != tj){
            __syncthreads();
            #pragma unroll
            for (int rep = 0; rep < 4; ++rep){
                int lin = rep*2048 + t*8;
                int rr = lin >> 6;
                int cc0 = lin & 63;
                size_t eo = (size_t)(j0+rr)*C_DIM + i0 + h*64 + cc0;
                #pragma unroll
                for (int x=0;x<8;x++){
                    bm[eo+x]     = tH[cc0+x][rr];
                    bm[MSZ+eo+x] = tL[cc0+x][rr];
                }
            }
            __syncthreads();
        }
    }
}

// ---------- A^2 row abs-sums via MFMA (no C write), 64x128 tiles ----------

__global__ __launch_bounds__(256) void k_mm_rowsum(
        const ushort* __restrict__ A, float* __restrict__ rowpart){
    __shared__ ushort As[2][4096];
    __shared__ ushort Bs[2][8192];
    __shared__ float rs[64][2];
    int wg = xcd_swz(blockIdx.x, NMAT*32);
    int mat = wg >> 5, tile = wg & 31;
    int ti = tile >> 2, tj = tile & 3;
    int i0 = ti*64, j0 = tj*128;
    const ushort* Am = A + (size_t)mat*2*MSZ;
    int t = threadIdx.x;
    int lane = t & 63, wave = t >> 6;
    int wm = wave >> 1, wn = wave & 1;
    int lr = lane & 15, lk = lane >> 4;
    f32x4 zero = {0.f,0.f,0.f,0.f};
    f32x4 acc[2][4];
    #pragma unroll
    for (int m=0;m<2;m++)
        #pragma unroll
        for (int n=0;n<4;n++) acc[m][n] = zero;
    mm_coreT<2>(Am, MSZ, C_DIM, Am, MSZ, C_DIM, i0, j0, 0, C_DIM,
                As, Bs, acc, wm, wn, lr, lk);
    #pragma unroll
    for (int m=0;m<2;m++)
        #pragma unroll
        for (int j=0;j<4;j++){
            float s = 0.0f;
            #pragma unroll
            for (int n=0;n<4;n++) s += fabsf(acc[m][n][j]);
            #pragma unroll
            for (int d=1; d<16; d<<=1) s += __shfl_xor(s, d);
            if (lr == 0) rs[wm*32 + m*16 + lk*4 + j][wn] = s;
        }
    __syncthreads();
    if (t < 64)
        rowpart[((size_t)mat*4 + tj)*512 + i0 + t] = rs[t][0] + rs[t][1];
}

__global__ __launch_bounds__(256) void k_tmax(const float* __restrict__ rowpart,
                                              float* __restrict__ tvals){
    int mat = blockIdx.x, t = threadIdx.x;
    const float* rp = rowpart + (size_t)mat*4*512;
    float mx = 0.0f;
    for (int r = t; r < 512; r += 256){
        float s = rp[r] + rp[512+r] + rp[1024+r] + rp[1536+r];
        mx = fmaxf(mx, s);
    }
    __shared__ float red[256];
    red[t] = mx; __syncthreads();
    for (int s=128; s>0; s>>=1){ if (t<s) red[t]=fmaxf(red[t],red[t+s]); __syncthreads(); }
    if (t == 0) tvals[mat] = sqrtf(red[0]);
}

// ---------- Y0 = A/t, P0 = q(Y0) = 1.5I - 0.5*Y0 (iteration-0 collapse) ----------

__global__ __launch_bounds__(256) void k_split_initP(const ushort* __restrict__ bA,
        const float* __restrict__ tvals, ushort* __restrict__ Y,
        ushort* __restrict__ P){
    int mat = blockIdx.y;
    int e = blockIdx.x*256 + threadIdx.x;
    size_t base = (size_t)mat*2*MSZ;
    float inv = 1.0f / tvals[mat];
    float a = (bf2f(bA[base+e]) + bf2f(bA[base+MSZ+e])) * inv;
    ushort h,l; split2(a,h,l);
    Y[base + e] = h;
    Y[base + MSZ + e] = l;
    int i = e >> 9, j = e & 511;
    float p = ((i==j)?1.5f:0.0f) - 0.5f*a;
    split2(p,h,l);
    P[base + e] = h;
    P[base + MSZ + e] = l;
}

// ---------- generic 64x128-tile batched mm on split planes ----------
// EPI 0: split write; EPI 1: q(X) then split write; EPI 3: fp32 T + split M(ascale,diag)

template<int EPI>
__global__ __launch_bounds__(256) void k_mm_ns64(
        const ushort* __restrict__ A, const ushort* __restrict__ B,
        ushort* __restrict__ Co, float* __restrict__ Cf,
        const float* __restrict__ tvals, int nmat){
    __shared__ ushort As[2][4096];
    __shared__ ushort Bs[2][8192];
    int wg = xcd_swz(blockIdx.x, nmat*32);
    int mat = wg >> 5, tile = wg & 31;
    int i0 = (tile>>2)*64, j0 = (tile&3)*128;
    const ushort* Am = A + (size_t)mat*2*MSZ;
    const ushort* Bm = B + (size_t)mat*2*MSZ;
    int t = threadIdx.x;
    int lane = t & 63, wave = t >> 6;
    int wm = wave >> 1, wn = wave & 1;
    int lr = lane & 15, lk = lane >> 4;
    f32x4 zero = {0.f,0.f,0.f,0.f};
    f32x4 acc[2][4];
    #pragma unroll
    for (int m=0;m<2;m++)
        #pragma unroll
        for (int n=0;n<4;n++) acc[m][n] = zero;
    mm_coreT<2>(Am, MSZ, C_DIM, Bm, MSZ, C_DIM, i0, j0, 0, C_DIM,
                As, Bs, acc, wm, wn, lr, lk);
    if (EPI == 3){
        float* Cm = Cf + (size_t)mat*MSZ;
        ushort* Mh = Co + (size_t)mat*2*MSZ;
        ushort* Ml = Mh + MSZ;
        float ascale = ALPHA_C * sqrtf(tvals[8+mat]/tvals[mat]);
        #pragma unroll
        for (int m=0;m<2;m++)
            #pragma unroll
            for (int n=0;n<4;n++)
                #pragma unroll
                for (int j=0;j<4;j++){
                    int gr = i0 + wm*32 + m*16 + lk*4 + j;
                    int gc = j0 + wn*64 + n*16 + lr;
                    float v = acc[m][n][j];
                    size_t idx = (size_t)gr*C_DIM + gc;
                    Cm[idx] = v;
                    float mv = ascale*v + ((gr==gc)?(1.0f-ALPHA_C):0.0f);
                    ushort h,l; split2(mv,h,l);
                    Mh[idx] = h; Ml[idx] = l;
                }
    } else {
        ushort* Ch = Co + (size_t)mat*2*MSZ;
        ushort* Cl = Ch + MSZ;
        #pragma unroll
        for (int m=0;m<2;m++)
            #pragma unroll
            for (int n=0;n<4;n++)
                #pragma unroll
                for (int j=0;j<4;j++){
                    int gr = i0 + wm*32 + m*16 + lk*4 + j;
                    int gc = j0 + wn*64 + n*16 + lr;
                    float v = acc[m][n][j];
                    if (EPI == 1) v = ((gr==gc)?1.5f:0.0f) - 0.5f*v;
                    ushort h,l; split2(v,h,l);
                    size_t idx = (size_t)gr*C_DIM + gc;
                    Ch[idx] = h;
                    Cl[idx] = l;
                }
    }
}

// ---------- merged NS stage 2 (128x128 tiles, full chip): fy = Y*qP, fz = qP*Z ----------

__global__ __launch_bounds__(256,2) void k_mm_ns2(
        const ushort* __restrict__ Y, const ushort* __restrict__ P,
        const ushort* __restrict__ Z, ushort* __restrict__ fy,
        ushort* __restrict__ fz){
    __shared__ ushort As[2][8192];
    __shared__ ushort Bs[2][8192];
    int wg = xcd_swz(blockIdx.x, NMAT*32);
    int mat = wg >> 5;
    int r = wg & 31;
    int op = r >> 4, tile = r & 15;
    int i0 = (tile>>2)*128, j0 = (tile&3)*128;
    const ushort* Am = (op ? P : Y) + (size_t)mat*2*MSZ;
    const ushort* Bm = (op ? Z : P) + (size_t)mat*2*MSZ;
    ushort* Ch = (op ? fz : fy) + (size_t)mat*2*MSZ;
    ushort* Cl = Ch + MSZ;
    int t = threadIdx.x;
    int lane = t & 63, wave = t >> 6;
    int wm = wave >> 1, wn = wave & 1;
    int lr = lane & 15, lk = lane >> 4;
    f32x4 zero = {0.f,0.f,0.f,0.f};
    f32x4 acc[4][4];
    #pragma unroll
    for (int m=0;m<4;m++)
        #pragma unroll
        for (int n=0;n<4;n++) acc[m][n] = zero;
    mm_coreT<4>(Am, MSZ, C_DIM, Bm, MSZ, C_DIM, i0, j0, 0, C_DIM,
                As, Bs, acc, wm, wn, lr, lk);
    #pragma unroll
    for (int m=0;m<4;m++)
        #pragma unroll
        for (int n=0;n<4;n++)
            #pragma unroll
            for (int j=0;j<4;j++){
                int gr = i0 + wm*64 + m*16 + lk*4 + j;
                int gc = j0 + wn*64 + n*16 + lr;
                ushort h,l; split2(acc[m][n][j],h,l);
                size_t idx = (size_t)gr*C_DIM + gc;
                Ch[idx] = h;
                Cl[idx] = l;
            }
}

// ---------- last NS stage 2 (64x128 tiles): only consumed halves ----------

__global__ __launch_bounds__(256) void k_mm_ns2_last(
        const ushort* __restrict__ Y, const ushort* __restrict__ P,
        const ushort* __restrict__ Z, ushort* __restrict__ fy,
        ushort* __restrict__ fz){
    __shared__ ushort As[2][4096];
    __shared__ ushort Bs[2][8192];
    int wg = xcd_swz(blockIdx.x, NMAT*32);
    int mat = wg >> 5, tile = wg & 31;
    int op = (mat < 8) ? 1 : 0;         // content: fz = P*Z ; style: fy = Y*P
    int i0 = (tile>>2)*64, j0 = (tile&3)*128;
    const ushort* Am = (op ? P : Y) + (size_t)mat*2*MSZ;
    const ushort* Bm = (op ? Z : P) + (size_t)mat*2*MSZ;
    ushort* Ch = (op ? fz : fy) + (size_t)mat*2*MSZ;
    ushort* Cl = Ch + MSZ;
    int t = threadIdx.x;
    int lane = t & 63, wave = t >> 6;
    int wm = wave >> 1, wn = wave & 1;
    int lr = lane & 15, lk = lane >> 4;
    f32x4 zero = {0.f,0.f,0.f,0.f};
    f32x4 acc[2][4];
    #pragma unroll
    for (int m=0;m<2;m++)
        #pragma unroll
        for (int n=0;n<4;n++) acc[m][n] = zero;
    mm_coreT<2>(Am, MSZ, C_DIM, Bm, MSZ, C_DIM, i0, j0, 0, C_DIM,
                As, Bs, acc, wm, wn, lr, lk);
    #pragma unroll
    for (int m=0;m<2;m++)
        #pragma unroll
        for (int n=0;n<4;n++)
            #pragma unroll
            for (int j=0;j<4;j++){
                int gr = i0 + wm*32 + m*16 + lk*4 + j;
                int gc = j0 + wn*64 + n*16 + lr;
                ushort h,l; split2(acc[m][n][j],h,l);
                size_t idx = (size_t)gr*C_DIM + gc;
                Ch[idx] = h;
                Cl[idx] = l;
            }
}

// ---------- bias vector: vvec = alpha*smean - ascale*(T cmean) ----------

__global__ __launch_bounds__(256) void k_buildV(const float* __restrict__ T,
        const float* __restrict__ tvals, const float* __restrict__ cmean,
        const float* __restrict__ smean, float* __restrict__ vvec){
    __shared__ float cm[512];
    int k = blockIdx.x, t = threadIdx.x;
    cm[t] = cmean[k*C_DIM + t];
    cm[t+256] = cmean[k*C_DIM + t + 256];
    __syncthreads();
    float scale = ALPHA_C * sqrtf(tvals[8+k]/tvals[k]);
    int c = blockIdx.y*256 + t;
    const float* row = T + (size_t)k*MSZ + (size_t)c*C_DIM;
    float s = 0.0f;
    for (int d=0; d<C_DIM; d++) s = fmaf(row[d], cm[d], s);
    vvec[k*C_DIM + c] = ALPHA_C*smean[k*C_DIM + c] - scale*s;
}

// ---------- MFMA apply: Sg = M*Xc + v in gathered order (coalesced) ----------

__global__ __launch_bounds__(256,2) void k_apply_mfma(
        const ushort* __restrict__ Msp, const ushort* __restrict__ XT,
        const float* __restrict__ vvec, const int* __restrict__ offPad,
        float* __restrict__ Sg){
    __shared__ ushort As[2][8192];
    __shared__ ushort Bs[2][8192];
    __shared__ int so[9];
    int t = threadIdx.x;
    if (t < 9) so[t] = offPad[t];
    __syncthreads();
    int wg = xcd_swz(blockIdx.x, (CAP/128)*4);
    int j0 = (wg>>2)*128;
    int i0 = (wg&3)*128;
    if (j0 >= so[8]) return;
    int cl = 0;
    while (cl < 7 && j0 >= so[cl+1]) cl++;
    const ushort* Am = Msp + (size_t)cl*2*MSZ;
    int lane = t & 63, wave = t >> 6;
    int wm = wave >> 1, wn = wave & 1;
    int lr = lane & 15, lk = lane >> 4;
    f32x4 zero = {0.f,0.f,0.f,0.f};
    f32x4 acc[4][4];
    #pragma unroll
    for (int m=0;m<4;m++)
        #pragma unroll
        for (int n=0;n<4;n++) acc[m][n] = zero;
    mm_coreT<4>(Am, MSZ, C_DIM, XT, (size_t)CAP*C_DIM, C_DIM, i0, j0, 0, C_DIM,
                As, Bs, acc, wm, wn, lr, lk);
    #pragma unroll
    for (int m=0;m<4;m++)
        #pragma unroll
        for (int nn=0;nn<4;nn++)
            #pragma unroll
            for (int j=0;j<4;j++){
                int gr = i0 + wm*64 + m*16 + lk*4 + j;
                int gc = j0 + wn*64 + nn*16 + lr;
                Sg[(size_t)gr*CAP + gc] = acc[m][nn][j] + vvec[cl*C_DIM + gr];
            }
}

// ---------- scatter: out[c][p] = Sg[c][ginv[p]] (coalesced writes) ----------

__global__ __launch_bounds__(256) void k_scatter(const float* __restrict__ Sg,
        const int* __restrict__ ginv, float* __restrict__ out){
    size_t idx = (size_t)blockIdx.x*256 + threadIdx.x;
    int p = (int)(idx & (WH-1));
    int c = (int)(idx >> 14);
    out[idx] = Sg[(size_t)c*CAP + ginv[p]];
}

// ---------- host ----------

extern "C" void kernel_launch(void* const* d_in, const int* in_sizes, int n_in,
                              void* d_out, int out_size, void* d_ws, size_t ws_size,
                              hipStream_t stream) {
    (void)in_sizes; (void)n_in;
    const float* cf     = (const float*)d_in[0];
    const float* sf     = (const float*)d_in[1];
    const float* scores = (const float*)d_in[2];
    const int*   cl     = (const int*)d_in[3];
    const int*   sl     = (const int*)d_in[4];
    float* out = (float*)d_out;
    float* ws  = (float*)d_ws;

    size_t o = 0;
    ushort* XcH = (ushort*)(ws + o);
    float*  Sg  = ws + o;       o += (size_t)C_DIM*CAP;
    ushort* XcL = XcH + (size_t)C_DIM*CAP;
    ushort* XsH = (ushort*)(ws + o); o += (size_t)C_DIM*CAP;
    float* S4  = ws + o; o += (size_t)NMAT*MSZ;
    float* NS0 = ws + o; o += (size_t)4*NMAT*MSZ;
    float* cmean = ws + o; o += 8*C_DIM;
    float* ssum  = ws + o; o += 8*C_DIM;
    float* smean = ws + o; o += 8*C_DIM;
    float* vvec  = ws + o; o += 8*C_DIM;
    float* tvals = ws + o; o += 16;
    float* rowpart = ws + o; o += (size_t)NMAT*4*512;
    float* total = ws + o; o += 8;
    float* psumC = ws + o; o += (size_t)C_DIM*NBX;
    float* psumS = ws + o; o += (size_t)C_DIM*NBX;
    int* ip = (int*)(ws + o);
    int* permC    = ip; ip += CAP;
    int* permCinv = ip; ip += CAP;
    int* permS    = ip; ip += CAP;
    int* segOfC = ip; ip += NBX;
    int* segOfS = ip; ip += NBX;
    int* cntC  = ip; ip += 8;
    int* cntS  = ip; ip += 8;
    int* offC  = ip; ip += 9;
    int* offS  = ip; ip += 9;
    int* chC   = ip; ip += NCHUNK*8;
    int* chS   = ip; ip += NCHUNK*8;
    int* baseC = ip; ip += NCHUNK*8;
    int* baseS = ip; ip += NCHUNK*8;
    size_t need_bytes = (size_t)((char*)ip - (char*)d_ws);
    if (ws_size < need_bytes){
        hipMemcpyAsync(d_out, (const void*)cf, (size_t)out_size*sizeof(float),
                       hipMemcpyDeviceToDevice, stream);
        return;
    }
    float* Pf = NS0;
    ushort* s0 = (ushort*)(NS0 + 0*(size_t)NMAT*MSZ);
    ushort* s1 = (ushort*)(NS0 + 1*(size_t)NMAT*MSZ);
    ushort* s2 = (ushort*)(NS0 + 2*(size_t)NMAT*MSZ);
    ushort* s3 = (ushort*)(NS0 + 3*(size_t)NMAT*MSZ);
    ushort* s4 = (ushort*)S4;

    k_chunk_hist<<<dim3(NCHUNK,2),256,0,stream>>>(cl, sl, chC, chS);
    k_scan<<<1,64,0,stream>>>(chC, chS, cntC, cntS, offC, offS, baseC, baseS);
    k_place<<<dim3(NCHUNK,2),64,0,stream>>>(cl, sl, baseC, baseS, permC, permS, permCinv);

    // gather + split + fused cluster partial sums (content z=0, style z=1)
    dim3 gg(NBX, C_DIM/16, 2);
    k_gather2<<<gg,256,0,stream>>>(cf, sf, permC, permS, offC, offS, cntC, cntS,
                                   XcH, XcL, XsH, XsH + (size_t)C_DIM*CAP,
                                   psumC, psumS, segOfC, segOfS);

    k_meanred<<<dim3(8,2,2),256,0,stream>>>(psumC, psumS, segOfC, segOfS, cntC,
                                            cmean, ssum);
    k_style_mean<<<1,256,0,stream>>>(scores, cntS, ssum, total, smean);

    k_syrk_mfma<<<NMAT*NSLICE*10,256,0,stream>>>(XcH, XsH, offC, offS, Pf);

    k_transpose<<<dim3(CAP/64, C_DIM/64, 2),256,0,stream>>>(XcH, XsH);
    ushort* XT = XsH;

    ushort* bA = s4;
    k_assemble<<<dim3(10,16),256,0,stream>>>(Pf, scores, total, cmean, smean, cntC, bA);

    k_mm_rowsum<<<NMAT*32,256,0,stream>>>(bA, rowpart);
    k_tmax<<<NMAT,256,0,stream>>>(rowpart, tvals);

    // iteration 0 (collapsed): Y0=A/t, P0=q(Y0) elementwise; Y1=Y0*P0; Z1=P0 (alias)
    k_split_initP<<<dim3(MSZ/256,NMAT),256,0,stream>>>(bA, tvals, s0, s1);
    k_mm_ns64<0><<<NMAT*32,256,0,stream>>>(s0, s1, s2, nullptr, nullptr, NMAT);

    ushort* bY = s2;  ushort* bZ = s1;  ushort* bP = s3;
    ushort* fy = s4;  ushort* fz = s0;   // s4 = bA slot (consumed), s0 = Y0 (consumed)
    for (int it=0; it<NIT-1; ++it){
        k_mm_ns64<1><<<NMAT*32,256,0,stream>>>(bZ, bY, bP, nullptr, nullptr, NMAT); // P=q(Z*Y)
        if (it < NIT-2)
            k_mm_ns2<<<NMAT*32,256,0,stream>>>(bY, bP, bZ, fy, fz);
        else
            k_mm_ns2_last<<<NMAT*32,256,0,stream>>>(bY, bP, bZ, fy, fz);
        ushort* t1;
        t1 = bY; bY = fy; fy = t1;
        t1 = bZ; bZ = fz; fz = t1;
    }
    // T[k] = Y_style[8+k] * Z_content[k]: fp32 T + split M in one pass
    float* Tf = (float*)fy;
    ushort* Msp = fz;
    k_mm_ns64<3><<<8*32,256,0,stream>>>(bY + (size_t)8*2*MSZ, bZ, Msp, Tf, tvals, 8);

    k_buildV<<<dim3(8,2),256,0,stream>>>(Tf, tvals, cmean, smean, vvec);

    k_apply_mfma<<<(CAP/128)*4,256,0,stream>>>(Msp, XT, vvec, offC, Sg);
    k_scatter<<<(C_DIM*WH)/256,256,0,stream>>>(Sg, permCinv, out);
}

// Round 10
// 607.127 us; speedup vs baseline: 2.0144x; 1.0708x over previous
//
#include <hip/hip_runtime.h>
#include <math.h>

#define C_DIM 512
#define WH    16384
#define CAP   17408      // 16384 + 8*128 worst-case padding
#define NBX   136        // CAP/128
#define SEG_ALIGN 128
#define NCHUNK 64
#define CHUNK  256
#define NMAT 16
#define NSLICE 4
#define MSZ  (C_DIM*C_DIM)
#define ALPHA_C 0.8f
#define EPS_C   1e-6f
#define NIT 7            // total q-applications: 1 collapsed + 6 full

typedef __attribute__((ext_vector_type(8))) __bf16 bfrag;
typedef __attribute__((ext_vector_type(4))) float f32x4;

__device__ inline float bf2f(ushort h){ return __uint_as_float(((unsigned)h)<<16); }
__device__ inline void split2(float v, ushort& h, ushort& l){
    unsigned u = __float_as_uint(v);
    h = (ushort)(u >> 16);
    float r = v - __uint_as_float(u & 0xffff0000u);
    l = (ushort)(__float_as_uint(r) >> 16);
}

__device__ __forceinline__ int xcd_swz(int bid, int nwg){
    int c = nwg >> 3;
    return (bid & 7)*c + (bid >> 3);
}

__device__ __forceinline__ void gload16(const void* g, void* l){
    __builtin_amdgcn_global_load_lds(
        (const __attribute__((address_space(1))) unsigned int*)g,
        (__attribute__((address_space(3))) unsigned int*)l, 16, 0, 0);
}

// stage one R x 64 bf16 panel (R = 64 or 128): LDS linear, source pre-swizzled
template<int R>
__device__ __forceinline__ void stage_panelR(const ushort* __restrict__ src,
        int stride, int i0, int k0, ushort* lds){
    int t = threadIdx.x;
    #pragma unroll
    for (int i = 0; i < R/32; ++i){
        int slot = t + i*256;
        int row = slot >> 3, c8 = slot & 7;
        const ushort* g = src + (size_t)(i0+row)*stride + k0 + ((c8 ^ (row&7))<<3);
        gload16((const void*)g, (void*)&lds[(size_t)(i*256 + (t & 192))*8]);
    }
}

// MFMA inner block: (2*MFR*16) x 128 tile, K=64 step, split-3 products
template<int MFR>
__device__ __forceinline__ void mfma_block(const ushort* As0, const ushort* As1,
        const ushort* Bs0, const ushort* Bs1, f32x4 (&acc)[MFR][4],
        int wm, int wn, int lr, int lk){
    #pragma unroll
    for (int kk = 0; kk < 64; kk += 32){
        bfrag ah[MFR], al[MFR], bh[4], bl[4];
        #pragma unroll
        for (int m = 0; m < MFR; ++m){
            int row = wm*(MFR*16) + m*16 + lr;
            int off = (row*64 + kk + lk*8) ^ ((row&7)<<3);
            ah[m] = *(const bfrag*)&As0[off];
            al[m] = *(const bfrag*)&As1[off];
        }
        #pragma unroll
        for (int n = 0; n < 4; ++n){
            int row = wn*64 + n*16 + lr;
            int off = (row*64 + kk + lk*8) ^ ((row&7)<<3);
            bh[n] = *(const bfrag*)&Bs0[off];
            bl[n] = *(const bfrag*)&Bs1[off];
        }
        #pragma unroll
        for (int m = 0; m < MFR; ++m)
            #pragma unroll
            for (int n = 0; n < 4; ++n){
                acc[m][n] = __builtin_amdgcn_mfma_f32_16x16x32_bf16(ah[m], bh[n], acc[m][n], 0,0,0);
                acc[m][n] = __builtin_amdgcn_mfma_f32_16x16x32_bf16(ah[m], bl[n], acc[m][n], 0,0,0);
                acc[m][n] = __builtin_amdgcn_mfma_f32_16x16x32_bf16(al[m], bh[n], acc[m][n], 0,0,0);
            }
    }
}

// unified K-loop: C((2*MFR*16)x128) += A * B^T on split planes
template<int MFR>
__device__ __forceinline__ void mm_coreT(const ushort* __restrict__ Am, size_t aPl, int aStr,
        const ushort* __restrict__ Bm, size_t bPl, int bStr,
        int i0, int j0, int kLo, int kHi,
        ushort (&As)[2][MFR*2048], ushort (&Bs)[2][8192], f32x4 (&acc)[MFR][4],
        int wm, int wn, int lr, int lk){
    for (int k0 = kLo; k0 < kHi; k0 += 64){
        stage_panelR<MFR*32>(Am,       aStr, i0, k0, As[0]);
        stage_panelR<MFR*32>(Am + aPl, aStr, i0, k0, As[1]);
        stage_panelR<128>(Bm,       bStr, j0, k0, Bs[0]);
        stage_panelR<128>(Bm + bPl, bStr, j0, k0, Bs[1]);
        __syncthreads();
        mfma_block<MFR>(As[0], As[1], Bs[0], Bs[1], acc, wm, wn, lr, lk);
        __syncthreads();
    }
}

// ---------- label bookkeeping (deterministic counting sort), content+style merged ----------

__global__ __launch_bounds__(256) void k_chunk_hist(const int* __restrict__ lab0,
        const int* __restrict__ lab1, int* __restrict__ ch0, int* __restrict__ ch1){
    __shared__ int h[8];
    int t = threadIdx.x;
    const int* labels = blockIdx.y ? lab1 : lab0;
    int* chunkCnt = blockIdx.y ? ch1 : ch0;
    if (t < 8) h[t] = 0;
    __syncthreads();
    int l = labels[blockIdx.x*CHUNK + t];
    atomicAdd(&h[l], 1);
    __syncthreads();
    if (t < 8) chunkCnt[blockIdx.x*8 + t] = h[t];
}

__global__ void k_scan(const int* __restrict__ ch0, const int* __restrict__ ch1,
                       int* __restrict__ cnt0, int* __restrict__ cnt1,
                       int* __restrict__ off0, int* __restrict__ off1,
                       int* __restrict__ base0, int* __restrict__ base1){
    int which = threadIdx.x;
    if (which >= 2) return;
    const int* chunkCnt = which ? ch1 : ch0;
    int* cnt = which ? cnt1 : cnt0;
    int* offPad = which ? off1 : off0;
    int* base = which ? base1 : base0;
    int c[8];
    for (int k=0;k<8;k++) c[k]=0;
    for (int ch=0; ch<NCHUNK; ch++)
        for (int k=0;k<8;k++) c[k] += chunkCnt[ch*8+k];
    int off = 0;
    for (int k=0;k<8;k++){
        cnt[k] = c[k];
        offPad[k] = off;
        off += ((c[k] + SEG_ALIGN - 1)/SEG_ALIGN)*SEG_ALIGN;
    }
    offPad[8] = off;
    for (int k=0;k<8;k++){
        int run = offPad[k];
        for (int ch=0; ch<NCHUNK; ch++){
            base[ch*8+k] = run;
            run += chunkCnt[ch*8+k];
        }
    }
}

__global__ void k_place(const int* __restrict__ lab0, const int* __restrict__ lab1,
        const int* __restrict__ base0, const int* __restrict__ base1,
        int* __restrict__ perm0, int* __restrict__ perm1, int* __restrict__ inv0){
    int t = threadIdx.x;
    if (t >= 8) return;
    const int* labels = blockIdx.y ? lab1 : lab0;
    const int* base = blockIdx.y ? base1 : base0;
    int* perm = blockIdx.y ? perm1 : perm0;
    int* inv = blockIdx.y ? nullptr : inv0;
    int ch = blockIdx.x;
    int pos = base[ch*8+t];
    int s = ch*CHUNK;
    for (int i=0;i<CHUNK;i++){
        if (labels[s+i] == t){
            perm[pos] = s+i;
            if (inv) inv[s+i] = pos;
            pos++;
        }
    }
}

// ---------- gather + split + fused per-cluster partial sums (content & style via z) ----------

__global__ __launch_bounds__(256) void k_gather2(const float* __restrict__ src0,
        const float* __restrict__ src1,
        const int* __restrict__ perm0, const int* __restrict__ perm1,
        const int* __restrict__ off0, const int* __restrict__ off1,
        const int* __restrict__ cnt0, const int* __restrict__ cnt1,
        ushort* __restrict__ dH0, ushort* __restrict__ dL0,
        ushort* __restrict__ dH1, ushort* __restrict__ dL1,
        float* __restrict__ ps0, float* __restrict__ ps1,
        int* __restrict__ sg0, int* __restrict__ sg1){
    int z = blockIdx.z;
    const float* src = z ? src1 : src0;
    const int* perm = z ? perm1 : perm0;
    const int* offPad = z ? off1 : off0;
    const int* cnt = z ? cnt1 : cnt0;
    ushort* dstH = z ? dH1 : dH0;
    ushort* dstL = z ? dL1 : dL0;
    float* psum = z ? ps1 : ps0;
    int* segOf = z ? sg1 : sg0;
    __shared__ int so[9], sc[8];
    __shared__ int pcache[128];
    int t = threadIdx.x;
    if (t < 9) so[t] = offPad[t];
    if (t < 8) sc[t] = cnt[t];
    __syncthreads();
    int bx = blockIdx.x;
    int i0 = bx*128;
    if (t < 128) pcache[t] = (i0 + t < so[8]) ? perm[i0 + t] : 0;
    __syncthreads();
    int k = 0;
    while (k < 7 && i0 >= so[k+1]) k++;
    int n = sc[k], s0 = so[k];
    int ch = t >> 4, px0 = (t & 15)*8;
    int c  = blockIdx.y*16 + ch;
    const float* row = src + (size_t)c*WH;
    float v[8];
    #pragma unroll
    for (int x=0;x<8;x++){
        int i = i0 + px0 + x;
        v[x] = (i - s0 < n) ? row[pcache[px0+x]] : 0.0f;
    }
    float s = 0.0f;
    ushort hv[8], lv[8];
    #pragma unroll
    for (int x=0;x<8;x++){
        s += v[x];
        split2(v[x], hv[x], lv[x]);
    }
    *(uint4*)&dstH[(size_t)c*CAP + i0 + px0] = *(uint4*)hv;
    *(uint4*)&dstL[(size_t)c*CAP + i0 + px0] = *(uint4*)lv;
    #pragma unroll
    for (int d=1; d<16; d<<=1) s += __shfl_xor(s, d, 16);
    if ((t & 15) == 0) psum[(size_t)c*NBX + bx] = s;
    if (t == 0) segOf[bx] = k;
}

// ---------- reduce partials -> per-cluster sums/means (z: 0=content mean, 1=style sum) ----------

__global__ __launch_bounds__(256) void k_meanred(const float* __restrict__ ps0,
        const float* __restrict__ ps1, const int* __restrict__ sg0,
        const int* __restrict__ sg1, const int* __restrict__ cnt0,
        float* __restrict__ out0, float* __restrict__ out1){
    int z = blockIdx.z;
    const float* psum = z ? ps1 : ps0;
    const int* segOf = z ? sg1 : sg0;
    float* out = z ? out1 : out0;
    int k = blockIdx.x;
    int c = blockIdx.y*256 + threadIdx.x;
    float s = 0.0f;
    for (int bx=0; bx<NBX; bx++)
        if (segOf[bx] == k) s += psum[(size_t)c*NBX + bx];
    out[k*C_DIM + c] = z ? s : s/(float)cnt0[k];
}

// ---------- transpose plane: [512][CAP] -> [CAP][512] ----------

__global__ __launch_bounds__(256) void k_transpose(const ushort* __restrict__ S,
                                                   ushort* __restrict__ D){
    __shared__ ushort tile[64][72];
    int p = blockIdx.z;
    const ushort* Sp = S + (size_t)p*C_DIM*CAP;
    ushort* Dp = D + (size_t)p*CAP*C_DIM;
    int cb = blockIdx.x*64;
    int rb = blockIdx.y*64;
    int t = threadIdx.x;
    int tr = t >> 3, tc = t & 7;
    #pragma unroll
    for (int i=0;i<2;i++){
        int r = tr + i*32;
        uint4 v = *(const uint4*)&Sp[(size_t)(rb+r)*CAP + cb + tc*8];
        ushort* u = (ushort*)&v;
        #pragma unroll
        for (int j=0;j<8;j++) tile[tc*8+j][r] = u[j];
    }
    __syncthreads();
    #pragma unroll
    for (int i=0;i<2;i++){
        int r = tr + i*32;
        uint4 v;
        ushort* u = (ushort*)&v;
        #pragma unroll
        for (int j=0;j<8;j++) u[j] = tile[r][tc*8+j];
        *(uint4*)&Dp[(size_t)(cb+r)*C_DIM + rb + tc*8] = v;
    }
}

__global__ __launch_bounds__(256) void k_style_mean(const float* __restrict__ scores,
        const int* __restrict__ cntS, const float* __restrict__ ssum,
        float* __restrict__ total, float* __restrict__ smean){
    int t = threadIdx.x;
    __shared__ float tot[8];
    if (t < 8){
        float s = 0.0f;
        for (int j=0;j<8;j++) s += scores[t*8+j]*(float)cntS[j];
        tot[t] = s; total[t] = s;
    }
    __syncthreads();
    for (int idx=t; idx<8*C_DIM; idx+=256){
        int k = idx / C_DIM, c = idx % C_DIM;
        float s = 0.0f;
        for (int j=0;j<8;j++) s += scores[k*8+j]*ssum[j*C_DIM+c];
        smean[idx] = s / tot[k];
    }
}

// ---------- MFMA SYRK: partial S2 = X X^T, triangular tiles, split-K ----------

__global__ __launch_bounds__(256,2) void k_syrk_mfma(
        const ushort* __restrict__ Xc, const ushort* __restrict__ Xs,
        const int* __restrict__ offC, const int* __restrict__ offS,
        float* __restrict__ Pf){
    __shared__ ushort As[2][8192];
    __shared__ ushort Bs[2][8192];
    int wg = xcd_swz(blockIdx.x, NMAT*NSLICE*10);
    int mat = wg / (NSLICE*10);
    int rem = wg % (NSLICE*10);
    int slice = rem / 10, tt = rem % 10;
    int ti, tj;
    if (tt < 4){ ti=0; tj=tt; }
    else if (tt < 7){ ti=1; tj=tt-3; }
    else if (tt < 9){ ti=2; tj=tt-5; }
    else { ti=3; tj=3; }
    const ushort* X = (mat < 8) ? Xc : Xs;
    const int* offP = (mat < 8) ? offC : offS;
    int cl = mat & 7;
    int off = offP[cl], npad = offP[cl+1] - off;
    int i0 = ti*128, j0 = tj*128;
    int L = ((npad + NSLICE*64 - 1)/(NSLICE*64))*64;
    int k_lo = slice*L;
    int k_hi = min(k_lo + L, npad);
    int t = threadIdx.x;
    int lane = t & 63, wave = t >> 6;
    int wm = wave >> 1, wn = wave & 1;
    int lr = lane & 15, lk = lane >> 4;
    f32x4 zero = {0.f,0.f,0.f,0.f};
    f32x4 acc[4][4];
    #pragma unroll
    for (int m=0;m<4;m++)
        #pragma unroll
        for (int n=0;n<4;n++) acc[m][n] = zero;
    mm_coreT<4>(X + off, (size_t)C_DIM*CAP, CAP,
                X + off, (size_t)C_DIM*CAP, CAP,
                i0, j0, k_lo, k_hi, As, Bs, acc, wm, wn, lr, lk);
    float* O = Pf + ((size_t)(slice*16 + mat))*MSZ;
    #pragma unroll
    for (int m=0;m<4;m++)
        #pragma unroll
        for (int n=0;n<4;n++)
            #pragma unroll
            for (int j=0;j<4;j++){
                int gr = i0 + wm*64 + m*16 + lk*4 + j;
                int gc = j0 + wn*64 + n*16 + lr;
                O[(size_t)gr*C_DIM + gc] = acc[m][n][j];
            }
}

// ---------- assemble A (tile-based, coalesced, LDS mirror) -> split planes ----------

__global__ __launch_bounds__(256) void k_assemble(const float* __restrict__ P0,
        const float* __restrict__ scores, const float* __restrict__ total,
        const float* __restrict__ cmean, const float* __restrict__ smean,
        const int* __restrict__ cntC, ushort* __restrict__ bA){
    const size_t S = (size_t)NMAT*MSZ;
    __shared__ ushort tH[64][136];
    __shared__ ushort tL[64][136];
    int mat = blockIdx.y;
    int tt = blockIdx.x;
    int ti, tj;
    if (tt < 4){ ti=0; tj=tt; }
    else if (tt < 7){ ti=1; tj=tt-3; }
    else if (tt < 9){ ti=2; tj=tt-5; }
    else { ti=3; tj=3; }
    int i0 = ti*128, j0 = tj*128;
    int t = threadIdx.x;
    ushort* bm = bA + (size_t)mat*2*MSZ;
    int k = mat - 8;
    float nOrTot = (mat < 8) ? (float)cntC[mat] : total[k];
    float inv_nm1 = 1.0f/(nOrTot - 1.0f);
    const float* mrow = (mat < 8) ? (cmean + mat*C_DIM) : (smean + k*C_DIM);
    for (int h = 0; h < 2; ++h){
        #pragma unroll
        for (int rep = 0; rep < 4; ++rep){
            int lin = rep*2048 + t*8;
            int r = lin >> 7;
            int c = lin & 127;
            int gr = i0 + h*64 + r;
            int gc = j0 + c;
            size_t e = (size_t)gr*C_DIM + gc;
            float s2[8];
            if (mat < 8){
                size_t b = (size_t)mat*MSZ + e;
                #pragma unroll
                for (int x=0;x<8;x++)
                    s2[x] = P0[b+x] + P0[b+S+x] + P0[b+2*S+x] + P0[b+3*S+x];
            } else {
                #pragma unroll
                for (int x=0;x<8;x++) s2[x] = 0.0f;
                #pragma unroll
                for (int jj=0;jj<8;jj++){
                    float sc = scores[k*8+jj];
                    size_t b = (size_t)(8+jj)*MSZ + e;
                    #pragma unroll
                    for (int x=0;x<8;x++)
                        s2[x] += sc*(P0[b+x] + P0[b+S+x] + P0[b+2*S+x] + P0[b+3*S+x]);
                }
            }
            float mi = mrow[gr];
            #pragma unroll
            for (int x=0;x<8;x++){
                float v = (s2[x] - nOrTot*mi*mrow[gc+x])*inv_nm1;
                if (mat < 8 && gr == gc+x) v += EPS_C;
                ushort hh,ll; split2(v,hh,ll);
                bm[e+x] = hh; bm[MSZ+e+x] = ll;
                tH[r][c+x] = hh; tL[r][c+x] = ll;
            }
        }
        if (ti != tj){
            __syncthreads();
            #pragma unroll
            for (int rep = 0; rep < 4; ++rep){
                int lin = rep*2048 + t*8;
                int rr = lin >> 6;
                int cc0 = lin & 63;
                size_t eo = (size_t)(j0+rr)*C_DIM + i0 + h*64 + cc0;
                #pragma unroll
                for (int x=0;x<8;x++){
                    bm[eo+x]     = tH[cc0+x][rr];
                    bm[MSZ+eo+x] = tL[cc0+x][rr];
                }
            }
            __syncthreads();
        }
    }
}

// ---------- A^2 row abs-sums via MFMA (no C write), 64x128 tiles ----------

__global__ __launch_bounds__(256) void k_mm_rowsum(
        const ushort* __restrict__ A, float* __restrict__ rowpart){
    __shared__ ushort As[2][4096];
    __shared__ ushort Bs[2][8192];
    __shared__ float rs[64][2];
    int wg = xcd_swz(blockIdx.x, NMAT*32);
    int mat = wg >> 5, tile = wg & 31;
    int ti = tile >> 2, tj = tile & 3;
    int i0 = ti*64, j0 = tj*128;
    const ushort* Am = A + (size_t)mat*2*MSZ;
    int t = threadIdx.x;
    int lane = t & 63, wave = t >> 6;
    int wm = wave >> 1, wn = wave & 1;
    int lr = lane & 15, lk = lane >> 4;
    f32x4 zero = {0.f,0.f,0.f,0.f};
    f32x4 acc[2][4];
    #pragma unroll
    for (int m=0;m<2;m++)
        #pragma unroll
        for (int n=0;n<4;n++) acc[m][n] = zero;
    mm_coreT<2>(Am, MSZ, C_DIM, Am, MSZ, C_DIM, i0, j0, 0, C_DIM,
                As, Bs, acc, wm, wn, lr, lk);
    #pragma unroll
    for (int m=0;m<2;m++)
        #pragma unroll
        for (int j=0;j<4;j++){
            float s = 0.0f;
            #pragma unroll
            for (int n=0;n<4;n++) s += fabsf(acc[m][n][j]);
            #pragma unroll
            for (int d=1; d<16; d<<=1) s += __shfl_xor(s, d);
            if (lr == 0) rs[wm*32 + m*16 + lk*4 + j][wn] = s;
        }
    __syncthreads();
    if (t < 64)
        rowpart[((size_t)mat*4 + tj)*512 + i0 + t] = rs[t][0] + rs[t][1];
}

__global__ __launch_bounds__(256) void k_tmax(const float* __restrict__ rowpart,
                                              float* __restrict__ tvals){
    int mat = blockIdx.x, t = threadIdx.x;
    const float* rp = rowpart + (size_t)mat*4*512;
    float mx = 0.0f;
    for (int r = t; r < 512; r += 256){
        float s = rp[r] + rp[512+r] + rp[1024+r] + rp[1536+r];
        mx = fmaxf(mx, s);
    }
    __shared__ float red[256];
    red[t] = mx; __syncthreads();
    for (int s=128; s>0; s>>=1){ if (t<s) red[t]=fmaxf(red[t],red[t+s]); __syncthreads(); }
    if (t == 0) tvals[mat] = sqrtf(red[0]);
}

// ---------- Y0 = A/t, P0 = q(Y0) = 1.5I - 0.5*Y0 (iteration-0 collapse) ----------

__global__ __launch_bounds__(256) void k_split_initP(const ushort* __restrict__ bA,
        const float* __restrict__ tvals, ushort* __restrict__ Y,
        ushort* __restrict__ P){
    int mat = blockIdx.y;
    int e = blockIdx.x*256 + threadIdx.x;
    size_t base = (size_t)mat*2*MSZ;
    float inv = 1.0f / tvals[mat];
    float a = (bf2f(bA[base+e]) + bf2f(bA[base+MSZ+e])) * inv;
    ushort h,l; split2(a,h,l);
    Y[base + e] = h;
    Y[base + MSZ + e] = l;
    int i = e >> 9, j = e & 511;
    float p = ((i==j)?1.5f:0.0f) - 0.5f*a;
    split2(p,h,l);
    P[base + e] = h;
    P[base + MSZ + e] = l;
}

// ---------- generic 64x128-tile batched mm on split planes ----------
// EPI 0: split write; EPI 1: q(X) then split write; EPI 3: fp32 T + split M(ascale,diag)

template<int EPI>
__global__ __launch_bounds__(256) void k_mm_ns64(
        const ushort* __restrict__ A, const ushort* __restrict__ B,
        ushort* __restrict__ Co, float* __restrict__ Cf,
        const float* __restrict__ tvals, int nmat){
    __shared__ ushort As[2][4096];
    __shared__ ushort Bs[2][8192];
    int wg = xcd_swz(blockIdx.x, nmat*32);
    int mat = wg >> 5, tile = wg & 31;
    int i0 = (tile>>2)*64, j0 = (tile&3)*128;
    const ushort* Am = A + (size_t)mat*2*MSZ;
    const ushort* Bm = B + (size_t)mat*2*MSZ;
    int t = threadIdx.x;
    int lane = t & 63, wave = t >> 6;
    int wm = wave >> 1, wn = wave & 1;
    int lr = lane & 15, lk = lane >> 4;
    f32x4 zero = {0.f,0.f,0.f,0.f};
    f32x4 acc[2][4];
    #pragma unroll
    for (int m=0;m<2;m++)
        #pragma unroll
        for (int n=0;n<4;n++) acc[m][n] = zero;
    mm_coreT<2>(Am, MSZ, C_DIM, Bm, MSZ, C_DIM, i0, j0, 0, C_DIM,
                As, Bs, acc, wm, wn, lr, lk);
    if (EPI == 3){
        float* Cm = Cf + (size_t)mat*MSZ;
        ushort* Mh = Co + (size_t)mat*2*MSZ;
        ushort* Ml = Mh + MSZ;
        float ascale = ALPHA_C * sqrtf(tvals[8+mat]/tvals[mat]);
        #pragma unroll
        for (int m=0;m<2;m++)
            #pragma unroll
            for (int n=0;n<4;n++)
                #pragma unroll
                for (int j=0;j<4;j++){
                    int gr = i0 + wm*32 + m*16 + lk*4 + j;
                    int gc = j0 + wn*64 + n*16 + lr;
                    float v = acc[m][n][j];
                    size_t idx = (size_t)gr*C_DIM + gc;
                    Cm[idx] = v;
                    float mv = ascale*v + ((gr==gc)?(1.0f-ALPHA_C):0.0f);
                    ushort h,l; split2(mv,h,l);
                    Mh[idx] = h; Ml[idx] = l;
                }
    } else {
        ushort* Ch = Co + (size_t)mat*2*MSZ;
        ushort* Cl = Ch + MSZ;
        #pragma unroll
        for (int m=0;m<2;m++)
            #pragma unroll
            for (int n=0;n<4;n++)
                #pragma unroll
                for (int j=0;j<4;j++){
                    int gr = i0 + wm*32 + m*16 + lk*4 + j;
                    int gc = j0 + wn*64 + n*16 + lr;
                    float v = acc[m][n][j];
                    if (EPI == 1) v = ((gr==gc)?1.5f:0.0f) - 0.5f*v;
                    ushort h,l; split2(v,h,l);
                    size_t idx = (size_t)gr*C_DIM + gc;
                    Ch[idx] = h;
                    Cl[idx] = l;
                }
    }
}

// ---------- merged NS stage 2 (128x128 tiles, full chip): fy = Y*qP, fz = qP*Z ----------

__global__ __launch_bounds__(256,2) void k_mm_ns2(
        const ushort* __restrict__ Y, const ushort* __restrict__ P,
        const ushort* __restrict__ Z, ushort* __restrict__ fy,
        ushort* __restrict__ fz){
    __shared__ ushort As[2][8192];
    __shared__ ushort Bs[2][8192];
    int wg = xcd_swz(blockIdx.x, NMAT*32);
    int mat = wg >> 5;
    int r = wg & 31;
    int op = r >> 4, tile = r & 15;
    int i0 = (tile>>2)*128, j0 = (tile&3)*128;
    const ushort* Am = (op ? P : Y) + (size_t)mat*2*MSZ;
    const ushort* Bm = (op ? Z : P) + (size_t)mat*2*MSZ;
    ushort* Ch = (op ? fz : fy) + (size_t)mat*2*MSZ;
    ushort* Cl = Ch + MSZ;
    int t = threadIdx.x;
    int lane = t & 63, wave = t >> 6;
    int wm = wave >> 1, wn = wave & 1;
    int lr = lane & 15, lk = lane >> 4;
    f32x4 zero = {0.f,0.f,0.f,0.f};
    f32x4 acc[4][4];
    #pragma unroll
    for (int m=0;m<4;m++)
        #pragma unroll
        for (int n=0;n<4;n++) acc[m][n] = zero;
    mm_coreT<4>(Am, MSZ, C_DIM, Bm, MSZ, C_DIM, i0, j0, 0, C_DIM,
                As, Bs, acc, wm, wn, lr, lk);
    #pragma unroll
    for (int m=0;m<4;m++)
        #pragma unroll
        for (int n=0;n<4;n++)
            #pragma unroll
            for (int j=0;j<4;j++){
                int gr = i0 + wm*64 + m*16 + lk*4 + j;
                int gc = j0 + wn*64 + n*16 + lr;
                ushort h,l; split2(acc[m][n][j],h,l);
                size_t idx = (size_t)gr*C_DIM + gc;
                Ch[idx] = h;
                Cl[idx] = l;
            }
}

// ---------- last NS stage 2 (64x128 tiles): only consumed halves ----------

__global__ __launch_bounds__(256) void k_mm_ns2_last(
        const ushort* __restrict__ Y, const ushort* __restrict__ P,
        const ushort* __restrict__ Z, ushort* __restrict__ fy,
        ushort* __restrict__ fz){
    __shared__ ushort As[2][4096];
    __shared__ ushort Bs[2][8192];
    int wg = xcd_swz(blockIdx.x, NMAT*32);
    int mat = wg >> 5, tile = wg & 31;
    int op = (mat < 8) ? 1 : 0;         // content: fz = P*Z ; style: fy = Y*P
    int i0 = (tile>>2)*64, j0 = (tile&3)*128;
    const ushort* Am = (op ? P : Y) + (size_t)mat*2*MSZ;
    const ushort* Bm = (op ? Z : P) + (size_t)mat*2*MSZ;
    ushort* Ch = (op ? fz : fy) + (size_t)mat*2*MSZ;
    ushort* Cl = Ch + MSZ;
    int t = threadIdx.x;
    int lane = t & 63, wave = t >> 6;
    int wm = wave >> 1, wn = wave & 1;
    int lr = lane & 15, lk = lane >> 4;
    f32x4 zero = {0.f,0.f,0.f,0.f};
    f32x4 acc[2][4];
    #pragma unroll
    for (int m=0;m<2;m++)
        #pragma unroll
        for (int n=0;n<4;n++) acc[m][n] = zero;
    mm_coreT<2>(Am, MSZ, C_DIM, Bm, MSZ, C_DIM, i0, j0, 0, C_DIM,
                As, Bs, acc, wm, wn, lr, lk);
    #pragma unroll
    for (int m=0;m<2;m++)
        #pragma unroll
        for (int n=0;n<4;n++)
            #pragma unroll
            for (int j=0;j<4;j++){
                int gr = i0 + wm*32 + m*16 + lk*4 + j;
                int gc = j0 + wn*64 + n*16 + lr;
                ushort h,l; split2(acc[m][n][j],h,l);
                size_t idx = (size_t)gr*C_DIM + gc;
                Ch[idx] = h;
                Cl[idx] = l;
            }
}

// ---------- bias vector: vvec = alpha*smean - ascale*(T cmean) ----------

__global__ __launch_bounds__(256) void k_buildV(const float* __restrict__ T,
        const float* __restrict__ tvals, const float* __restrict__ cmean,
        const float* __restrict__ smean, float* __restrict__ vvec){
    __shared__ float cm[512];
    int k = blockIdx.x, t = threadIdx.x;
    cm[t] = cmean[k*C_DIM + t];
    cm[t+256] = cmean[k*C_DIM + t + 256];
    __syncthreads();
    float scale = ALPHA_C * sqrtf(tvals[8+k]/tvals[k]);
    int c = blockIdx.y*256 + t;
    const float* row = T + (size_t)k*MSZ + (size_t)c*C_DIM;
    float s = 0.0f;
    for (int d=0; d<C_DIM; d++) s = fmaf(row[d], cm[d], s);
    vvec[k*C_DIM + c] = ALPHA_C*smean[k*C_DIM + c] - scale*s;
}

// ---------- MFMA apply: Sg = M*Xc + v in gathered order (coalesced) ----------

__global__ __launch_bounds__(256,2) void k_apply_mfma(
        const ushort* __restrict__ Msp, const ushort* __restrict__ XT,
        const float* __restrict__ vvec, const int* __restrict__ offPad,
        float* __restrict__ Sg){
    __shared__ ushort As[2][8192];
    __shared__ ushort Bs[2][8192];
    __shared__ int so[9];
    int t = threadIdx.x;
    if (t < 9) so[t] = offPad[t];
    __syncthreads();
    int wg = xcd_swz(blockIdx.x, (CAP/128)*4);
    int j0 = (wg>>2)*128;
    int i0 = (wg&3)*128;
    if (j0 >= so[8]) return;
    int cl = 0;
    while (cl < 7 && j0 >= so[cl+1]) cl++;
    const ushort* Am = Msp + (size_t)cl*2*MSZ;
    int lane = t & 63, wave = t >> 6;
    int wm = wave >> 1, wn = wave & 1;
    int lr = lane & 15, lk = lane >> 4;
    f32x4 zero = {0.f,0.f,0.f,0.f};
    f32x4 acc[4][4];
    #pragma unroll
    for (int m=0;m<4;m++)
        #pragma unroll
        for (int n=0;n<4;n++) acc[m][n] = zero;
    mm_coreT<4>(Am, MSZ, C_DIM, XT, (size_t)CAP*C_DIM, C_DIM, i0, j0, 0, C_DIM,
                As, Bs, acc, wm, wn, lr, lk);
    #pragma unroll
    for (int m=0;m<4;m++)
        #pragma unroll
        for (int nn=0;nn<4;nn++)
            #pragma unroll
            for (int j=0;j<4;j++){
                int gr = i0 + wm*64 + m*16 + lk*4 + j;
                int gc = j0 + wn*64 + nn*16 + lr;
                Sg[(size_t)gr*CAP + gc] = acc[m][nn][j] + vvec[cl*C_DIM + gr];
            }
}

// ---------- scatter: out[c][p] = Sg[c][ginv[p]] (coalesced writes) ----------

__global__ __launch_bounds__(256) void k_scatter(const float* __restrict__ Sg,
        const int* __restrict__ ginv, float* __restrict__ out){
    size_t idx = (size_t)blockIdx.x*256 + threadIdx.x;
    int p = (int)(idx & (WH-1));
    int c = (int)(idx >> 14);
    out[idx] = Sg[(size_t)c*CAP + ginv[p]];
}

// ---------- host ----------

extern "C" void kernel_launch(void* const* d_in, const int* in_sizes, int n_in,
                              void* d_out, int out_size, void* d_ws, size_t ws_size,
                              hipStream_t stream) {
    (void)in_sizes; (void)n_in;
    const float* cf     = (const float*)d_in[0];
    const float* sf     = (const float*)d_in[1];
    const float* scores = (const float*)d_in[2];
    const int*   cl     = (const int*)d_in[3];
    const int*   sl     = (const int*)d_in[4];
    float* out = (float*)d_out;
    float* ws  = (float*)d_ws;

    size_t o = 0;
    ushort* XcH = (ushort*)(ws + o);
    float*  Sg  = ws + o;       o += (size_t)C_DIM*CAP;
    ushort* XcL = XcH + (size_t)C_DIM*CAP;
    ushort* XsH = (ushort*)(ws + o); o += (size_t)C_DIM*CAP;
    float* S4  = ws + o; o += (size_t)NMAT*MSZ;
    float* NS0 = ws + o; o += (size_t)4*NMAT*MSZ;
    float* cmean = ws + o; o += 8*C_DIM;
    float* ssum  = ws + o; o += 8*C_DIM;
    float* smean = ws + o; o += 8*C_DIM;
    float* vvec  = ws + o; o += 8*C_DIM;
    float* tvals = ws + o; o += 16;
    float* rowpart = ws + o; o += (size_t)NMAT*4*512;
    float* total = ws + o; o += 8;
    float* psumC = ws + o; o += (size_t)C_DIM*NBX;
    float* psumS = ws + o; o += (size_t)C_DIM*NBX;
    int* ip = (int*)(ws + o);
    int* permC    = ip; ip += CAP;
    int* permCinv = ip; ip += CAP;
    int* permS    = ip; ip += CAP;
    int* segOfC = ip; ip += NBX;
    int* segOfS = ip; ip += NBX;
    int* cntC  = ip; ip += 8;
    int* cntS  = ip; ip += 8;
    int* offC  = ip; ip += 9;
    int* offS  = ip; ip += 9;
    int* chC   = ip; ip += NCHUNK*8;
    int* chS   = ip; ip += NCHUNK*8;
    int* baseC = ip; ip += NCHUNK*8;
    int* baseS = ip; ip += NCHUNK*8;
    size_t need_bytes = (size_t)((char*)ip - (char*)d_ws);
    if (ws_size < need_bytes){
        hipMemcpyAsync(d_out, (const void*)cf, (size_t)out_size*sizeof(float),
                       hipMemcpyDeviceToDevice, stream);
        return;
    }
    float* Pf = NS0;
    ushort* s0 = (ushort*)(NS0 + 0*(size_t)NMAT*MSZ);
    ushort* s1 = (ushort*)(NS0 + 1*(size_t)NMAT*MSZ);
    ushort* s2 = (ushort*)(NS0 + 2*(size_t)NMAT*MSZ);
    ushort* s3 = (ushort*)(NS0 + 3*(size_t)NMAT*MSZ);
    ushort* s4 = (ushort*)S4;

    k_chunk_hist<<<dim3(NCHUNK,2),256,0,stream>>>(cl, sl, chC, chS);
    k_scan<<<1,64,0,stream>>>(chC, chS, cntC, cntS, offC, offS, baseC, baseS);
    k_place<<<dim3(NCHUNK,2),64,0,stream>>>(cl, sl, baseC, baseS, permC, permS, permCinv);

    // gather + split + fused cluster partial sums (content z=0, style z=1)
    dim3 gg(NBX, C_DIM/16, 2);
    k_gather2<<<gg,256,0,stream>>>(cf, sf, permC, permS, offC, offS, cntC, cntS,
                                   XcH, XcL, XsH, XsH + (size_t)C_DIM*CAP,
                                   psumC, psumS, segOfC, segOfS);

    k_meanred<<<dim3(8,2,2),256,0,stream>>>(psumC, psumS, segOfC, segOfS, cntC,
                                            cmean, ssum);
    k_style_mean<<<1,256,0,stream>>>(scores, cntS, ssum, total, smean);

    k_syrk_mfma<<<NMAT*NSLICE*10,256,0,stream>>>(XcH, XsH, offC, offS, Pf);

    k_transpose<<<dim3(CAP/64, C_DIM/64, 2),256,0,stream>>>(XcH, XsH);
    ushort* XT = XsH;

    ushort* bA = s4;
    k_assemble<<<dim3(10,16),256,0,stream>>>(Pf, scores, total, cmean, smean, cntC, bA);

    k_mm_rowsum<<<NMAT*32,256,0,stream>>>(bA, rowpart);
    k_tmax<<<NMAT,256,0,stream>>>(rowpart, tvals);

    // iteration 0 (collapsed): Y0=A/t, P0=q(Y0) elementwise; Y1=Y0*P0; Z1=P0 (alias)
    k_split_initP<<<dim3(MSZ/256,NMAT),256,0,stream>>>(bA, tvals, s0, s1);
    k_mm_ns64<0><<<NMAT*32,256,0,stream>>>(s0, s1, s2, nullptr, nullptr, NMAT);

    ushort* bY = s2;  ushort* bZ = s1;  ushort* bP = s3;
    ushort* fy = s4;  ushort* fz = s0;   // s4 = bA slot (consumed), s0 = Y0 (consumed)
    for (int it=0; it<NIT-1; ++it){
        k_mm_ns64<1><<<NMAT*32,256,0,stream>>>(bZ, bY, bP, nullptr, nullptr, NMAT); // P=q(Z*Y)
        if (it < NIT-2)
            k_mm_ns2<<<NMAT*32,256,0,stream>>>(bY, bP, bZ, fy, fz);
        else
            k_mm_ns2_last<<<NMAT*32,256,0,stream>>>(bY, bP, bZ, fy, fz);
        ushort* t1;
        t1 = bY; bY = fy; fy = t1;
        t1 = bZ; bZ = fz; fz = t1;
    }
    // T[k] = Y_style[8+k] * Z_content[k]: fp32 T + split M in one pass
    float* Tf = (float*)fy;
    ushort* Msp = fz;
    k_mm_ns64<3><<<8*32,256,0,stream>>>(bY + (size_t)8*2*MSZ, bZ, Msp, Tf, tvals, 8);

    k_buildV<<<dim3(8,2),256,0,stream>>>(Tf, tvals, cmean, smean, vvec);

    k_apply_mfma<<<(CAP/128)*4,256,0,stream>>>(Msp, XT, vvec, offC, Sg);
    k_scatter<<<(C_DIM*WH)/256,256,0,stream>>>(Sg, permCinv, out);
}

// Round 11
// 559.449 us; speedup vs baseline: 2.1861x; 1.0852x over previous
//
#include <hip/hip_runtime.h>
#include <math.h>

#define C_DIM 512
#define WH    16384
#define CAP   17408      // 16384 + 8*128 worst-case padding
#define NBX   136        // CAP/128
#define SEG_ALIGN 128
#define NCHUNK 64
#define CHUNK  256
#define NMAT 16
#define NSLICE 4
#define MSZ  (C_DIM*C_DIM)
#define ALPHA_C 0.8f
#define EPS_C   1e-6f
#define NIT 6            // total q-applications: 1 collapsed + 5 full

typedef __attribute__((ext_vector_type(8))) __bf16 bfrag;
typedef __attribute__((ext_vector_type(4))) float f32x4;

__device__ inline float bf2f(ushort h){ return __uint_as_float(((unsigned)h)<<16); }
__device__ inline void split2(float v, ushort& h, ushort& l){
    unsigned u = __float_as_uint(v);
    h = (ushort)(u >> 16);
    float r = v - __uint_as_float(u & 0xffff0000u);
    l = (ushort)(__float_as_uint(r) >> 16);
}

__device__ __forceinline__ int xcd_swz(int bid, int nwg){
    int c = nwg >> 3;
    return (bid & 7)*c + (bid >> 3);
}

__device__ __forceinline__ void gload16(const void* g, void* l){
    __builtin_amdgcn_global_load_lds(
        (const __attribute__((address_space(1))) unsigned int*)g,
        (__attribute__((address_space(3))) unsigned int*)l, 16, 0, 0);
}

// stage one R x 64 bf16 panel (R = 64 or 128): LDS linear, source pre-swizzled
template<int R>
__device__ __forceinline__ void stage_panelR(const ushort* __restrict__ src,
        int stride, int i0, int k0, ushort* lds){
    int t = threadIdx.x;
    #pragma unroll
    for (int i = 0; i < R/32; ++i){
        int slot = t + i*256;
        int row = slot >> 3, c8 = slot & 7;
        const ushort* g = src + (size_t)(i0+row)*stride + k0 + ((c8 ^ (row&7))<<3);
        gload16((const void*)g, (void*)&lds[(size_t)(i*256 + (t & 192))*8]);
    }
}

// MFMA inner block: (2*MFR*16) x 128 tile, K=64 step, split-3 products
template<int MFR>
__device__ __forceinline__ void mfma_block(const ushort* As0, const ushort* As1,
        const ushort* Bs0, const ushort* Bs1, f32x4 (&acc)[MFR][4],
        int wm, int wn, int lr, int lk){
    #pragma unroll
    for (int kk = 0; kk < 64; kk += 32){
        bfrag ah[MFR], al[MFR], bh[4], bl[4];
        #pragma unroll
        for (int m = 0; m < MFR; ++m){
            int row = wm*(MFR*16) + m*16 + lr;
            int off = (row*64 + kk + lk*8) ^ ((row&7)<<3);
            ah[m] = *(const bfrag*)&As0[off];
            al[m] = *(const bfrag*)&As1[off];
        }
        #pragma unroll
        for (int n = 0; n < 4; ++n){
            int row = wn*64 + n*16 + lr;
            int off = (row*64 + kk + lk*8) ^ ((row&7)<<3);
            bh[n] = *(const bfrag*)&Bs0[off];
            bl[n] = *(const bfrag*)&Bs1[off];
        }
        #pragma unroll
        for (int m = 0; m < MFR; ++m)
            #pragma unroll
            for (int n = 0; n < 4; ++n){
                acc[m][n] = __builtin_amdgcn_mfma_f32_16x16x32_bf16(ah[m], bh[n], acc[m][n], 0,0,0);
                acc[m][n] = __builtin_amdgcn_mfma_f32_16x16x32_bf16(ah[m], bl[n], acc[m][n], 0,0,0);
                acc[m][n] = __builtin_amdgcn_mfma_f32_16x16x32_bf16(al[m], bh[n], acc[m][n], 0,0,0);
            }
    }
}

// unified K-loop: C((2*MFR*16)x128) += A * B^T on split planes
template<int MFR>
__device__ __forceinline__ void mm_coreT(const ushort* __restrict__ Am, size_t aPl, int aStr,
        const ushort* __restrict__ Bm, size_t bPl, int bStr,
        int i0, int j0, int kLo, int kHi,
        ushort (&As)[2][MFR*2048], ushort (&Bs)[2][8192], f32x4 (&acc)[MFR][4],
        int wm, int wn, int lr, int lk){
    for (int k0 = kLo; k0 < kHi; k0 += 64){
        stage_panelR<MFR*32>(Am,       aStr, i0, k0, As[0]);
        stage_panelR<MFR*32>(Am + aPl, aStr, i0, k0, As[1]);
        stage_panelR<128>(Bm,       bStr, j0, k0, Bs[0]);
        stage_panelR<128>(Bm + bPl, bStr, j0, k0, Bs[1]);
        __syncthreads();
        mfma_block<MFR>(As[0], As[1], Bs[0], Bs[1], acc, wm, wn, lr, lk);
        __syncthreads();
    }
}

// ---------- label bookkeeping (deterministic counting sort), content+style merged ----------

__global__ __launch_bounds__(256) void k_chunk_hist(const int* __restrict__ lab0,
        const int* __restrict__ lab1, int* __restrict__ ch0, int* __restrict__ ch1){
    __shared__ int h[8];
    int t = threadIdx.x;
    const int* labels = blockIdx.y ? lab1 : lab0;
    int* chunkCnt = blockIdx.y ? ch1 : ch0;
    if (t < 8) h[t] = 0;
    __syncthreads();
    int l = labels[blockIdx.x*CHUNK + t];
    atomicAdd(&h[l], 1);
    __syncthreads();
    if (t < 8) chunkCnt[blockIdx.x*8 + t] = h[t];
}

__global__ void k_scan(const int* __restrict__ ch0, const int* __restrict__ ch1,
                       int* __restrict__ cnt0, int* __restrict__ cnt1,
                       int* __restrict__ off0, int* __restrict__ off1,
                       int* __restrict__ base0, int* __restrict__ base1){
    int which = threadIdx.x;
    if (which >= 2) return;
    const int* chunkCnt = which ? ch1 : ch0;
    int* cnt = which ? cnt1 : cnt0;
    int* offPad = which ? off1 : off0;
    int* base = which ? base1 : base0;
    int c[8];
    for (int k=0;k<8;k++) c[k]=0;
    for (int ch=0; ch<NCHUNK; ch++)
        for (int k=0;k<8;k++) c[k] += chunkCnt[ch*8+k];
    int off = 0;
    for (int k=0;k<8;k++){
        cnt[k] = c[k];
        offPad[k] = off;
        off += ((c[k] + SEG_ALIGN - 1)/SEG_ALIGN)*SEG_ALIGN;
    }
    offPad[8] = off;
    for (int k=0;k<8;k++){
        int run = offPad[k];
        for (int ch=0; ch<NCHUNK; ch++){
            base[ch*8+k] = run;
            run += chunkCnt[ch*8+k];
        }
    }
}

__global__ void k_place(const int* __restrict__ lab0, const int* __restrict__ lab1,
        const int* __restrict__ base0, const int* __restrict__ base1,
        int* __restrict__ perm0, int* __restrict__ perm1, int* __restrict__ inv0){
    int t = threadIdx.x;
    if (t >= 8) return;
    const int* labels = blockIdx.y ? lab1 : lab0;
    const int* base = blockIdx.y ? base1 : base0;
    int* perm = blockIdx.y ? perm1 : perm0;
    int* inv = blockIdx.y ? nullptr : inv0;
    int ch = blockIdx.x;
    int pos = base[ch*8+t];
    int s = ch*CHUNK;
    for (int i=0;i<CHUNK;i++){
        if (labels[s+i] == t){
            perm[pos] = s+i;
            if (inv) inv[s+i] = pos;
            pos++;
        }
    }
}

// ---------- gather + split + fused per-cluster partial sums (content & style via z) ----------

__global__ __launch_bounds__(256) void k_gather2(const float* __restrict__ src0,
        const float* __restrict__ src1,
        const int* __restrict__ perm0, const int* __restrict__ perm1,
        const int* __restrict__ off0, const int* __restrict__ off1,
        const int* __restrict__ cnt0, const int* __restrict__ cnt1,
        ushort* __restrict__ dH0, ushort* __restrict__ dL0,
        ushort* __restrict__ dH1, ushort* __restrict__ dL1,
        float* __restrict__ ps0, float* __restrict__ ps1,
        int* __restrict__ sg0, int* __restrict__ sg1){
    int z = blockIdx.z;
    const float* src = z ? src1 : src0;
    const int* perm = z ? perm1 : perm0;
    const int* offPad = z ? off1 : off0;
    const int* cnt = z ? cnt1 : cnt0;
    ushort* dstH = z ? dH1 : dH0;
    ushort* dstL = z ? dL1 : dL0;
    float* psum = z ? ps1 : ps0;
    int* segOf = z ? sg1 : sg0;
    __shared__ int so[9], sc[8];
    __shared__ int pcache[128];
    int t = threadIdx.x;
    if (t < 9) so[t] = offPad[t];
    if (t < 8) sc[t] = cnt[t];
    __syncthreads();
    int bx = blockIdx.x;
    int i0 = bx*128;
    if (t < 128) pcache[t] = (i0 + t < so[8]) ? perm[i0 + t] : 0;
    __syncthreads();
    int k = 0;
    while (k < 7 && i0 >= so[k+1]) k++;
    int n = sc[k], s0 = so[k];
    int ch = t >> 4, px0 = (t & 15)*8;
    int c  = blockIdx.y*16 + ch;
    const float* row = src + (size_t)c*WH;
    float v[8];
    #pragma unroll
    for (int x=0;x<8;x++){
        int i = i0 + px0 + x;
        v[x] = (i - s0 < n) ? row[pcache[px0+x]] : 0.0f;
    }
    float s = 0.0f;
    ushort hv[8], lv[8];
    #pragma unroll
    for (int x=0;x<8;x++){
        s += v[x];
        split2(v[x], hv[x], lv[x]);
    }
    *(uint4*)&dstH[(size_t)c*CAP + i0 + px0] = *(uint4*)hv;
    *(uint4*)&dstL[(size_t)c*CAP + i0 + px0] = *(uint4*)lv;
    #pragma unroll
    for (int d=1; d<16; d<<=1) s += __shfl_xor(s, d, 16);
    if ((t & 15) == 0) psum[(size_t)c*NBX + bx] = s;
    if (t == 0) segOf[bx] = k;
}

// ---------- reduce partials -> per-cluster sums/means (z: 0=content mean, 1=style sum) ----------

__global__ __launch_bounds__(256) void k_meanred(const float* __restrict__ ps0,
        const float* __restrict__ ps1, const int* __restrict__ sg0,
        const int* __restrict__ sg1, const int* __restrict__ cnt0,
        float* __restrict__ out0, float* __restrict__ out1){
    int z = blockIdx.z;
    const float* psum = z ? ps1 : ps0;
    const int* segOf = z ? sg1 : sg0;
    float* out = z ? out1 : out0;
    int k = blockIdx.x;
    int c = blockIdx.y*256 + threadIdx.x;
    float s = 0.0f;
    for (int bx=0; bx<NBX; bx++)
        if (segOf[bx] == k) s += psum[(size_t)c*NBX + bx];
    out[k*C_DIM + c] = z ? s : s/(float)cnt0[k];
}

// ---------- transpose plane: [512][CAP] -> [CAP][512] ----------

__global__ __launch_bounds__(256) void k_transpose(const ushort* __restrict__ S,
                                                   ushort* __restrict__ D){
    __shared__ ushort tile[64][72];
    int p = blockIdx.z;
    const ushort* Sp = S + (size_t)p*C_DIM*CAP;
    ushort* Dp = D + (size_t)p*CAP*C_DIM;
    int cb = blockIdx.x*64;
    int rb = blockIdx.y*64;
    int t = threadIdx.x;
    int tr = t >> 3, tc = t & 7;
    #pragma unroll
    for (int i=0;i<2;i++){
        int r = tr + i*32;
        uint4 v = *(const uint4*)&Sp[(size_t)(rb+r)*CAP + cb + tc*8];
        ushort* u = (ushort*)&v;
        #pragma unroll
        for (int j=0;j<8;j++) tile[tc*8+j][r] = u[j];
    }
    __syncthreads();
    #pragma unroll
    for (int i=0;i<2;i++){
        int r = tr + i*32;
        uint4 v;
        ushort* u = (ushort*)&v;
        #pragma unroll
        for (int j=0;j<8;j++) u[j] = tile[r][tc*8+j];
        *(uint4*)&Dp[(size_t)(cb+r)*C_DIM + rb + tc*8] = v;
    }
}

__global__ __launch_bounds__(256) void k_style_mean(const float* __restrict__ scores,
        const int* __restrict__ cntS, const float* __restrict__ ssum,
        float* __restrict__ total, float* __restrict__ smean){
    int t = threadIdx.x;
    __shared__ float tot[8];
    if (t < 8){
        float s = 0.0f;
        for (int j=0;j<8;j++) s += scores[t*8+j]*(float)cntS[j];
        tot[t] = s; total[t] = s;
    }
    __syncthreads();
    for (int idx=t; idx<8*C_DIM; idx+=256){
        int k = idx / C_DIM, c = idx % C_DIM;
        float s = 0.0f;
        for (int j=0;j<8;j++) s += scores[k*8+j]*ssum[j*C_DIM+c];
        smean[idx] = s / tot[k];
    }
}

// ---------- MFMA SYRK: partial S2 = X X^T, triangular tiles, split-K ----------

__global__ __launch_bounds__(256,2) void k_syrk_mfma(
        const ushort* __restrict__ Xc, const ushort* __restrict__ Xs,
        const int* __restrict__ offC, const int* __restrict__ offS,
        float* __restrict__ Pf){
    __shared__ ushort As[2][8192];
    __shared__ ushort Bs[2][8192];
    int wg = xcd_swz(blockIdx.x, NMAT*NSLICE*10);
    int mat = wg / (NSLICE*10);
    int rem = wg % (NSLICE*10);
    int slice = rem / 10, tt = rem % 10;
    int ti, tj;
    if (tt < 4){ ti=0; tj=tt; }
    else if (tt < 7){ ti=1; tj=tt-3; }
    else if (tt < 9){ ti=2; tj=tt-5; }
    else { ti=3; tj=3; }
    const ushort* X = (mat < 8) ? Xc : Xs;
    const int* offP = (mat < 8) ? offC : offS;
    int cl = mat & 7;
    int off = offP[cl], npad = offP[cl+1] - off;
    int i0 = ti*128, j0 = tj*128;
    int L = ((npad + NSLICE*64 - 1)/(NSLICE*64))*64;
    int k_lo = slice*L;
    int k_hi = min(k_lo + L, npad);
    int t = threadIdx.x;
    int lane = t & 63, wave = t >> 6;
    int wm = wave >> 1, wn = wave & 1;
    int lr = lane & 15, lk = lane >> 4;
    f32x4 zero = {0.f,0.f,0.f,0.f};
    f32x4 acc[4][4];
    #pragma unroll
    for (int m=0;m<4;m++)
        #pragma unroll
        for (int n=0;n<4;n++) acc[m][n] = zero;
    mm_coreT<4>(X + off, (size_t)C_DIM*CAP, CAP,
                X + off, (size_t)C_DIM*CAP, CAP,
                i0, j0, k_lo, k_hi, As, Bs, acc, wm, wn, lr, lk);
    float* O = Pf + ((size_t)(slice*16 + mat))*MSZ;
    #pragma unroll
    for (int m=0;m<4;m++)
        #pragma unroll
        for (int n=0;n<4;n++)
            #pragma unroll
            for (int j=0;j<4;j++){
                int gr = i0 + wm*64 + m*16 + lk*4 + j;
                int gc = j0 + wn*64 + n*16 + lr;
                O[(size_t)gr*C_DIM + gc] = acc[m][n][j];
            }
}

// ---------- assemble A (tile-based, coalesced, LDS mirror) -> split planes ----------

__global__ __launch_bounds__(256) void k_assemble(const float* __restrict__ P0,
        const float* __restrict__ scores, const float* __restrict__ total,
        const float* __restrict__ cmean, const float* __restrict__ smean,
        const int* __restrict__ cntC, ushort* __restrict__ bA){
    const size_t S = (size_t)NMAT*MSZ;
    __shared__ ushort tH[64][136];
    __shared__ ushort tL[64][136];
    int mat = blockIdx.y;
    int tt = blockIdx.x;
    int ti, tj;
    if (tt < 4){ ti=0; tj=tt; }
    else if (tt < 7){ ti=1; tj=tt-3; }
    else if (tt < 9){ ti=2; tj=tt-5; }
    else { ti=3; tj=3; }
    int i0 = ti*128, j0 = tj*128;
    int t = threadIdx.x;
    ushort* bm = bA + (size_t)mat*2*MSZ;
    int k = mat - 8;
    float nOrTot = (mat < 8) ? (float)cntC[mat] : total[k];
    float inv_nm1 = 1.0f/(nOrTot - 1.0f);
    const float* mrow = (mat < 8) ? (cmean + mat*C_DIM) : (smean + k*C_DIM);
    for (int h = 0; h < 2; ++h){
        #pragma unroll
        for (int rep = 0; rep < 4; ++rep){
            int lin = rep*2048 + t*8;
            int r = lin >> 7;
            int c = lin & 127;
            int gr = i0 + h*64 + r;
            int gc = j0 + c;
            size_t e = (size_t)gr*C_DIM + gc;
            float s2[8];
            if (mat < 8){
                size_t b = (size_t)mat*MSZ + e;
                #pragma unroll
                for (int x=0;x<8;x++)
                    s2[x] = P0[b+x] + P0[b+S+x] + P0[b+2*S+x] + P0[b+3*S+x];
            } else {
                #pragma unroll
                for (int x=0;x<8;x++) s2[x] = 0.0f;
                #pragma unroll
                for (int jj=0;jj<8;jj++){
                    float sc = scores[k*8+jj];
                    size_t b = (size_t)(8+jj)*MSZ + e;
                    #pragma unroll
                    for (int x=0;x<8;x++)
                        s2[x] += sc*(P0[b+x] + P0[b+S+x] + P0[b+2*S+x] + P0[b+3*S+x]);
                }
            }
            float mi = mrow[gr];
            #pragma unroll
            for (int x=0;x<8;x++){
                float v = (s2[x] - nOrTot*mi*mrow[gc+x])*inv_nm1;
                if (mat < 8 && gr == gc+x) v += EPS_C;
                ushort hh,ll; split2(v,hh,ll);
                bm[e+x] = hh; bm[MSZ+e+x] = ll;
                tH[r][c+x] = hh; tL[r][c+x] = ll;
            }
        }
        if (ti != tj){
            __syncthreads();
            #pragma unroll
            for (int rep = 0; rep < 4; ++rep){
                int lin = rep*2048 + t*8;
                int rr = lin >> 6;
                int cc0 = lin & 63;
                size_t eo = (size_t)(j0+rr)*C_DIM + i0 + h*64 + cc0;
                #pragma unroll
                for (int x=0;x<8;x++){
                    bm[eo+x]     = tH[cc0+x][rr];
                    bm[MSZ+eo+x] = tL[cc0+x][rr];
                }
            }
            __syncthreads();
        }
    }
}

// ---------- A^2 row abs-sums via MFMA (no C write), 64x128 tiles ----------

__global__ __launch_bounds__(256) void k_mm_rowsum(
        const ushort* __restrict__ A, float* __restrict__ rowpart){
    __shared__ ushort As[2][4096];
    __shared__ ushort Bs[2][8192];
    __shared__ float rs[64][2];
    int wg = xcd_swz(blockIdx.x, NMAT*32);
    int mat = wg >> 5, tile = wg & 31;
    int ti = tile >> 2, tj = tile & 3;
    int i0 = ti*64, j0 = tj*128;
    const ushort* Am = A + (size_t)mat*2*MSZ;
    int t = threadIdx.x;
    int lane = t & 63, wave = t >> 6;
    int wm = wave >> 1, wn = wave & 1;
    int lr = lane & 15, lk = lane >> 4;
    f32x4 zero = {0.f,0.f,0.f,0.f};
    f32x4 acc[2][4];
    #pragma unroll
    for (int m=0;m<2;m++)
        #pragma unroll
        for (int n=0;n<4;n++) acc[m][n] = zero;
    mm_coreT<2>(Am, MSZ, C_DIM, Am, MSZ, C_DIM, i0, j0, 0, C_DIM,
                As, Bs, acc, wm, wn, lr, lk);
    #pragma unroll
    for (int m=0;m<2;m++)
        #pragma unroll
        for (int j=0;j<4;j++){
            float s = 0.0f;
            #pragma unroll
            for (int n=0;n<4;n++) s += fabsf(acc[m][n][j]);
            #pragma unroll
            for (int d=1; d<16; d<<=1) s += __shfl_xor(s, d);
            if (lr == 0) rs[wm*32 + m*16 + lk*4 + j][wn] = s;
        }
    __syncthreads();
    if (t < 64)
        rowpart[((size_t)mat*4 + tj)*512 + i0 + t] = rs[t][0] + rs[t][1];
}

__global__ __launch_bounds__(256) void k_tmax(const float* __restrict__ rowpart,
                                              float* __restrict__ tvals){
    int mat = blockIdx.x, t = threadIdx.x;
    const float* rp = rowpart + (size_t)mat*4*512;
    float mx = 0.0f;
    for (int r = t; r < 512; r += 256){
        float s = rp[r] + rp[512+r] + rp[1024+r] + rp[1536+r];
        mx = fmaxf(mx, s);
    }
    __shared__ float red[256];
    red[t] = mx; __syncthreads();
    for (int s=128; s>0; s>>=1){ if (t<s) red[t]=fmaxf(red[t],red[t+s]); __syncthreads(); }
    if (t == 0) tvals[mat] = sqrtf(red[0]);
}

// ---------- P0 = q(A/t) = 1.5I - 0.5*A/t (Y0 never materialized) ----------

__global__ __launch_bounds__(256) void k_initP0(const ushort* __restrict__ bA,
        const float* __restrict__ tvals, ushort* __restrict__ P){
    int mat = blockIdx.y;
    int e = blockIdx.x*256 + threadIdx.x;
    size_t base = (size_t)mat*2*MSZ;
    float inv = 1.0f / tvals[mat];
    float a = (bf2f(bA[base+e]) + bf2f(bA[base+MSZ+e])) * inv;
    int i = e >> 9, j = e & 511;
    float p = ((i==j)?1.5f:0.0f) - 0.5f*a;
    ushort h,l; split2(p,h,l);
    P[base + e] = h;
    P[base + MSZ + e] = l;
}

// ---------- generic 64x128-tile batched mm on split planes ----------
// EPI 0: split write; EPI 1: q(X) then split write; EPI 3: fp32 T + split M(ascale,diag);
// EPI 4: split write of acc/tvals[mat]  (Y1 = (A*P0)/t)

template<int EPI>
__global__ __launch_bounds__(256) void k_mm_ns64(
        const ushort* __restrict__ A, const ushort* __restrict__ B,
        ushort* __restrict__ Co, float* __restrict__ Cf,
        const float* __restrict__ tvals, int nmat){
    __shared__ ushort As[2][4096];
    __shared__ ushort Bs[2][8192];
    int wg = xcd_swz(blockIdx.x, nmat*32);
    int mat = wg >> 5, tile = wg & 31;
    int i0 = (tile>>2)*64, j0 = (tile&3)*128;
    const ushort* Am = A + (size_t)mat*2*MSZ;
    const ushort* Bm = B + (size_t)mat*2*MSZ;
    int t = threadIdx.x;
    int lane = t & 63, wave = t >> 6;
    int wm = wave >> 1, wn = wave & 1;
    int lr = lane & 15, lk = lane >> 4;
    f32x4 zero = {0.f,0.f,0.f,0.f};
    f32x4 acc[2][4];
    #pragma unroll
    for (int m=0;m<2;m++)
        #pragma unroll
        for (int n=0;n<4;n++) acc[m][n] = zero;
    mm_coreT<2>(Am, MSZ, C_DIM, Bm, MSZ, C_DIM, i0, j0, 0, C_DIM,
                As, Bs, acc, wm, wn, lr, lk);
    if (EPI == 3){
        float* Cm = Cf + (size_t)mat*MSZ;
        ushort* Mh = Co + (size_t)mat*2*MSZ;
        ushort* Ml = Mh + MSZ;
        float ascale = ALPHA_C * sqrtf(tvals[8+mat]/tvals[mat]);
        #pragma unroll
        for (int m=0;m<2;m++)
            #pragma unroll
            for (int n=0;n<4;n++)
                #pragma unroll
                for (int j=0;j<4;j++){
                    int gr = i0 + wm*32 + m*16 + lk*4 + j;
                    int gc = j0 + wn*64 + n*16 + lr;
                    float v = acc[m][n][j];
                    size_t idx = (size_t)gr*C_DIM + gc;
                    Cm[idx] = v;
                    float mv = ascale*v + ((gr==gc)?(1.0f-ALPHA_C):0.0f);
                    ushort h,l; split2(mv,h,l);
                    Mh[idx] = h; Ml[idx] = l;
                }
    } else {
        float sc = (EPI == 4) ? 1.0f/tvals[mat] : 1.0f;
        ushort* Ch = Co + (size_t)mat*2*MSZ;
        ushort* Cl = Ch + MSZ;
        #pragma unroll
        for (int m=0;m<2;m++)
            #pragma unroll
            for (int n=0;n<4;n++)
                #pragma unroll
                for (int j=0;j<4;j++){
                    int gr = i0 + wm*32 + m*16 + lk*4 + j;
                    int gc = j0 + wn*64 + n*16 + lr;
                    float v = acc[m][n][j];
                    if (EPI == 1) v = ((gr==gc)?1.5f:0.0f) - 0.5f*v;
                    if (EPI == 4) v *= sc;
                    ushort h,l; split2(v,h,l);
                    size_t idx = (size_t)gr*C_DIM + gc;
                    Ch[idx] = h;
                    Cl[idx] = l;
                }
    }
}

// ---------- merged NS stage 2 (128x128 tiles, full chip): fy = Y*qP, fz = qP*Z ----------

__global__ __launch_bounds__(256,2) void k_mm_ns2(
        const ushort* __restrict__ Y, const ushort* __restrict__ P,
        const ushort* __restrict__ Z, ushort* __restrict__ fy,
        ushort* __restrict__ fz){
    __shared__ ushort As[2][8192];
    __shared__ ushort Bs[2][8192];
    int wg = xcd_swz(blockIdx.x, NMAT*32);
    int mat = wg >> 5;
    int r = wg & 31;
    int op = r >> 4, tile = r & 15;
    int i0 = (tile>>2)*128, j0 = (tile&3)*128;
    const ushort* Am = (op ? P : Y) + (size_t)mat*2*MSZ;
    const ushort* Bm = (op ? Z : P) + (size_t)mat*2*MSZ;
    ushort* Ch = (op ? fz : fy) + (size_t)mat*2*MSZ;
    ushort* Cl = Ch + MSZ;
    int t = threadIdx.x;
    int lane = t & 63, wave = t >> 6;
    int wm = wave >> 1, wn = wave & 1;
    int lr = lane & 15, lk = lane >> 4;
    f32x4 zero = {0.f,0.f,0.f,0.f};
    f32x4 acc[4][4];
    #pragma unroll
    for (int m=0;m<4;m++)
        #pragma unroll
        for (int n=0;n<4;n++) acc[m][n] = zero;
    mm_coreT<4>(Am, MSZ, C_DIM, Bm, MSZ, C_DIM, i0, j0, 0, C_DIM,
                As, Bs, acc, wm, wn, lr, lk);
    #pragma unroll
    for (int m=0;m<4;m++)
        #pragma unroll
        for (int n=0;n<4;n++)
            #pragma unroll
            for (int j=0;j<4;j++){
                int gr = i0 + wm*64 + m*16 + lk*4 + j;
                int gc = j0 + wn*64 + n*16 + lr;
                ushort h,l; split2(acc[m][n][j],h,l);
                size_t idx = (size_t)gr*C_DIM + gc;
                Ch[idx] = h;
                Cl[idx] = l;
            }
}

// ---------- last NS stage 2 (64x128 tiles): only consumed halves ----------

__global__ __launch_bounds__(256) void k_mm_ns2_last(
        const ushort* __restrict__ Y, const ushort* __restrict__ P,
        const ushort* __restrict__ Z, ushort* __restrict__ fy,
        ushort* __restrict__ fz){
    __shared__ ushort As[2][4096];
    __shared__ ushort Bs[2][8192];
    int wg = xcd_swz(blockIdx.x, NMAT*32);
    int mat = wg >> 5, tile = wg & 31;
    int op = (mat < 8) ? 1 : 0;         // content: fz = P*Z ; style: fy = Y*P
    int i0 = (tile>>2)*64, j0 = (tile&3)*128;
    const ushort* Am = (op ? P : Y) + (size_t)mat*2*MSZ;
    const ushort* Bm = (op ? Z : P) + (size_t)mat*2*MSZ;
    ushort* Ch = (op ? fz : fy) + (size_t)mat*2*MSZ;
    ushort* Cl = Ch + MSZ;
    int t = threadIdx.x;
    int lane = t & 63, wave = t >> 6;
    int wm = wave >> 1, wn = wave & 1;
    int lr = lane & 15, lk = lane >> 4;
    f32x4 zero = {0.f,0.f,0.f,0.f};
    f32x4 acc[2][4];
    #pragma unroll
    for (int m=0;m<2;m++)
        #pragma unroll
        for (int n=0;n<4;n++) acc[m][n] = zero;
    mm_coreT<2>(Am, MSZ, C_DIM, Bm, MSZ, C_DIM, i0, j0, 0, C_DIM,
                As, Bs, acc, wm, wn, lr, lk);
    #pragma unroll
    for (int m=0;m<2;m++)
        #pragma unroll
        for (int n=0;n<4;n++)
            #pragma unroll
            for (int j=0;j<4;j++){
                int gr = i0 + wm*32 + m*16 + lk*4 + j;
                int gc = j0 + wn*64 + n*16 + lr;
                ushort h,l; split2(acc[m][n][j],h,l);
                size_t idx = (size_t)gr*C_DIM + gc;
                Ch[idx] = h;
                Cl[idx] = l;
            }
}

// ---------- bias vector: vvec = alpha*smean - ascale*(T cmean) ----------

__global__ __launch_bounds__(256) void k_buildV(const float* __restrict__ T,
        const float* __restrict__ tvals, const float* __restrict__ cmean,
        const float* __restrict__ smean, float* __restrict__ vvec){
    __shared__ float cm[512];
    int k = blockIdx.x, t = threadIdx.x;
    cm[t] = cmean[k*C_DIM + t];
    cm[t+256] = cmean[k*C_DIM + t + 256];
    __syncthreads();
    float scale = ALPHA_C * sqrtf(tvals[8+k]/tvals[k]);
    int c = blockIdx.y*256 + t;
    const float* row = T + (size_t)k*MSZ + (size_t)c*C_DIM;
    float s = 0.0f;
    for (int d=0; d<C_DIM; d++) s = fmaf(row[d], cm[d], s);
    vvec[k*C_DIM + c] = ALPHA_C*smean[k*C_DIM + c] - scale*s;
}

// ---------- MFMA apply: Sg = M*Xc + v in gathered order (coalesced) ----------

__global__ __launch_bounds__(256,2) void k_apply_mfma(
        const ushort* __restrict__ Msp, const ushort* __restrict__ XT,
        const float* __restrict__ vvec, const int* __restrict__ offPad,
        float* __restrict__ Sg){
    __shared__ ushort As[2][8192];
    __shared__ ushort Bs[2][8192];
    __shared__ int so[9];
    int t = threadIdx.x;
    if (t < 9) so[t] = offPad[t];
    __syncthreads();
    int wg = xcd_swz(blockIdx.x, (CAP/128)*4);
    int j0 = (wg>>2)*128;
    int i0 = (wg&3)*128;
    if (j0 >= so[8]) return;
    int cl = 0;
    while (cl < 7 && j0 >= so[cl+1]) cl++;
    const ushort* Am = Msp + (size_t)cl*2*MSZ;
    int lane = t & 63, wave = t >> 6;
    int wm = wave >> 1, wn = wave & 1;
    int lr = lane & 15, lk = lane >> 4;
    f32x4 zero = {0.f,0.f,0.f,0.f};
    f32x4 acc[4][4];
    #pragma unroll
    for (int m=0;m<4;m++)
        #pragma unroll
        for (int n=0;n<4;n++) acc[m][n] = zero;
    mm_coreT<4>(Am, MSZ, C_DIM, XT, (size_t)CAP*C_DIM, C_DIM, i0, j0, 0, C_DIM,
                As, Bs, acc, wm, wn, lr, lk);
    #pragma unroll
    for (int m=0;m<4;m++)
        #pragma unroll
        for (int nn=0;nn<4;nn++)
            #pragma unroll
            for (int j=0;j<4;j++){
                int gr = i0 + wm*64 + m*16 + lk*4 + j;
                int gc = j0 + wn*64 + nn*16 + lr;
                Sg[(size_t)gr*CAP + gc] = acc[m][nn][j] + vvec[cl*C_DIM + gr];
            }
}

// ---------- scatter: out[c][p] = Sg[c][ginv[p]] (coalesced writes) ----------

__global__ __launch_bounds__(256) void k_scatter(const float* __restrict__ Sg,
        const int* __restrict__ ginv, float* __restrict__ out){
    size_t idx = (size_t)blockIdx.x*256 + threadIdx.x;
    int p = (int)(idx & (WH-1));
    int c = (int)(idx >> 14);
    out[idx] = Sg[(size_t)c*CAP + ginv[p]];
}

// ---------- host ----------

extern "C" void kernel_launch(void* const* d_in, const int* in_sizes, int n_in,
                              void* d_out, int out_size, void* d_ws, size_t ws_size,
                              hipStream_t stream) {
    (void)in_sizes; (void)n_in;
    const float* cf     = (const float*)d_in[0];
    const float* sf     = (const float*)d_in[1];
    const float* scores = (const float*)d_in[2];
    const int*   cl     = (const int*)d_in[3];
    const int*   sl     = (const int*)d_in[4];
    float* out = (float*)d_out;
    float* ws  = (float*)d_ws;

    size_t o = 0;
    ushort* XcH = (ushort*)(ws + o);
    float*  Sg  = ws + o;       o += (size_t)C_DIM*CAP;
    ushort* XcL = XcH + (size_t)C_DIM*CAP;
    ushort* XsH = (ushort*)(ws + o); o += (size_t)C_DIM*CAP;
    float* S4  = ws + o; o += (size_t)NMAT*MSZ;
    float* NS0 = ws + o; o += (size_t)4*NMAT*MSZ;
    float* cmean = ws + o; o += 8*C_DIM;
    float* ssum  = ws + o; o += 8*C_DIM;
    float* smean = ws + o; o += 8*C_DIM;
    float* vvec  = ws + o; o += 8*C_DIM;
    float* tvals = ws + o; o += 16;
    float* rowpart = ws + o; o += (size_t)NMAT*4*512;
    float* total = ws + o; o += 8;
    float* psumC = ws + o; o += (size_t)C_DIM*NBX;
    float* psumS = ws + o; o += (size_t)C_DIM*NBX;
    int* ip = (int*)(ws + o);
    int* permC    = ip; ip += CAP;
    int* permCinv = ip; ip += CAP;
    int* permS    = ip; ip += CAP;
    int* segOfC = ip; ip += NBX;
    int* segOfS = ip; ip += NBX;
    int* cntC  = ip; ip += 8;
    int* cntS  = ip; ip += 8;
    int* offC  = ip; ip += 9;
    int* offS  = ip; ip += 9;
    int* chC   = ip; ip += NCHUNK*8;
    int* chS   = ip; ip += NCHUNK*8;
    int* baseC = ip; ip += NCHUNK*8;
    int* baseS = ip; ip += NCHUNK*8;
    size_t need_bytes = (size_t)((char*)ip - (char*)d_ws);
    if (ws_size < need_bytes){
        hipMemcpyAsync(d_out, (const void*)cf, (size_t)out_size*sizeof(float),
                       hipMemcpyDeviceToDevice, stream);
        return;
    }
    float* Pf = NS0;
    ushort* s0 = (ushort*)(NS0 + 0*(size_t)NMAT*MSZ);
    ushort* s1 = (ushort*)(NS0 + 1*(size_t)NMAT*MSZ);
    ushort* s2 = (ushort*)(NS0 + 2*(size_t)NMAT*MSZ);
    ushort* s3 = (ushort*)(NS0 + 3*(size_t)NMAT*MSZ);
    ushort* s4 = (ushort*)S4;

    k_chunk_hist<<<dim3(NCHUNK,2),256,0,stream>>>(cl, sl, chC, chS);
    k_scan<<<1,64,0,stream>>>(chC, chS, cntC, cntS, offC, offS, baseC, baseS);
    k_place<<<dim3(NCHUNK,2),64,0,stream>>>(cl, sl, baseC, baseS, permC, permS, permCinv);

    // gather + split + fused cluster partial sums (content z=0, style z=1)
    dim3 gg(NBX, C_DIM/16, 2);
    k_gather2<<<gg,256,0,stream>>>(cf, sf, permC, permS, offC, offS, cntC, cntS,
                                   XcH, XcL, XsH, XsH + (size_t)C_DIM*CAP,
                                   psumC, psumS, segOfC, segOfS);

    k_meanred<<<dim3(8,2,2),256,0,stream>>>(psumC, psumS, segOfC, segOfS, cntC,
                                            cmean, ssum);
    k_style_mean<<<1,256,0,stream>>>(scores, cntS, ssum, total, smean);

    k_syrk_mfma<<<NMAT*NSLICE*10,256,0,stream>>>(XcH, XsH, offC, offS, Pf);

    k_transpose<<<dim3(CAP/64, C_DIM/64, 2),256,0,stream>>>(XcH, XsH);
    ushort* XT = XsH;

    ushort* bA = s4;
    k_assemble<<<dim3(10,16),256,0,stream>>>(Pf, scores, total, cmean, smean, cntC, bA);

    k_mm_rowsum<<<NMAT*32,256,0,stream>>>(bA, rowpart);
    k_tmax<<<NMAT,256,0,stream>>>(rowpart, tvals);

    // iteration 0 (collapsed): P0 = q(A/t) elementwise; Y1 = (A*P0)/t (scale in
    // epilogue, A read directly from bA planes); Z1 = P0 (alias)
    k_initP0<<<dim3(MSZ/256,NMAT),256,0,stream>>>(bA, tvals, s1);
    k_mm_ns64<4><<<NMAT*32,256,0,stream>>>(bA, s1, s2, nullptr, tvals, NMAT);

    ushort* bY = s2;  ushort* bZ = s1;  ushort* bP = s3;
    ushort* fy = s4;  ushort* fz = s0;   // s4 = bA slot (dead after ns64<4>), s0 unused
    for (int it=0; it<NIT-1; ++it){
        k_mm_ns64<1><<<NMAT*32,256,0,stream>>>(bZ, bY, bP, nullptr, nullptr, NMAT); // P=q(Z*Y)
        if (it < NIT-2)
            k_mm_ns2<<<NMAT*32,256,0,stream>>>(bY, bP, bZ, fy, fz);
        else
            k_mm_ns2_last<<<NMAT*32,256,0,stream>>>(bY, bP, bZ, fy, fz);
        ushort* t1;
        t1 = bY; bY = fy; fy = t1;
        t1 = bZ; bZ = fz; fz = t1;
    }
    // T[k] = Y_style[8+k] * Z_content[k]: fp32 T + split M in one pass
    float* Tf = (float*)fy;
    ushort* Msp = fz;
    k_mm_ns64<3><<<8*32,256,0,stream>>>(bY + (size_t)8*2*MSZ, bZ, Msp, Tf, tvals, 8);

    k_buildV<<<dim3(8,2),256,0,stream>>>(Tf, tvals, cmean, smean, vvec);

    k_apply_mfma<<<(CAP/128)*4,256,0,stream>>>(Msp, XT, vvec, offC, Sg);
    k_scatter<<<(C_DIM*WH)/256,256,0,stream>>>(Sg, permCinv, out);
}

// Round 12
// 520.332 us; speedup vs baseline: 2.3505x; 1.0752x over previous
//
#include <hip/hip_runtime.h>
#include <math.h>

#define C_DIM 512
#define WH    16384
#define CAP   17408      // 16384 + 8*128 worst-case padding
#define NBX   136        // CAP/128
#define SEG_ALIGN 128
#define NCHUNK 64
#define CHUNK  256
#define NMAT 16
#define NSLICE 4
#define MSZ  (C_DIM*C_DIM)
#define ALPHA_C 0.8f
#define EPS_C   1e-6f
#define NIT 5            // total q-applications: 1 collapsed + 4 full (halved-t start)

typedef __attribute__((ext_vector_type(8))) __bf16 bfrag;
typedef __attribute__((ext_vector_type(4))) float f32x4;

__device__ inline float bf2f(ushort h){ return __uint_as_float(((unsigned)h)<<16); }
__device__ inline void split2(float v, ushort& h, ushort& l){
    unsigned u = __float_as_uint(v);
    h = (ushort)(u >> 16);
    float r = v - __uint_as_float(u & 0xffff0000u);
    l = (ushort)(__float_as_uint(r) >> 16);
}

__device__ __forceinline__ int xcd_swz(int bid, int nwg){
    int c = nwg >> 3;
    return (bid & 7)*c + (bid >> 3);
}

__device__ __forceinline__ void gload16(const void* g, void* l){
    __builtin_amdgcn_global_load_lds(
        (const __attribute__((address_space(1))) unsigned int*)g,
        (__attribute__((address_space(3))) unsigned int*)l, 16, 0, 0);
}

// stage one R x 64 bf16 panel (R = 64 or 128): LDS linear, source pre-swizzled
template<int R>
__device__ __forceinline__ void stage_panelR(const ushort* __restrict__ src,
        int stride, int i0, int k0, ushort* lds){
    int t = threadIdx.x;
    #pragma unroll
    for (int i = 0; i < R/32; ++i){
        int slot = t + i*256;
        int row = slot >> 3, c8 = slot & 7;
        const ushort* g = src + (size_t)(i0+row)*stride + k0 + ((c8 ^ (row&7))<<3);
        gload16((const void*)g, (void*)&lds[(size_t)(i*256 + (t & 192))*8]);
    }
}

// MFMA inner block: (2*MFR*16) x 128 tile, K=64 step, split-3 products
template<int MFR>
__device__ __forceinline__ void mfma_block(const ushort* As0, const ushort* As1,
        const ushort* Bs0, const ushort* Bs1, f32x4 (&acc)[MFR][4],
        int wm, int wn, int lr, int lk){
    #pragma unroll
    for (int kk = 0; kk < 64; kk += 32){
        bfrag ah[MFR], al[MFR], bh[4], bl[4];
        #pragma unroll
        for (int m = 0; m < MFR; ++m){
            int row = wm*(MFR*16) + m*16 + lr;
            int off = (row*64 + kk + lk*8) ^ ((row&7)<<3);
            ah[m] = *(const bfrag*)&As0[off];
            al[m] = *(const bfrag*)&As1[off];
        }
        #pragma unroll
        for (int n = 0; n < 4; ++n){
            int row = wn*64 + n*16 + lr;
            int off = (row*64 + kk + lk*8) ^ ((row&7)<<3);
            bh[n] = *(const bfrag*)&Bs0[off];
            bl[n] = *(const bfrag*)&Bs1[off];
        }
        #pragma unroll
        for (int m = 0; m < MFR; ++m)
            #pragma unroll
            for (int n = 0; n < 4; ++n){
                acc[m][n] = __builtin_amdgcn_mfma_f32_16x16x32_bf16(ah[m], bh[n], acc[m][n], 0,0,0);
                acc[m][n] = __builtin_amdgcn_mfma_f32_16x16x32_bf16(ah[m], bl[n], acc[m][n], 0,0,0);
                acc[m][n] = __builtin_amdgcn_mfma_f32_16x16x32_bf16(al[m], bh[n], acc[m][n], 0,0,0);
            }
    }
}

// unified K-loop: C((2*MFR*16)x128) += A * B^T on split planes
template<int MFR>
__device__ __forceinline__ void mm_coreT(const ushort* __restrict__ Am, size_t aPl, int aStr,
        const ushort* __restrict__ Bm, size_t bPl, int bStr,
        int i0, int j0, int kLo, int kHi,
        ushort (&As)[2][MFR*2048], ushort (&Bs)[2][8192], f32x4 (&acc)[MFR][4],
        int wm, int wn, int lr, int lk){
    for (int k0 = kLo; k0 < kHi; k0 += 64){
        stage_panelR<MFR*32>(Am,       aStr, i0, k0, As[0]);
        stage_panelR<MFR*32>(Am + aPl, aStr, i0, k0, As[1]);
        stage_panelR<128>(Bm,       bStr, j0, k0, Bs[0]);
        stage_panelR<128>(Bm + bPl, bStr, j0, k0, Bs[1]);
        __syncthreads();
        mfma_block<MFR>(As[0], As[1], Bs[0], Bs[1], acc, wm, wn, lr, lk);
        __syncthreads();
    }
}

// ---------- label bookkeeping (deterministic counting sort), content+style merged ----------

__global__ __launch_bounds__(256) void k_chunk_hist(const int* __restrict__ lab0,
        const int* __restrict__ lab1, int* __restrict__ ch0, int* __restrict__ ch1){
    __shared__ int h[8];
    int t = threadIdx.x;
    const int* labels = blockIdx.y ? lab1 : lab0;
    int* chunkCnt = blockIdx.y ? ch1 : ch0;
    if (t < 8) h[t] = 0;
    __syncthreads();
    int l = labels[blockIdx.x*CHUNK + t];
    atomicAdd(&h[l], 1);
    __syncthreads();
    if (t < 8) chunkCnt[blockIdx.x*8 + t] = h[t];
}

__global__ void k_scan(const int* __restrict__ ch0, const int* __restrict__ ch1,
                       int* __restrict__ cnt0, int* __restrict__ cnt1,
                       int* __restrict__ off0, int* __restrict__ off1,
                       int* __restrict__ base0, int* __restrict__ base1){
    int which = threadIdx.x;
    if (which >= 2) return;
    const int* chunkCnt = which ? ch1 : ch0;
    int* cnt = which ? cnt1 : cnt0;
    int* offPad = which ? off1 : off0;
    int* base = which ? base1 : base0;
    int c[8];
    for (int k=0;k<8;k++) c[k]=0;
    for (int ch=0; ch<NCHUNK; ch++)
        for (int k=0;k<8;k++) c[k] += chunkCnt[ch*8+k];
    int off = 0;
    for (int k=0;k<8;k++){
        cnt[k] = c[k];
        offPad[k] = off;
        off += ((c[k] + SEG_ALIGN - 1)/SEG_ALIGN)*SEG_ALIGN;
    }
    offPad[8] = off;
    for (int k=0;k<8;k++){
        int run = offPad[k];
        for (int ch=0; ch<NCHUNK; ch++){
            base[ch*8+k] = run;
            run += chunkCnt[ch*8+k];
        }
    }
}

__global__ void k_place(const int* __restrict__ lab0, const int* __restrict__ lab1,
        const int* __restrict__ base0, const int* __restrict__ base1,
        int* __restrict__ perm0, int* __restrict__ perm1, int* __restrict__ inv0){
    int t = threadIdx.x;
    if (t >= 8) return;
    const int* labels = blockIdx.y ? lab1 : lab0;
    const int* base = blockIdx.y ? base1 : base0;
    int* perm = blockIdx.y ? perm1 : perm0;
    int* inv = blockIdx.y ? nullptr : inv0;
    int ch = blockIdx.x;
    int pos = base[ch*8+t];
    int s = ch*CHUNK;
    for (int i=0;i<CHUNK;i++){
        if (labels[s+i] == t){
            perm[pos] = s+i;
            if (inv) inv[s+i] = pos;
            pos++;
        }
    }
}

// ---------- gather + split + fused per-cluster partial sums (content & style via z) ----------

__global__ __launch_bounds__(256) void k_gather2(const float* __restrict__ src0,
        const float* __restrict__ src1,
        const int* __restrict__ perm0, const int* __restrict__ perm1,
        const int* __restrict__ off0, const int* __restrict__ off1,
        const int* __restrict__ cnt0, const int* __restrict__ cnt1,
        ushort* __restrict__ dH0, ushort* __restrict__ dL0,
        ushort* __restrict__ dH1, ushort* __restrict__ dL1,
        float* __restrict__ ps0, float* __restrict__ ps1,
        int* __restrict__ sg0, int* __restrict__ sg1){
    int z = blockIdx.z;
    const float* src = z ? src1 : src0;
    const int* perm = z ? perm1 : perm0;
    const int* offPad = z ? off1 : off0;
    const int* cnt = z ? cnt1 : cnt0;
    ushort* dstH = z ? dH1 : dH0;
    ushort* dstL = z ? dL1 : dL0;
    float* psum = z ? ps1 : ps0;
    int* segOf = z ? sg1 : sg0;
    __shared__ int so[9], sc[8];
    __shared__ int pcache[128];
    int t = threadIdx.x;
    if (t < 9) so[t] = offPad[t];
    if (t < 8) sc[t] = cnt[t];
    __syncthreads();
    int bx = blockIdx.x;
    int i0 = bx*128;
    if (t < 128) pcache[t] = (i0 + t < so[8]) ? perm[i0 + t] : 0;
    __syncthreads();
    int k = 0;
    while (k < 7 && i0 >= so[k+1]) k++;
    int n = sc[k], s0 = so[k];
    int ch = t >> 4, px0 = (t & 15)*8;
    int c  = blockIdx.y*16 + ch;
    const float* row = src + (size_t)c*WH;
    float v[8];
    #pragma unroll
    for (int x=0;x<8;x++){
        int i = i0 + px0 + x;
        v[x] = (i - s0 < n) ? row[pcache[px0+x]] : 0.0f;
    }
    float s = 0.0f;
    ushort hv[8], lv[8];
    #pragma unroll
    for (int x=0;x<8;x++){
        s += v[x];
        split2(v[x], hv[x], lv[x]);
    }
    *(uint4*)&dstH[(size_t)c*CAP + i0 + px0] = *(uint4*)hv;
    *(uint4*)&dstL[(size_t)c*CAP + i0 + px0] = *(uint4*)lv;
    #pragma unroll
    for (int d=1; d<16; d<<=1) s += __shfl_xor(s, d, 16);
    if ((t & 15) == 0) psum[(size_t)c*NBX + bx] = s;
    if (t == 0) segOf[bx] = k;
}

// ---------- reduce partials -> per-cluster sums/means (z: 0=content mean, 1=style sum) ----------

__global__ __launch_bounds__(256) void k_meanred(const float* __restrict__ ps0,
        const float* __restrict__ ps1, const int* __restrict__ sg0,
        const int* __restrict__ sg1, const int* __restrict__ cnt0,
        float* __restrict__ out0, float* __restrict__ out1){
    int z = blockIdx.z;
    const float* psum = z ? ps1 : ps0;
    const int* segOf = z ? sg1 : sg0;
    float* out = z ? out1 : out0;
    int k = blockIdx.x;
    int c = blockIdx.y*256 + threadIdx.x;
    float s = 0.0f;
    for (int bx=0; bx<NBX; bx++)
        if (segOf[bx] == k) s += psum[(size_t)c*NBX + bx];
    out[k*C_DIM + c] = z ? s : s/(float)cnt0[k];
}

// ---------- transpose plane: [512][CAP] -> [CAP][512] ----------

__global__ __launch_bounds__(256) void k_transpose(const ushort* __restrict__ S,
                                                   ushort* __restrict__ D){
    __shared__ ushort tile[64][72];
    int p = blockIdx.z;
    const ushort* Sp = S + (size_t)p*C_DIM*CAP;
    ushort* Dp = D + (size_t)p*CAP*C_DIM;
    int cb = blockIdx.x*64;
    int rb = blockIdx.y*64;
    int t = threadIdx.x;
    int tr = t >> 3, tc = t & 7;
    #pragma unroll
    for (int i=0;i<2;i++){
        int r = tr + i*32;
        uint4 v = *(const uint4*)&Sp[(size_t)(rb+r)*CAP + cb + tc*8];
        ushort* u = (ushort*)&v;
        #pragma unroll
        for (int j=0;j<8;j++) tile[tc*8+j][r] = u[j];
    }
    __syncthreads();
    #pragma unroll
    for (int i=0;i<2;i++){
        int r = tr + i*32;
        uint4 v;
        ushort* u = (ushort*)&v;
        #pragma unroll
        for (int j=0;j<8;j++) u[j] = tile[r][tc*8+j];
        *(uint4*)&Dp[(size_t)(cb+r)*C_DIM + rb + tc*8] = v;
    }
}

__global__ __launch_bounds__(256) void k_style_mean(const float* __restrict__ scores,
        const int* __restrict__ cntS, const float* __restrict__ ssum,
        float* __restrict__ total, float* __restrict__ smean){
    int t = threadIdx.x;
    __shared__ float tot[8];
    if (t < 8){
        float s = 0.0f;
        for (int j=0;j<8;j++) s += scores[t*8+j]*(float)cntS[j];
        tot[t] = s; total[t] = s;
    }
    __syncthreads();
    for (int idx=t; idx<8*C_DIM; idx+=256){
        int k = idx / C_DIM, c = idx % C_DIM;
        float s = 0.0f;
        for (int j=0;j<8;j++) s += scores[k*8+j]*ssum[j*C_DIM+c];
        smean[idx] = s / tot[k];
    }
}

// ---------- MFMA SYRK: partial S2 = X X^T, triangular tiles, split-K ----------

__global__ __launch_bounds__(256,2) void k_syrk_mfma(
        const ushort* __restrict__ Xc, const ushort* __restrict__ Xs,
        const int* __restrict__ offC, const int* __restrict__ offS,
        float* __restrict__ Pf){
    __shared__ ushort As[2][8192];
    __shared__ ushort Bs[2][8192];
    int wg = xcd_swz(blockIdx.x, NMAT*NSLICE*10);
    int mat = wg / (NSLICE*10);
    int rem = wg % (NSLICE*10);
    int slice = rem / 10, tt = rem % 10;
    int ti, tj;
    if (tt < 4){ ti=0; tj=tt; }
    else if (tt < 7){ ti=1; tj=tt-3; }
    else if (tt < 9){ ti=2; tj=tt-5; }
    else { ti=3; tj=3; }
    const ushort* X = (mat < 8) ? Xc : Xs;
    const int* offP = (mat < 8) ? offC : offS;
    int cl = mat & 7;
    int off = offP[cl], npad = offP[cl+1] - off;
    int i0 = ti*128, j0 = tj*128;
    int L = ((npad + NSLICE*64 - 1)/(NSLICE*64))*64;
    int k_lo = slice*L;
    int k_hi = min(k_lo + L, npad);
    int t = threadIdx.x;
    int lane = t & 63, wave = t >> 6;
    int wm = wave >> 1, wn = wave & 1;
    int lr = lane & 15, lk = lane >> 4;
    f32x4 zero = {0.f,0.f,0.f,0.f};
    f32x4 acc[4][4];
    #pragma unroll
    for (int m=0;m<4;m++)
        #pragma unroll
        for (int n=0;n<4;n++) acc[m][n] = zero;
    mm_coreT<4>(X + off, (size_t)C_DIM*CAP, CAP,
                X + off, (size_t)C_DIM*CAP, CAP,
                i0, j0, k_lo, k_hi, As, Bs, acc, wm, wn, lr, lk);
    float* O = Pf + ((size_t)(slice*16 + mat))*MSZ;
    #pragma unroll
    for (int m=0;m<4;m++)
        #pragma unroll
        for (int n=0;n<4;n++)
            #pragma unroll
            for (int j=0;j<4;j++){
                int gr = i0 + wm*64 + m*16 + lk*4 + j;
                int gc = j0 + wn*64 + n*16 + lr;
                O[(size_t)gr*C_DIM + gc] = acc[m][n][j];
            }
}

// ---------- assemble A (tile-based, coalesced, LDS mirror) -> split planes ----------

__global__ __launch_bounds__(256) void k_assemble(const float* __restrict__ P0,
        const float* __restrict__ scores, const float* __restrict__ total,
        const float* __restrict__ cmean, const float* __restrict__ smean,
        const int* __restrict__ cntC, ushort* __restrict__ bA){
    const size_t S = (size_t)NMAT*MSZ;
    __shared__ ushort tH[64][136];
    __shared__ ushort tL[64][136];
    int mat = blockIdx.y;
    int tt = blockIdx.x;
    int ti, tj;
    if (tt < 4){ ti=0; tj=tt; }
    else if (tt < 7){ ti=1; tj=tt-3; }
    else if (tt < 9){ ti=2; tj=tt-5; }
    else { ti=3; tj=3; }
    int i0 = ti*128, j0 = tj*128;
    int t = threadIdx.x;
    ushort* bm = bA + (size_t)mat*2*MSZ;
    int k = mat - 8;
    float nOrTot = (mat < 8) ? (float)cntC[mat] : total[k];
    float inv_nm1 = 1.0f/(nOrTot - 1.0f);
    const float* mrow = (mat < 8) ? (cmean + mat*C_DIM) : (smean + k*C_DIM);
    for (int h = 0; h < 2; ++h){
        #pragma unroll
        for (int rep = 0; rep < 4; ++rep){
            int lin = rep*2048 + t*8;
            int r = lin >> 7;
            int c = lin & 127;
            int gr = i0 + h*64 + r;
            int gc = j0 + c;
            size_t e = (size_t)gr*C_DIM + gc;
            float s2[8];
            if (mat < 8){
                size_t b = (size_t)mat*MSZ + e;
                #pragma unroll
                for (int x=0;x<8;x++)
                    s2[x] = P0[b+x] + P0[b+S+x] + P0[b+2*S+x] + P0[b+3*S+x];
            } else {
                #pragma unroll
                for (int x=0;x<8;x++) s2[x] = 0.0f;
                #pragma unroll
                for (int jj=0;jj<8;jj++){
                    float sc = scores[k*8+jj];
                    size_t b = (size_t)(8+jj)*MSZ + e;
                    #pragma unroll
                    for (int x=0;x<8;x++)
                        s2[x] += sc*(P0[b+x] + P0[b+S+x] + P0[b+2*S+x] + P0[b+3*S+x]);
                }
            }
            float mi = mrow[gr];
            #pragma unroll
            for (int x=0;x<8;x++){
                float v = (s2[x] - nOrTot*mi*mrow[gc+x])*inv_nm1;
                if (mat < 8 && gr == gc+x) v += EPS_C;
                ushort hh,ll; split2(v,hh,ll);
                bm[e+x] = hh; bm[MSZ+e+x] = ll;
                tH[r][c+x] = hh; tL[r][c+x] = ll;
            }
        }
        if (ti != tj){
            __syncthreads();
            #pragma unroll
            for (int rep = 0; rep < 4; ++rep){
                int lin = rep*2048 + t*8;
                int rr = lin >> 6;
                int cc0 = lin & 63;
                size_t eo = (size_t)(j0+rr)*C_DIM + i0 + h*64 + cc0;
                #pragma unroll
                for (int x=0;x<8;x++){
                    bm[eo+x]     = tH[cc0+x][rr];
                    bm[MSZ+eo+x] = tL[cc0+x][rr];
                }
            }
            __syncthreads();
        }
    }
}

// ---------- A^2 row abs-sums via MFMA (no C write), 64x128 tiles ----------

__global__ __launch_bounds__(256) void k_mm_rowsum(
        const ushort* __restrict__ A, float* __restrict__ rowpart){
    __shared__ ushort As[2][4096];
    __shared__ ushort Bs[2][8192];
    __shared__ float rs[64][2];
    int wg = xcd_swz(blockIdx.x, NMAT*32);
    int mat = wg >> 5, tile = wg & 31;
    int ti = tile >> 2, tj = tile & 3;
    int i0 = ti*64, j0 = tj*128;
    const ushort* Am = A + (size_t)mat*2*MSZ;
    int t = threadIdx.x;
    int lane = t & 63, wave = t >> 6;
    int wm = wave >> 1, wn = wave & 1;
    int lr = lane & 15, lk = lane >> 4;
    f32x4 zero = {0.f,0.f,0.f,0.f};
    f32x4 acc[2][4];
    #pragma unroll
    for (int m=0;m<2;m++)
        #pragma unroll
        for (int n=0;n<4;n++) acc[m][n] = zero;
    mm_coreT<2>(Am, MSZ, C_DIM, Am, MSZ, C_DIM, i0, j0, 0, C_DIM,
                As, Bs, acc, wm, wn, lr, lk);
    #pragma unroll
    for (int m=0;m<2;m++)
        #pragma unroll
        for (int j=0;j<4;j++){
            float s = 0.0f;
            #pragma unroll
            for (int n=0;n<4;n++) s += fabsf(acc[m][n][j]);
            #pragma unroll
            for (int d=1; d<16; d<<=1) s += __shfl_xor(s, d);
            if (lr == 0) rs[wm*32 + m*16 + lk*4 + j][wn] = s;
        }
    __syncthreads();
    if (t < 64)
        rowpart[((size_t)mat*4 + tj)*512 + i0 + t] = rs[t][0] + rs[t][1];
}

// ---------- t = 0.5*sqrt(max row sum of |A^2|); NS converges for p in (0,3) ----------

__global__ __launch_bounds__(256) void k_tmax(const float* __restrict__ rowpart,
                                              float* __restrict__ tvals){
    int mat = blockIdx.x, t = threadIdx.x;
    const float* rp = rowpart + (size_t)mat*4*512;
    float mx = 0.0f;
    for (int r = t; r < 512; r += 256){
        float s = rp[r] + rp[512+r] + rp[1024+r] + rp[1536+r];
        mx = fmaxf(mx, s);
    }
    __shared__ float red[256];
    red[t] = mx; __syncthreads();
    for (int s=128; s>0; s>>=1){ if (t<s) red[t]=fmaxf(red[t],red[t+s]); __syncthreads(); }
    if (t == 0) tvals[mat] = 0.5f*sqrtf(red[0]);
}

// ---------- P0 = q(A/t) = 1.5I - 0.5*A/t (Y0 never materialized) ----------

__global__ __launch_bounds__(256) void k_initP0(const ushort* __restrict__ bA,
        const float* __restrict__ tvals, ushort* __restrict__ P){
    int mat = blockIdx.y;
    int e = blockIdx.x*256 + threadIdx.x;
    size_t base = (size_t)mat*2*MSZ;
    float inv = 1.0f / tvals[mat];
    float a = (bf2f(bA[base+e]) + bf2f(bA[base+MSZ+e])) * inv;
    int i = e >> 9, j = e & 511;
    float p = ((i==j)?1.5f:0.0f) - 0.5f*a;
    ushort h,l; split2(p,h,l);
    P[base + e] = h;
    P[base + MSZ + e] = l;
}

// ---------- generic 64x128-tile batched mm on split planes ----------
// EPI 0: split write; EPI 1: q(X) then split write; EPI 3: fp32 T + split M(ascale,diag);
// EPI 4: split write of acc/tvals[mat]  (Y1 = (A*P0)/t)

template<int EPI>
__global__ __launch_bounds__(256) void k_mm_ns64(
        const ushort* __restrict__ A, const ushort* __restrict__ B,
        ushort* __restrict__ Co, float* __restrict__ Cf,
        const float* __restrict__ tvals, int nmat){
    __shared__ ushort As[2][4096];
    __shared__ ushort Bs[2][8192];
    int wg = xcd_swz(blockIdx.x, nmat*32);
    int mat = wg >> 5, tile = wg & 31;
    int i0 = (tile>>2)*64, j0 = (tile&3)*128;
    const ushort* Am = A + (size_t)mat*2*MSZ;
    const ushort* Bm = B + (size_t)mat*2*MSZ;
    int t = threadIdx.x;
    int lane = t & 63, wave = t >> 6;
    int wm = wave >> 1, wn = wave & 1;
    int lr = lane & 15, lk = lane >> 4;
    f32x4 zero = {0.f,0.f,0.f,0.f};
    f32x4 acc[2][4];
    #pragma unroll
    for (int m=0;m<2;m++)
        #pragma unroll
        for (int n=0;n<4;n++) acc[m][n] = zero;
    mm_coreT<2>(Am, MSZ, C_DIM, Bm, MSZ, C_DIM, i0, j0, 0, C_DIM,
                As, Bs, acc, wm, wn, lr, lk);
    if (EPI == 3){
        float* Cm = Cf + (size_t)mat*MSZ;
        ushort* Mh = Co + (size_t)mat*2*MSZ;
        ushort* Ml = Mh + MSZ;
        float ascale = ALPHA_C * sqrtf(tvals[8+mat]/tvals[mat]);
        #pragma unroll
        for (int m=0;m<2;m++)
            #pragma unroll
            for (int n=0;n<4;n++)
                #pragma unroll
                for (int j=0;j<4;j++){
                    int gr = i0 + wm*32 + m*16 + lk*4 + j;
                    int gc = j0 + wn*64 + n*16 + lr;
                    float v = acc[m][n][j];
                    size_t idx = (size_t)gr*C_DIM + gc;
                    Cm[idx] = v;
                    float mv = ascale*v + ((gr==gc)?(1.0f-ALPHA_C):0.0f);
                    ushort h,l; split2(mv,h,l);
                    Mh[idx] = h; Ml[idx] = l;
                }
    } else {
        float sc = (EPI == 4) ? 1.0f/tvals[mat] : 1.0f;
        ushort* Ch = Co + (size_t)mat*2*MSZ;
        ushort* Cl = Ch + MSZ;
        #pragma unroll
        for (int m=0;m<2;m++)
            #pragma unroll
            for (int n=0;n<4;n++)
                #pragma unroll
                for (int j=0;j<4;j++){
                    int gr = i0 + wm*32 + m*16 + lk*4 + j;
                    int gc = j0 + wn*64 + n*16 + lr;
                    float v = acc[m][n][j];
                    if (EPI == 1) v = ((gr==gc)?1.5f:0.0f) - 0.5f*v;
                    if (EPI == 4) v *= sc;
                    ushort h,l; split2(v,h,l);
                    size_t idx = (size_t)gr*C_DIM + gc;
                    Ch[idx] = h;
                    Cl[idx] = l;
                }
    }
}

// ---------- merged NS stage 2 (128x128 tiles, full chip): fy = Y*qP, fz = qP*Z ----------

__global__ __launch_bounds__(256,2) void k_mm_ns2(
        const ushort* __restrict__ Y, const ushort* __restrict__ P,
        const ushort* __restrict__ Z, ushort* __restrict__ fy,
        ushort* __restrict__ fz){
    __shared__ ushort As[2][8192];
    __shared__ ushort Bs[2][8192];
    int wg = xcd_swz(blockIdx.x, NMAT*32);
    int mat = wg >> 5;
    int r = wg & 31;
    int op = r >> 4, tile = r & 15;
    int i0 = (tile>>2)*128, j0 = (tile&3)*128;
    const ushort* Am = (op ? P : Y) + (size_t)mat*2*MSZ;
    const ushort* Bm = (op ? Z : P) + (size_t)mat*2*MSZ;
    ushort* Ch = (op ? fz : fy) + (size_t)mat*2*MSZ;
    ushort* Cl = Ch + MSZ;
    int t = threadIdx.x;
    int lane = t & 63, wave = t >> 6;
    int wm = wave >> 1, wn = wave & 1;
    int lr = lane & 15, lk = lane >> 4;
    f32x4 zero = {0.f,0.f,0.f,0.f};
    f32x4 acc[4][4];
    #pragma unroll
    for (int m=0;m<4;m++)
        #pragma unroll
        for (int n=0;n<4;n++) acc[m][n] = zero;
    mm_coreT<4>(Am, MSZ, C_DIM, Bm, MSZ, C_DIM, i0, j0, 0, C_DIM,
                As, Bs, acc, wm, wn, lr, lk);
    #pragma unroll
    for (int m=0;m<4;m++)
        #pragma unroll
        for (int n=0;n<4;n++)
            #pragma unroll
            for (int j=0;j<4;j++){
                int gr = i0 + wm*64 + m*16 + lk*4 + j;
                int gc = j0 + wn*64 + n*16 + lr;
                ushort h,l; split2(acc[m][n][j],h,l);
                size_t idx = (size_t)gr*C_DIM + gc;
                Ch[idx] = h;
                Cl[idx] = l;
            }
}

// ---------- last NS stage 2 (64x128 tiles): only consumed halves ----------

__global__ __launch_bounds__(256) void k_mm_ns2_last(
        const ushort* __restrict__ Y, const ushort* __restrict__ P,
        const ushort* __restrict__ Z, ushort* __restrict__ fy,
        ushort* __restrict__ fz){
    __shared__ ushort As[2][4096];
    __shared__ ushort Bs[2][8192];
    int wg = xcd_swz(blockIdx.x, NMAT*32);
    int mat = wg >> 5, tile = wg & 31;
    int op = (mat < 8) ? 1 : 0;         // content: fz = P*Z ; style: fy = Y*P
    int i0 = (tile>>2)*64, j0 = (tile&3)*128;
    const ushort* Am = (op ? P : Y) + (size_t)mat*2*MSZ;
    const ushort* Bm = (op ? Z : P) + (size_t)mat*2*MSZ;
    ushort* Ch = (op ? fz : fy) + (size_t)mat*2*MSZ;
    ushort* Cl = Ch + MSZ;
    int t = threadIdx.x;
    int lane = t & 63, wave = t >> 6;
    int wm = wave >> 1, wn = wave & 1;
    int lr = lane & 15, lk = lane >> 4;
    f32x4 zero = {0.f,0.f,0.f,0.f};
    f32x4 acc[2][4];
    #pragma unroll
    for (int m=0;m<2;m++)
        #pragma unroll
        for (int n=0;n<4;n++) acc[m][n] = zero;
    mm_coreT<2>(Am, MSZ, C_DIM, Bm, MSZ, C_DIM, i0, j0, 0, C_DIM,
                As, Bs, acc, wm, wn, lr, lk);
    #pragma unroll
    for (int m=0;m<2;m++)
        #pragma unroll
        for (int n=0;n<4;n++)
            #pragma unroll
            for (int j=0;j<4;j++){
                int gr = i0 + wm*32 + m*16 + lk*4 + j;
                int gc = j0 + wn*64 + n*16 + lr;
                ushort h,l; split2(acc[m][n][j],h,l);
                size_t idx = (size_t)gr*C_DIM + gc;
                Ch[idx] = h;
                Cl[idx] = l;
            }
}

// ---------- bias vector: vvec = alpha*smean - ascale*(T cmean) ----------

__global__ __launch_bounds__(256) void k_buildV(const float* __restrict__ T,
        const float* __restrict__ tvals, const float* __restrict__ cmean,
        const float* __restrict__ smean, float* __restrict__ vvec){
    __shared__ float cm[512];
    int k = blockIdx.x, t = threadIdx.x;
    cm[t] = cmean[k*C_DIM + t];
    cm[t+256] = cmean[k*C_DIM + t + 256];
    __syncthreads();
    float scale = ALPHA_C * sqrtf(tvals[8+k]/tvals[k]);
    int c = blockIdx.y*256 + t;
    const float* row = T + (size_t)k*MSZ + (size_t)c*C_DIM;
    float s = 0.0f;
    for (int d=0; d<C_DIM; d++) s = fmaf(row[d], cm[d], s);
    vvec[k*C_DIM + c] = ALPHA_C*smean[k*C_DIM + c] - scale*s;
}

// ---------- MFMA apply: Sg = M*Xc + v in gathered order (coalesced) ----------

__global__ __launch_bounds__(256,2) void k_apply_mfma(
        const ushort* __restrict__ Msp, const ushort* __restrict__ XT,
        const float* __restrict__ vvec, const int* __restrict__ offPad,
        float* __restrict__ Sg){
    __shared__ ushort As[2][8192];
    __shared__ ushort Bs[2][8192];
    __shared__ int so[9];
    int t = threadIdx.x;
    if (t < 9) so[t] = offPad[t];
    __syncthreads();
    int wg = xcd_swz(blockIdx.x, (CAP/128)*4);
    int j0 = (wg>>2)*128;
    int i0 = (wg&3)*128;
    if (j0 >= so[8]) return;
    int cl = 0;
    while (cl < 7 && j0 >= so[cl+1]) cl++;
    const ushort* Am = Msp + (size_t)cl*2*MSZ;
    int lane = t & 63, wave = t >> 6;
    int wm = wave >> 1, wn = wave & 1;
    int lr = lane & 15, lk = lane >> 4;
    f32x4 zero = {0.f,0.f,0.f,0.f};
    f32x4 acc[4][4];
    #pragma unroll
    for (int m=0;m<4;m++)
        #pragma unroll
        for (int n=0;n<4;n++) acc[m][n] = zero;
    mm_coreT<4>(Am, MSZ, C_DIM, XT, (size_t)CAP*C_DIM, C_DIM, i0, j0, 0, C_DIM,
                As, Bs, acc, wm, wn, lr, lk);
    #pragma unroll
    for (int m=0;m<4;m++)
        #pragma unroll
        for (int nn=0;nn<4;nn++)
            #pragma unroll
            for (int j=0;j<4;j++){
                int gr = i0 + wm*64 + m*16 + lk*4 + j;
                int gc = j0 + wn*64 + nn*16 + lr;
                Sg[(size_t)gr*CAP + gc] = acc[m][nn][j] + vvec[cl*C_DIM + gr];
            }
}

// ---------- scatter: out[c][p] = Sg[c][ginv[p]] (coalesced writes) ----------

__global__ __launch_bounds__(256) void k_scatter(const float* __restrict__ Sg,
        const int* __restrict__ ginv, float* __restrict__ out){
    size_t idx = (size_t)blockIdx.x*256 + threadIdx.x;
    int p = (int)(idx & (WH-1));
    int c = (int)(idx >> 14);
    out[idx] = Sg[(size_t)c*CAP + ginv[p]];
}

// ---------- host ----------

extern "C" void kernel_launch(void* const* d_in, const int* in_sizes, int n_in,
                              void* d_out, int out_size, void* d_ws, size_t ws_size,
                              hipStream_t stream) {
    (void)in_sizes; (void)n_in;
    const float* cf     = (const float*)d_in[0];
    const float* sf     = (const float*)d_in[1];
    const float* scores = (const float*)d_in[2];
    const int*   cl     = (const int*)d_in[3];
    const int*   sl     = (const int*)d_in[4];
    float* out = (float*)d_out;
    float* ws  = (float*)d_ws;

    size_t o = 0;
    ushort* XcH = (ushort*)(ws + o);
    float*  Sg  = ws + o;       o += (size_t)C_DIM*CAP;
    ushort* XcL = XcH + (size_t)C_DIM*CAP;
    ushort* XsH = (ushort*)(ws + o); o += (size_t)C_DIM*CAP;
    float* S4  = ws + o; o += (size_t)NMAT*MSZ;
    float* NS0 = ws + o; o += (size_t)4*NMAT*MSZ;
    float* cmean = ws + o; o += 8*C_DIM;
    float* ssum  = ws + o; o += 8*C_DIM;
    float* smean = ws + o; o += 8*C_DIM;
    float* vvec  = ws + o; o += 8*C_DIM;
    float* tvals = ws + o; o += 16;
    float* rowpart = ws + o; o += (size_t)NMAT*4*512;
    float* total = ws + o; o += 8;
    float* psumC = ws + o; o += (size_t)C_DIM*NBX;
    float* psumS = ws + o; o += (size_t)C_DIM*NBX;
    int* ip = (int*)(ws + o);
    int* permC    = ip; ip += CAP;
    int* permCinv = ip; ip += CAP;
    int* permS    = ip; ip += CAP;
    int* segOfC = ip; ip += NBX;
    int* segOfS = ip; ip += NBX;
    int* cntC  = ip; ip += 8;
    int* cntS  = ip; ip += 8;
    int* offC  = ip; ip += 9;
    int* offS  = ip; ip += 9;
    int* chC   = ip; ip += NCHUNK*8;
    int* chS   = ip; ip += NCHUNK*8;
    int* baseC = ip; ip += NCHUNK*8;
    int* baseS = ip; ip += NCHUNK*8;
    size_t need_bytes = (size_t)((char*)ip - (char*)d_ws);
    if (ws_size < need_bytes){
        hipMemcpyAsync(d_out, (const void*)cf, (size_t)out_size*sizeof(float),
                       hipMemcpyDeviceToDevice, stream);
        return;
    }
    float* Pf = NS0;
    ushort* s0 = (ushort*)(NS0 + 0*(size_t)NMAT*MSZ);
    ushort* s1 = (ushort*)(NS0 + 1*(size_t)NMAT*MSZ);
    ushort* s2 = (ushort*)(NS0 + 2*(size_t)NMAT*MSZ);
    ushort* s3 = (ushort*)(NS0 + 3*(size_t)NMAT*MSZ);
    ushort* s4 = (ushort*)S4;

    k_chunk_hist<<<dim3(NCHUNK,2),256,0,stream>>>(cl, sl, chC, chS);
    k_scan<<<1,64,0,stream>>>(chC, chS, cntC, cntS, offC, offS, baseC, baseS);
    k_place<<<dim3(NCHUNK,2),64,0,stream>>>(cl, sl, baseC, baseS, permC, permS, permCinv);

    // gather + split + fused cluster partial sums (content z=0, style z=1)
    dim3 gg(NBX, C_DIM/16, 2);
    k_gather2<<<gg,256,0,stream>>>(cf, sf, permC, permS, offC, offS, cntC, cntS,
                                   XcH, XcL, XsH, XsH + (size_t)C_DIM*CAP,
                                   psumC, psumS, segOfC, segOfS);

    k_meanred<<<dim3(8,2,2),256,0,stream>>>(psumC, psumS, segOfC, segOfS, cntC,
                                            cmean, ssum);
    k_style_mean<<<1,256,0,stream>>>(scores, cntS, ssum, total, smean);

    k_syrk_mfma<<<NMAT*NSLICE*10,256,0,stream>>>(XcH, XsH, offC, offS, Pf);

    k_transpose<<<dim3(CAP/64, C_DIM/64, 2),256,0,stream>>>(XcH, XsH);
    ushort* XT = XsH;

    ushort* bA = s4;
    k_assemble<<<dim3(10,16),256,0,stream>>>(Pf, scores, total, cmean, smean, cntC, bA);

    k_mm_rowsum<<<NMAT*32,256,0,stream>>>(bA, rowpart);
    k_tmax<<<NMAT,256,0,stream>>>(rowpart, tvals);

    // iteration 0 (collapsed): P0 = q(A/t) elementwise; Y1 = (A*P0)/t (scale in
    // epilogue, A read directly from bA planes); Z1 = P0 (alias)
    k_initP0<<<dim3(MSZ/256,NMAT),256,0,stream>>>(bA, tvals, s1);
    k_mm_ns64<4><<<NMAT*32,256,0,stream>>>(bA, s1, s2, nullptr, tvals, NMAT);

    ushort* bY = s2;  ushort* bZ = s1;  ushort* bP = s3;
    ushort* fy = s4;  ushort* fz = s0;   // s4 = bA slot (dead after ns64<4>), s0 unused
    for (int it=0; it<NIT-1; ++it){
        k_mm_ns64<1><<<NMAT*32,256,0,stream>>>(bZ, bY, bP, nullptr, nullptr, NMAT); // P=q(Z*Y)
        if (it < NIT-2)
            k_mm_ns2<<<NMAT*32,256,0,stream>>>(bY, bP, bZ, fy, fz);
        else
            k_mm_ns2_last<<<NMAT*32,256,0,stream>>>(bY, bP, bZ, fy, fz);
        ushort* t1;
        t1 = bY; bY = fy; fy = t1;
        t1 = bZ; bZ = fz; fz = t1;
    }
    // T[k] = Y_style[8+k] * Z_content[k]: fp32 T + split M in one pass
    float* Tf = (float*)fy;
    ushort* Msp = fz;
    k_mm_ns64<3><<<8*32,256,0,stream>>>(bY + (size_t)8*2*MSZ, bZ, Msp, Tf, tvals, 8);

    k_buildV<<<dim3(8,2),256,0,stream>>>(Tf, tvals, cmean, smean, vvec);

    k_apply_mfma<<<(CAP/128)*4,256,0,stream>>>(Msp, XT, vvec, offC, Sg);
    k_scatter<<<(C_DIM*WH)/256,256,0,stream>>>(Sg, permCinv, out);
}

// Round 13
// 520.219 us; speedup vs baseline: 2.3510x; 1.0002x over previous
//
#include <hip/hip_runtime.h>
#include <math.h>

#define C_DIM 512
#define WH    16384
#define CAP   17408      // 16384 + 8*128 worst-case padding
#define NBX   136        // CAP/128
#define SEG_ALIGN 128
#define NCHUNK 64
#define CHUNK  256
#define NMAT 16
#define NSLICE 4
#define MSZ  (C_DIM*C_DIM)
#define ALPHA_C 0.8f
#define EPS_C   1e-6f
#define NIT 5            // total q-applications: 1 collapsed + 4 full (halved-t start)

typedef __attribute__((ext_vector_type(8))) __bf16 bfrag;
typedef __attribute__((ext_vector_type(4))) float f32x4;

__device__ inline float bf2f(ushort h){ return __uint_as_float(((unsigned)h)<<16); }
__device__ inline void split2(float v, ushort& h, ushort& l){
    unsigned u = __float_as_uint(v);
    h = (ushort)(u >> 16);
    float r = v - __uint_as_float(u & 0xffff0000u);
    l = (ushort)(__float_as_uint(r) >> 16);
}

__device__ __forceinline__ int xcd_swz(int bid, int nwg){
    int c = nwg >> 3;
    return (bid & 7)*c + (bid >> 3);
}

__device__ __forceinline__ void gload16(const void* g, void* l){
    __builtin_amdgcn_global_load_lds(
        (const __attribute__((address_space(1))) unsigned int*)g,
        (__attribute__((address_space(3))) unsigned int*)l, 16, 0, 0);
}

// stage one R x 64 bf16 panel (R = 64 or 128): LDS linear, source pre-swizzled
template<int R>
__device__ __forceinline__ void stage_panelR(const ushort* __restrict__ src,
        int stride, int i0, int k0, ushort* lds){
    int t = threadIdx.x;
    #pragma unroll
    for (int i = 0; i < R/32; ++i){
        int slot = t + i*256;
        int row = slot >> 3, c8 = slot & 7;
        const ushort* g = src + (size_t)(i0+row)*stride + k0 + ((c8 ^ (row&7))<<3);
        gload16((const void*)g, (void*)&lds[(size_t)(i*256 + (t & 192))*8]);
    }
}

// MFMA inner block: (2*MFR*16) x 128 tile, K=64 step, split-3 products
template<int MFR>
__device__ __forceinline__ void mfma_block(const ushort* As0, const ushort* As1,
        const ushort* Bs0, const ushort* Bs1, f32x4 (&acc)[MFR][4],
        int wm, int wn, int lr, int lk){
    #pragma unroll
    for (int kk = 0; kk < 64; kk += 32){
        bfrag ah[MFR], al[MFR], bh[4], bl[4];
        #pragma unroll
        for (int m = 0; m < MFR; ++m){
            int row = wm*(MFR*16) + m*16 + lr;
            int off = (row*64 + kk + lk*8) ^ ((row&7)<<3);
            ah[m] = *(const bfrag*)&As0[off];
            al[m] = *(const bfrag*)&As1[off];
        }
        #pragma unroll
        for (int n = 0; n < 4; ++n){
            int row = wn*64 + n*16 + lr;
            int off = (row*64 + kk + lk*8) ^ ((row&7)<<3);
            bh[n] = *(const bfrag*)&Bs0[off];
            bl[n] = *(const bfrag*)&Bs1[off];
        }
        #pragma unroll
        for (int m = 0; m < MFR; ++m)
            #pragma unroll
            for (int n = 0; n < 4; ++n){
                acc[m][n] = __builtin_amdgcn_mfma_f32_16x16x32_bf16(ah[m], bh[n], acc[m][n], 0,0,0);
                acc[m][n] = __builtin_amdgcn_mfma_f32_16x16x32_bf16(ah[m], bl[n], acc[m][n], 0,0,0);
                acc[m][n] = __builtin_amdgcn_mfma_f32_16x16x32_bf16(al[m], bh[n], acc[m][n], 0,0,0);
            }
    }
}

// unified K-loop: C((2*MFR*16)x128) += A * B^T on split planes
template<int MFR>
__device__ __forceinline__ void mm_coreT(const ushort* __restrict__ Am, size_t aPl, int aStr,
        const ushort* __restrict__ Bm, size_t bPl, int bStr,
        int i0, int j0, int kLo, int kHi,
        ushort (&As)[2][MFR*2048], ushort (&Bs)[2][8192], f32x4 (&acc)[MFR][4],
        int wm, int wn, int lr, int lk){
    for (int k0 = kLo; k0 < kHi; k0 += 64){
        stage_panelR<MFR*32>(Am,       aStr, i0, k0, As[0]);
        stage_panelR<MFR*32>(Am + aPl, aStr, i0, k0, As[1]);
        stage_panelR<128>(Bm,       bStr, j0, k0, Bs[0]);
        stage_panelR<128>(Bm + bPl, bStr, j0, k0, Bs[1]);
        __syncthreads();
        mfma_block<MFR>(As[0], As[1], Bs[0], Bs[1], acc, wm, wn, lr, lk);
        __syncthreads();
    }
}

// ---------- label bookkeeping (deterministic counting sort), content+style merged ----------

__global__ __launch_bounds__(256) void k_chunk_hist(const int* __restrict__ lab0,
        const int* __restrict__ lab1, int* __restrict__ ch0, int* __restrict__ ch1){
    __shared__ int h[8];
    int t = threadIdx.x;
    const int* labels = blockIdx.y ? lab1 : lab0;
    int* chunkCnt = blockIdx.y ? ch1 : ch0;
    if (t < 8) h[t] = 0;
    __syncthreads();
    int l = labels[blockIdx.x*CHUNK + t];
    atomicAdd(&h[l], 1);
    __syncthreads();
    if (t < 8) chunkCnt[blockIdx.x*8 + t] = h[t];
}

__global__ void k_scan(const int* __restrict__ ch0, const int* __restrict__ ch1,
                       int* __restrict__ cnt0, int* __restrict__ cnt1,
                       int* __restrict__ off0, int* __restrict__ off1,
                       int* __restrict__ base0, int* __restrict__ base1){
    int which = threadIdx.x;
    if (which >= 2) return;
    const int* chunkCnt = which ? ch1 : ch0;
    int* cnt = which ? cnt1 : cnt0;
    int* offPad = which ? off1 : off0;
    int* base = which ? base1 : base0;
    int c[8];
    for (int k=0;k<8;k++) c[k]=0;
    for (int ch=0; ch<NCHUNK; ch++)
        for (int k=0;k<8;k++) c[k] += chunkCnt[ch*8+k];
    int off = 0;
    for (int k=0;k<8;k++){
        cnt[k] = c[k];
        offPad[k] = off;
        off += ((c[k] + SEG_ALIGN - 1)/SEG_ALIGN)*SEG_ALIGN;
    }
    offPad[8] = off;
    for (int k=0;k<8;k++){
        int run = offPad[k];
        for (int ch=0; ch<NCHUNK; ch++){
            base[ch*8+k] = run;
            run += chunkCnt[ch*8+k];
        }
    }
}

__global__ void k_place(const int* __restrict__ lab0, const int* __restrict__ lab1,
        const int* __restrict__ base0, const int* __restrict__ base1,
        int* __restrict__ perm0, int* __restrict__ perm1, int* __restrict__ inv0){
    int t = threadIdx.x;
    if (t >= 8) return;
    const int* labels = blockIdx.y ? lab1 : lab0;
    const int* base = blockIdx.y ? base1 : base0;
    int* perm = blockIdx.y ? perm1 : perm0;
    int* inv = blockIdx.y ? nullptr : inv0;
    int ch = blockIdx.x;
    int pos = base[ch*8+t];
    int s = ch*CHUNK;
    for (int i=0;i<CHUNK;i++){
        if (labels[s+i] == t){
            perm[pos] = s+i;
            if (inv) inv[s+i] = pos;
            pos++;
        }
    }
}

// ---------- gather + split + fused per-cluster partial sums (content & style via z) ----------

__global__ __launch_bounds__(256) void k_gather2(const float* __restrict__ src0,
        const float* __restrict__ src1,
        const int* __restrict__ perm0, const int* __restrict__ perm1,
        const int* __restrict__ off0, const int* __restrict__ off1,
        const int* __restrict__ cnt0, const int* __restrict__ cnt1,
        ushort* __restrict__ dH0, ushort* __restrict__ dL0,
        ushort* __restrict__ dH1, ushort* __restrict__ dL1,
        float* __restrict__ ps0, float* __restrict__ ps1,
        int* __restrict__ sg0, int* __restrict__ sg1){
    int z = blockIdx.z;
    const float* src = z ? src1 : src0;
    const int* perm = z ? perm1 : perm0;
    const int* offPad = z ? off1 : off0;
    const int* cnt = z ? cnt1 : cnt0;
    ushort* dstH = z ? dH1 : dH0;
    ushort* dstL = z ? dL1 : dL0;
    float* psum = z ? ps1 : ps0;
    int* segOf = z ? sg1 : sg0;
    __shared__ int so[9], sc[8];
    __shared__ int pcache[128];
    int t = threadIdx.x;
    if (t < 9) so[t] = offPad[t];
    if (t < 8) sc[t] = cnt[t];
    __syncthreads();
    int bx = blockIdx.x;
    int i0 = bx*128;
    if (t < 128) pcache[t] = (i0 + t < so[8]) ? perm[i0 + t] : 0;
    __syncthreads();
    int k = 0;
    while (k < 7 && i0 >= so[k+1]) k++;
    int n = sc[k], s0 = so[k];
    int ch = t >> 4, px0 = (t & 15)*8;
    int c  = blockIdx.y*16 + ch;
    const float* row = src + (size_t)c*WH;
    float v[8];
    #pragma unroll
    for (int x=0;x<8;x++){
        int i = i0 + px0 + x;
        v[x] = (i - s0 < n) ? row[pcache[px0+x]] : 0.0f;
    }
    float s = 0.0f;
    ushort hv[8], lv[8];
    #pragma unroll
    for (int x=0;x<8;x++){
        s += v[x];
        split2(v[x], hv[x], lv[x]);
    }
    *(uint4*)&dstH[(size_t)c*CAP + i0 + px0] = *(uint4*)hv;
    *(uint4*)&dstL[(size_t)c*CAP + i0 + px0] = *(uint4*)lv;
    #pragma unroll
    for (int d=1; d<16; d<<=1) s += __shfl_xor(s, d, 16);
    if ((t & 15) == 0) psum[(size_t)c*NBX + bx] = s;
    if (t == 0) segOf[bx] = k;
}

// ---------- reduce partials -> per-cluster sums/means (z: 0=content mean, 1=style sum) ----------

__global__ __launch_bounds__(256) void k_meanred(const float* __restrict__ ps0,
        const float* __restrict__ ps1, const int* __restrict__ sg0,
        const int* __restrict__ sg1, const int* __restrict__ cnt0,
        float* __restrict__ out0, float* __restrict__ out1){
    int z = blockIdx.z;
    const float* psum = z ? ps1 : ps0;
    const int* segOf = z ? sg1 : sg0;
    float* out = z ? out1 : out0;
    int k = blockIdx.x;
    int c = blockIdx.y*256 + threadIdx.x;
    float s = 0.0f;
    for (int bx=0; bx<NBX; bx++)
        if (segOf[bx] == k) s += psum[(size_t)c*NBX + bx];
    out[k*C_DIM + c] = z ? s : s/(float)cnt0[k];
}

// ---------- transpose plane: [512][CAP] -> [CAP][512] ----------

__global__ __launch_bounds__(256) void k_transpose(const ushort* __restrict__ S,
                                                   ushort* __restrict__ D){
    __shared__ ushort tile[64][72];
    int p = blockIdx.z;
    const ushort* Sp = S + (size_t)p*C_DIM*CAP;
    ushort* Dp = D + (size_t)p*CAP*C_DIM;
    int cb = blockIdx.x*64;
    int rb = blockIdx.y*64;
    int t = threadIdx.x;
    int tr = t >> 3, tc = t & 7;
    #pragma unroll
    for (int i=0;i<2;i++){
        int r = tr + i*32;
        uint4 v = *(const uint4*)&Sp[(size_t)(rb+r)*CAP + cb + tc*8];
        ushort* u = (ushort*)&v;
        #pragma unroll
        for (int j=0;j<8;j++) tile[tc*8+j][r] = u[j];
    }
    __syncthreads();
    #pragma unroll
    for (int i=0;i<2;i++){
        int r = tr + i*32;
        uint4 v;
        ushort* u = (ushort*)&v;
        #pragma unroll
        for (int j=0;j<8;j++) u[j] = tile[r][tc*8+j];
        *(uint4*)&Dp[(size_t)(cb+r)*C_DIM + rb + tc*8] = v;
    }
}

__global__ __launch_bounds__(256) void k_style_mean(const float* __restrict__ scores,
        const int* __restrict__ cntS, const float* __restrict__ ssum,
        float* __restrict__ total, float* __restrict__ smean){
    int t = threadIdx.x;
    __shared__ float tot[8];
    if (t < 8){
        float s = 0.0f;
        for (int j=0;j<8;j++) s += scores[t*8+j]*(float)cntS[j];
        tot[t] = s; total[t] = s;
    }
    __syncthreads();
    for (int idx=t; idx<8*C_DIM; idx+=256){
        int k = idx / C_DIM, c = idx % C_DIM;
        float s = 0.0f;
        for (int j=0;j<8;j++) s += scores[k*8+j]*ssum[j*C_DIM+c];
        smean[idx] = s / tot[k];
    }
}

// ---------- MFMA SYRK: partial S2 = X X^T, triangular tiles, split-K ----------

__global__ __launch_bounds__(256,2) void k_syrk_mfma(
        const ushort* __restrict__ Xc, const ushort* __restrict__ Xs,
        const int* __restrict__ offC, const int* __restrict__ offS,
        float* __restrict__ Pf){
    __shared__ ushort As[2][8192];
    __shared__ ushort Bs[2][8192];
    int wg = xcd_swz(blockIdx.x, NMAT*NSLICE*10);
    int mat = wg / (NSLICE*10);
    int rem = wg % (NSLICE*10);
    int slice = rem / 10, tt = rem % 10;
    int ti, tj;
    if (tt < 4){ ti=0; tj=tt; }
    else if (tt < 7){ ti=1; tj=tt-3; }
    else if (tt < 9){ ti=2; tj=tt-5; }
    else { ti=3; tj=3; }
    const ushort* X = (mat < 8) ? Xc : Xs;
    const int* offP = (mat < 8) ? offC : offS;
    int cl = mat & 7;
    int off = offP[cl], npad = offP[cl+1] - off;
    int i0 = ti*128, j0 = tj*128;
    int L = ((npad + NSLICE*64 - 1)/(NSLICE*64))*64;
    int k_lo = slice*L;
    int k_hi = min(k_lo + L, npad);
    int t = threadIdx.x;
    int lane = t & 63, wave = t >> 6;
    int wm = wave >> 1, wn = wave & 1;
    int lr = lane & 15, lk = lane >> 4;
    f32x4 zero = {0.f,0.f,0.f,0.f};
    f32x4 acc[4][4];
    #pragma unroll
    for (int m=0;m<4;m++)
        #pragma unroll
        for (int n=0;n<4;n++) acc[m][n] = zero;
    mm_coreT<4>(X + off, (size_t)C_DIM*CAP, CAP,
                X + off, (size_t)C_DIM*CAP, CAP,
                i0, j0, k_lo, k_hi, As, Bs, acc, wm, wn, lr, lk);
    float* O = Pf + ((size_t)(slice*16 + mat))*MSZ;
    #pragma unroll
    for (int m=0;m<4;m++)
        #pragma unroll
        for (int n=0;n<4;n++)
            #pragma unroll
            for (int j=0;j<4;j++){
                int gr = i0 + wm*64 + m*16 + lk*4 + j;
                int gc = j0 + wn*64 + n*16 + lr;
                O[(size_t)gr*C_DIM + gc] = acc[m][n][j];
            }
}

// ---------- assemble A (tile-based, coalesced, LDS mirror) -> split planes ----------

__global__ __launch_bounds__(256) void k_assemble(const float* __restrict__ P0,
        const float* __restrict__ scores, const float* __restrict__ total,
        const float* __restrict__ cmean, const float* __restrict__ smean,
        const int* __restrict__ cntC, ushort* __restrict__ bA){
    const size_t S = (size_t)NMAT*MSZ;
    __shared__ ushort tH[64][136];
    __shared__ ushort tL[64][136];
    int mat = blockIdx.y;
    int tt = blockIdx.x;
    int ti, tj;
    if (tt < 4){ ti=0; tj=tt; }
    else if (tt < 7){ ti=1; tj=tt-3; }
    else if (tt < 9){ ti=2; tj=tt-5; }
    else { ti=3; tj=3; }
    int i0 = ti*128, j0 = tj*128;
    int t = threadIdx.x;
    ushort* bm = bA + (size_t)mat*2*MSZ;
    int k = mat - 8;
    float nOrTot = (mat < 8) ? (float)cntC[mat] : total[k];
    float inv_nm1 = 1.0f/(nOrTot - 1.0f);
    const float* mrow = (mat < 8) ? (cmean + mat*C_DIM) : (smean + k*C_DIM);
    for (int h = 0; h < 2; ++h){
        #pragma unroll
        for (int rep = 0; rep < 4; ++rep){
            int lin = rep*2048 + t*8;
            int r = lin >> 7;
            int c = lin & 127;
            int gr = i0 + h*64 + r;
            int gc = j0 + c;
            size_t e = (size_t)gr*C_DIM + gc;
            float s2[8];
            if (mat < 8){
                size_t b = (size_t)mat*MSZ + e;
                #pragma unroll
                for (int x=0;x<8;x++)
                    s2[x] = P0[b+x] + P0[b+S+x] + P0[b+2*S+x] + P0[b+3*S+x];
            } else {
                #pragma unroll
                for (int x=0;x<8;x++) s2[x] = 0.0f;
                #pragma unroll
                for (int jj=0;jj<8;jj++){
                    float sc = scores[k*8+jj];
                    size_t b = (size_t)(8+jj)*MSZ + e;
                    #pragma unroll
                    for (int x=0;x<8;x++)
                        s2[x] += sc*(P0[b+x] + P0[b+S+x] + P0[b+2*S+x] + P0[b+3*S+x]);
                }
            }
            float mi = mrow[gr];
            #pragma unroll
            for (int x=0;x<8;x++){
                float v = (s2[x] - nOrTot*mi*mrow[gc+x])*inv_nm1;
                if (mat < 8 && gr == gc+x) v += EPS_C;
                ushort hh,ll; split2(v,hh,ll);
                bm[e+x] = hh; bm[MSZ+e+x] = ll;
                tH[r][c+x] = hh; tL[r][c+x] = ll;
            }
        }
        if (ti != tj){
            __syncthreads();
            #pragma unroll
            for (int rep = 0; rep < 4; ++rep){
                int lin = rep*2048 + t*8;
                int rr = lin >> 6;
                int cc0 = lin & 63;
                size_t eo = (size_t)(j0+rr)*C_DIM + i0 + h*64 + cc0;
                #pragma unroll
                for (int x=0;x<8;x++){
                    bm[eo+x]     = tH[cc0+x][rr];
                    bm[MSZ+eo+x] = tL[cc0+x][rr];
                }
            }
            __syncthreads();
        }
    }
}

// ---------- A^2 row abs-sums via MFMA (no C write), 64x128 tiles ----------

__global__ __launch_bounds__(256) void k_mm_rowsum(
        const ushort* __restrict__ A, float* __restrict__ rowpart){
    __shared__ ushort As[2][4096];
    __shared__ ushort Bs[2][8192];
    __shared__ float rs[64][2];
    int wg = xcd_swz(blockIdx.x, NMAT*32);
    int mat = wg >> 5, tile = wg & 31;
    int ti = tile >> 2, tj = tile & 3;
    int i0 = ti*64, j0 = tj*128;
    const ushort* Am = A + (size_t)mat*2*MSZ;
    int t = threadIdx.x;
    int lane = t & 63, wave = t >> 6;
    int wm = wave >> 1, wn = wave & 1;
    int lr = lane & 15, lk = lane >> 4;
    f32x4 zero = {0.f,0.f,0.f,0.f};
    f32x4 acc[2][4];
    #pragma unroll
    for (int m=0;m<2;m++)
        #pragma unroll
        for (int n=0;n<4;n++) acc[m][n] = zero;
    mm_coreT<2>(Am, MSZ, C_DIM, Am, MSZ, C_DIM, i0, j0, 0, C_DIM,
                As, Bs, acc, wm, wn, lr, lk);
    #pragma unroll
    for (int m=0;m<2;m++)
        #pragma unroll
        for (int j=0;j<4;j++){
            float s = 0.0f;
            #pragma unroll
            for (int n=0;n<4;n++) s += fabsf(acc[m][n][j]);
            #pragma unroll
            for (int d=1; d<16; d<<=1) s += __shfl_xor(s, d);
            if (lr == 0) rs[wm*32 + m*16 + lk*4 + j][wn] = s;
        }
    __syncthreads();
    if (t < 64)
        rowpart[((size_t)mat*4 + tj)*512 + i0 + t] = rs[t][0] + rs[t][1];
}

// ---------- t = 0.5*sqrt(max row sum of |A^2|); NS converges for p in (0,3) ----------

__global__ __launch_bounds__(256) void k_tmax(const float* __restrict__ rowpart,
                                              float* __restrict__ tvals){
    int mat = blockIdx.x, t = threadIdx.x;
    const float* rp = rowpart + (size_t)mat*4*512;
    float mx = 0.0f;
    for (int r = t; r < 512; r += 256){
        float s = rp[r] + rp[512+r] + rp[1024+r] + rp[1536+r];
        mx = fmaxf(mx, s);
    }
    __shared__ float red[256];
    red[t] = mx; __syncthreads();
    for (int s=128; s>0; s>>=1){ if (t<s) red[t]=fmaxf(red[t],red[t+s]); __syncthreads(); }
    if (t == 0) tvals[mat] = 0.5f*sqrtf(red[0]);
}

// ---------- P0 = q(A/t) = 1.5I - 0.5*A/t (Y0 never materialized) ----------

__global__ __launch_bounds__(256) void k_initP0(const ushort* __restrict__ bA,
        const float* __restrict__ tvals, ushort* __restrict__ P){
    int mat = blockIdx.y;
    int e = blockIdx.x*256 + threadIdx.x;
    size_t base = (size_t)mat*2*MSZ;
    float inv = 1.0f / tvals[mat];
    float a = (bf2f(bA[base+e]) + bf2f(bA[base+MSZ+e])) * inv;
    int i = e >> 9, j = e & 511;
    float p = ((i==j)?1.5f:0.0f) - 0.5f*a;
    ushort h,l; split2(p,h,l);
    P[base + e] = h;
    P[base + MSZ + e] = l;
}

// ---------- generic 64x128-tile batched mm on split planes ----------
// EPI 0: split write; EPI 1: q(X) then split write; EPI 3: fp32 T + split M(ascale,diag);
// EPI 4: split write of acc/tvals[mat]  (Y1 = (A*P0)/t)

template<int EPI>
__global__ __launch_bounds__(256) void k_mm_ns64(
        const ushort* __restrict__ A, const ushort* __restrict__ B,
        ushort* __restrict__ Co, float* __restrict__ Cf,
        const float* __restrict__ tvals, int nmat){
    __shared__ ushort As[2][4096];
    __shared__ ushort Bs[2][8192];
    int wg = xcd_swz(blockIdx.x, nmat*32);
    int mat = wg >> 5, tile = wg & 31;
    int i0 = (tile>>2)*64, j0 = (tile&3)*128;
    const ushort* Am = A + (size_t)mat*2*MSZ;
    const ushort* Bm = B + (size_t)mat*2*MSZ;
    int t = threadIdx.x;
    int lane = t & 63, wave = t >> 6;
    int wm = wave >> 1, wn = wave & 1;
    int lr = lane & 15, lk = lane >> 4;
    f32x4 zero = {0.f,0.f,0.f,0.f};
    f32x4 acc[2][4];
    #pragma unroll
    for (int m=0;m<2;m++)
        #pragma unroll
        for (int n=0;n<4;n++) acc[m][n] = zero;
    mm_coreT<2>(Am, MSZ, C_DIM, Bm, MSZ, C_DIM, i0, j0, 0, C_DIM,
                As, Bs, acc, wm, wn, lr, lk);
    if (EPI == 3){
        float* Cm = Cf + (size_t)mat*MSZ;
        ushort* Mh = Co + (size_t)mat*2*MSZ;
        ushort* Ml = Mh + MSZ;
        float ascale = ALPHA_C * sqrtf(tvals[8+mat]/tvals[mat]);
        #pragma unroll
        for (int m=0;m<2;m++)
            #pragma unroll
            for (int n=0;n<4;n++)
                #pragma unroll
                for (int j=0;j<4;j++){
                    int gr = i0 + wm*32 + m*16 + lk*4 + j;
                    int gc = j0 + wn*64 + n*16 + lr;
                    float v = acc[m][n][j];
                    size_t idx = (size_t)gr*C_DIM + gc;
                    Cm[idx] = v;
                    float mv = ascale*v + ((gr==gc)?(1.0f-ALPHA_C):0.0f);
                    ushort h,l; split2(mv,h,l);
                    Mh[idx] = h; Ml[idx] = l;
                }
    } else {
        float sc = (EPI == 4) ? 1.0f/tvals[mat] : 1.0f;
        ushort* Ch = Co + (size_t)mat*2*MSZ;
        ushort* Cl = Ch + MSZ;
        #pragma unroll
        for (int m=0;m<2;m++)
            #pragma unroll
            for (int n=0;n<4;n++)
                #pragma unroll
                for (int j=0;j<4;j++){
                    int gr = i0 + wm*32 + m*16 + lk*4 + j;
                    int gc = j0 + wn*64 + n*16 + lr;
                    float v = acc[m][n][j];
                    if (EPI == 1) v = ((gr==gc)?1.5f:0.0f) - 0.5f*v;
                    if (EPI == 4) v *= sc;
                    ushort h,l; split2(v,h,l);
                    size_t idx = (size_t)gr*C_DIM + gc;
                    Ch[idx] = h;
                    Cl[idx] = l;
                }
    }
}

// ---------- merged NS stage 2, TRIANGULAR (64x128 tiles, mirror lower): fy=Y*qP, fz=qP*Z ----------
// outputs are symmetric (commuting polynomials of one symmetric matrix)

__global__ __launch_bounds__(256) void k_mm_ns2(
        const ushort* __restrict__ Y, const ushort* __restrict__ P,
        const ushort* __restrict__ Z, ushort* __restrict__ fy,
        ushort* __restrict__ fz){
    __shared__ ushort lds[24576];   // mm staging (48 KB), then transpose staging
    ushort* As0 = lds;
    ushort* As1 = lds + 4096;
    ushort* Bs0 = lds + 8192;
    ushort* Bs1 = lds + 16384;
    int wg = xcd_swz(blockIdx.x, NMAT*40);
    int mat = wg / 40;
    int rem = wg % 40;
    int op = rem / 20, tt = rem % 20;
    int ti, tj;
    if (tt < 2){ tj=0; ti=tt; }
    else if (tt < 6){ tj=1; ti=tt-2; }
    else if (tt < 12){ tj=2; ti=tt-6; }
    else { tj=3; ti=tt-12; }
    int i0 = ti*64, j0 = tj*128;
    const ushort* Am = (op ? P : Y) + (size_t)mat*2*MSZ;
    const ushort* Bm = (op ? Z : P) + (size_t)mat*2*MSZ;
    ushort* Ch = (op ? fz : fy) + (size_t)mat*2*MSZ;
    ushort* Cl = Ch + MSZ;
    int t = threadIdx.x;
    int lane = t & 63, wave = t >> 6;
    int wm = wave >> 1, wn = wave & 1;
    int lr = lane & 15, lk = lane >> 4;
    f32x4 zero = {0.f,0.f,0.f,0.f};
    f32x4 acc[2][4];
    #pragma unroll
    for (int m=0;m<2;m++)
        #pragma unroll
        for (int n=0;n<4;n++) acc[m][n] = zero;
    for (int k0 = 0; k0 < C_DIM; k0 += 64){
        stage_panelR<64>(Am,        C_DIM, i0, k0, As0);
        stage_panelR<64>(Am + MSZ,  C_DIM, i0, k0, As1);
        stage_panelR<128>(Bm,       C_DIM, j0, k0, Bs0);
        stage_panelR<128>(Bm + MSZ, C_DIM, j0, k0, Bs1);
        __syncthreads();
        mfma_block<2>(As0, As1, Bs0, Bs1, acc, wm, wn, lr, lk);
        __syncthreads();
    }
    bool strict_up = (ti < 2*tj);
    ushort* stgH = lds;             // [128][68] per plane
    ushort* stgL = lds + 8704;
    #pragma unroll
    for (int m=0;m<2;m++)
        #pragma unroll
        for (int n=0;n<4;n++)
            #pragma unroll
            for (int j=0;j<4;j++){
                int rl = wm*32 + m*16 + lk*4 + j;   // 0..63
                int cll = wn*64 + n*16 + lr;        // 0..127
                int gr = i0 + rl, gc = j0 + cll;
                ushort h,l; split2(acc[m][n][j],h,l);
                size_t idx = (size_t)gr*C_DIM + gc;
                Ch[idx] = h;
                Cl[idx] = l;
                if (strict_up){
                    stgH[cll*68 + rl] = h;
                    stgL[cll*68 + rl] = l;
                }
            }
    if (strict_up){
        __syncthreads();
        int r = t >> 1, pl = t & 1;
        const ushort* src = (pl ? stgL : stgH) + r*68;
        ushort* dst = (pl ? Cl : Ch) + (size_t)(j0 + r)*C_DIM + i0;
        #pragma unroll
        for (int x=0;x<16;x++)
            ((uint2*)dst)[x] = ((const uint2*)src)[x];
    }
}

// ---------- last NS stage 2 (64x128 tiles): only consumed halves ----------

__global__ __launch_bounds__(256) void k_mm_ns2_last(
        const ushort* __restrict__ Y, const ushort* __restrict__ P,
        const ushort* __restrict__ Z, ushort* __restrict__ fy,
        ushort* __restrict__ fz){
    __shared__ ushort As[2][4096];
    __shared__ ushort Bs[2][8192];
    int wg = xcd_swz(blockIdx.x, NMAT*32);
    int mat = wg >> 5, tile = wg & 31;
    int op = (mat < 8) ? 1 : 0;         // content: fz = P*Z ; style: fy = Y*P
    int i0 = (tile>>2)*64, j0 = (tile&3)*128;
    const ushort* Am = (op ? P : Y) + (size_t)mat*2*MSZ;
    const ushort* Bm = (op ? Z : P) + (size_t)mat*2*MSZ;
    ushort* Ch = (op ? fz : fy) + (size_t)mat*2*MSZ;
    ushort* Cl = Ch + MSZ;
    int t = threadIdx.x;
    int lane = t & 63, wave = t >> 6;
    int wm = wave >> 1, wn = wave & 1;
    int lr = lane & 15, lk = lane >> 4;
    f32x4 zero = {0.f,0.f,0.f,0.f};
    f32x4 acc[2][4];
    #pragma unroll
    for (int m=0;m<2;m++)
        #pragma unroll
        for (int n=0;n<4;n++) acc[m][n] = zero;
    mm_coreT<2>(Am, MSZ, C_DIM, Bm, MSZ, C_DIM, i0, j0, 0, C_DIM,
                As, Bs, acc, wm, wn, lr, lk);
    #pragma unroll
    for (int m=0;m<2;m++)
        #pragma unroll
        for (int n=0;n<4;n++)
            #pragma unroll
            for (int j=0;j<4;j++){
                int gr = i0 + wm*32 + m*16 + lk*4 + j;
                int gc = j0 + wn*64 + n*16 + lr;
                ushort h,l; split2(acc[m][n][j],h,l);
                size_t idx = (size_t)gr*C_DIM + gc;
                Ch[idx] = h;
                Cl[idx] = l;
            }
}

// ---------- bias vector: vvec = alpha*smean - ascale*(T cmean) ----------

__global__ __launch_bounds__(256) void k_buildV(const float* __restrict__ T,
        const float* __restrict__ tvals, const float* __restrict__ cmean,
        const float* __restrict__ smean, float* __restrict__ vvec){
    __shared__ float cm[512];
    int k = blockIdx.x, t = threadIdx.x;
    cm[t] = cmean[k*C_DIM + t];
    cm[t+256] = cmean[k*C_DIM + t + 256];
    __syncthreads();
    float scale = ALPHA_C * sqrtf(tvals[8+k]/tvals[k]);
    int c = blockIdx.y*256 + t;
    const float* row = T + (size_t)k*MSZ + (size_t)c*C_DIM;
    float s = 0.0f;
    for (int d=0; d<C_DIM; d++) s = fmaf(row[d], cm[d], s);
    vvec[k*C_DIM + c] = ALPHA_C*smean[k*C_DIM + c] - scale*s;
}

// ---------- MFMA apply: Sg = M*Xc + v in gathered order (coalesced) ----------

__global__ __launch_bounds__(256,2) void k_apply_mfma(
        const ushort* __restrict__ Msp, const ushort* __restrict__ XT,
        const float* __restrict__ vvec, const int* __restrict__ offPad,
        float* __restrict__ Sg){
    __shared__ ushort As[2][8192];
    __shared__ ushort Bs[2][8192];
    __shared__ int so[9];
    int t = threadIdx.x;
    if (t < 9) so[t] = offPad[t];
    __syncthreads();
    int wg = xcd_swz(blockIdx.x, (CAP/128)*4);
    int j0 = (wg>>2)*128;
    int i0 = (wg&3)*128;
    if (j0 >= so[8]) return;
    int cl = 0;
    while (cl < 7 && j0 >= so[cl+1]) cl++;
    const ushort* Am = Msp + (size_t)cl*2*MSZ;
    int lane = t & 63, wave = t >> 6;
    int wm = wave >> 1, wn = wave & 1;
    int lr = lane & 15, lk = lane >> 4;
    f32x4 zero = {0.f,0.f,0.f,0.f};
    f32x4 acc[4][4];
    #pragma unroll
    for (int m=0;m<4;m++)
        #pragma unroll
        for (int n=0;n<4;n++) acc[m][n] = zero;
    mm_coreT<4>(Am, MSZ, C_DIM, XT, (size_t)CAP*C_DIM, C_DIM, i0, j0, 0, C_DIM,
                As, Bs, acc, wm, wn, lr, lk);
    #pragma unroll
    for (int m=0;m<4;m++)
        #pragma unroll
        for (int nn=0;nn<4;nn++)
            #pragma unroll
            for (int j=0;j<4;j++){
                int gr = i0 + wm*64 + m*16 + lk*4 + j;
                int gc = j0 + wn*64 + nn*16 + lr;
                Sg[(size_t)gr*CAP + gc] = acc[m][nn][j] + vvec[cl*C_DIM + gr];
            }
}

// ---------- scatter: out[c][p] = Sg[c][ginv[p]] (coalesced writes) ----------

__global__ __launch_bounds__(256) void k_scatter(const float* __restrict__ Sg,
        const int* __restrict__ ginv, float* __restrict__ out){
    size_t idx = (size_t)blockIdx.x*256 + threadIdx.x;
    int p = (int)(idx & (WH-1));
    int c = (int)(idx >> 14);
    out[idx] = Sg[(size_t)c*CAP + ginv[p]];
}

// ---------- host ----------

extern "C" void kernel_launch(void* const* d_in, const int* in_sizes, int n_in,
                              void* d_out, int out_size, void* d_ws, size_t ws_size,
                              hipStream_t stream) {
    (void)in_sizes; (void)n_in;
    const float* cf     = (const float*)d_in[0];
    const float* sf     = (const float*)d_in[1];
    const float* scores = (const float*)d_in[2];
    const int*   cl     = (const int*)d_in[3];
    const int*   sl     = (const int*)d_in[4];
    float* out = (float*)d_out;
    float* ws  = (float*)d_ws;

    size_t o = 0;
    ushort* XcH = (ushort*)(ws + o);
    float*  Sg  = ws + o;       o += (size_t)C_DIM*CAP;
    ushort* XcL = XcH + (size_t)C_DIM*CAP;
    ushort* XsH = (ushort*)(ws + o); o += (size_t)C_DIM*CAP;
    float* S4  = ws + o; o += (size_t)NMAT*MSZ;
    float* NS0 = ws + o; o += (size_t)4*NMAT*MSZ;
    float* cmean = ws + o; o += 8*C_DIM;
    float* ssum  = ws + o; o += 8*C_DIM;
    float* smean = ws + o; o += 8*C_DIM;
    float* vvec  = ws + o; o += 8*C_DIM;
    float* tvals = ws + o; o += 16;
    float* rowpart = ws + o; o += (size_t)NMAT*4*512;
    float* total = ws + o; o += 8;
    float* psumC = ws + o; o += (size_t)C_DIM*NBX;
    float* psumS = ws + o; o += (size_t)C_DIM*NBX;
    int* ip = (int*)(ws + o);
    int* permC    = ip; ip += CAP;
    int* permCinv = ip; ip += CAP;
    int* permS    = ip; ip += CAP;
    int* segOfC = ip; ip += NBX;
    int* segOfS = ip; ip += NBX;
    int* cntC  = ip; ip += 8;
    int* cntS  = ip; ip += 8;
    int* offC  = ip; ip += 9;
    int* offS  = ip; ip += 9;
    int* chC   = ip; ip += NCHUNK*8;
    int* chS   = ip; ip += NCHUNK*8;
    int* baseC = ip; ip += NCHUNK*8;
    int* baseS = ip; ip += NCHUNK*8;
    size_t need_bytes = (size_t)((char*)ip - (char*)d_ws);
    if (ws_size < need_bytes){
        hipMemcpyAsync(d_out, (const void*)cf, (size_t)out_size*sizeof(float),
                       hipMemcpyDeviceToDevice, stream);
        return;
    }
    float* Pf = NS0;
    ushort* s0 = (ushort*)(NS0 + 0*(size_t)NMAT*MSZ);
    ushort* s1 = (ushort*)(NS0 + 1*(size_t)NMAT*MSZ);
    ushort* s2 = (ushort*)(NS0 + 2*(size_t)NMAT*MSZ);
    ushort* s3 = (ushort*)(NS0 + 3*(size_t)NMAT*MSZ);
    ushort* s4 = (ushort*)S4;

    k_chunk_hist<<<dim3(NCHUNK,2),256,0,stream>>>(cl, sl, chC, chS);
    k_scan<<<1,64,0,stream>>>(chC, chS, cntC, cntS, offC, offS, baseC, baseS);
    k_place<<<dim3(NCHUNK,2),64,0,stream>>>(cl, sl, baseC, baseS, permC, permS, permCinv);

    // gather + split + fused cluster partial sums (content z=0, style z=1)
    dim3 gg(NBX, C_DIM/16, 2);
    k_gather2<<<gg,256,0,stream>>>(cf, sf, permC, permS, offC, offS, cntC, cntS,
                                   XcH, XcL, XsH, XsH + (size_t)C_DIM*CAP,
                                   psumC, psumS, segOfC, segOfS);

    k_meanred<<<dim3(8,2,2),256,0,stream>>>(psumC, psumS, segOfC, segOfS, cntC,
                                            cmean, ssum);
    k_style_mean<<<1,256,0,stream>>>(scores, cntS, ssum, total, smean);

    k_syrk_mfma<<<NMAT*NSLICE*10,256,0,stream>>>(XcH, XsH, offC, offS, Pf);

    k_transpose<<<dim3(CAP/64, C_DIM/64, 2),256,0,stream>>>(XcH, XsH);
    ushort* XT = XsH;

    ushort* bA = s4;
    k_assemble<<<dim3(10,16),256,0,stream>>>(Pf, scores, total, cmean, smean, cntC, bA);

    k_mm_rowsum<<<NMAT*32,256,0,stream>>>(bA, rowpart);
    k_tmax<<<NMAT,256,0,stream>>>(rowpart, tvals);

    // iteration 0 (collapsed): P0 = q(A/t) elementwise; Y1 = (A*P0)/t; Z1 = P0 (alias)
    k_initP0<<<dim3(MSZ/256,NMAT),256,0,stream>>>(bA, tvals, s1);
    k_mm_ns64<4><<<NMAT*32,256,0,stream>>>(bA, s1, s2, nullptr, tvals, NMAT);

    ushort* bY = s2;  ushort* bZ = s1;  ushort* bP = s3;
    ushort* fy = s4;  ushort* fz = s0;   // s4 = bA slot (dead after ns64<4>), s0 unused
    for (int it=0; it<NIT-1; ++it){
        k_mm_ns64<1><<<NMAT*32,256,0,stream>>>(bZ, bY, bP, nullptr, nullptr, NMAT); // P=q(Z*Y)
        if (it < NIT-2)
            k_mm_ns2<<<NMAT*40,256,0,stream>>>(bY, bP, bZ, fy, fz);   // triangular+mirror
        else
            k_mm_ns2_last<<<NMAT*32,256,0,stream>>>(bY, bP, bZ, fy, fz);
        ushort* t1;
        t1 = bY; bY = fy; fy = t1;
        t1 = bZ; bZ = fz; fz = t1;
    }
    // T[k] = Y_style[8+k] * Z_content[k]: fp32 T + split M in one pass
    float* Tf = (float*)fy;
    ushort* Msp = fz;
    k_mm_ns64<3><<<8*32,256,0,stream>>>(bY + (size_t)8*2*MSZ, bZ, Msp, Tf, tvals, 8);

    k_buildV<<<dim3(8,2),256,0,stream>>>(Tf, tvals, cmean, smean, vvec);

    k_apply_mfma<<<(CAP/128)*4,256,0,stream>>>(Msp, XT, vvec, offC, Sg);
    k_scatter<<<(C_DIM*WH)/256,256,0,stream>>>(Sg, permCinv, out);
}

// Round 14
// 501.986 us; speedup vs baseline: 2.4364x; 1.0363x over previous
//
#include <hip/hip_runtime.h>
#include <math.h>

#define C_DIM 512
#define WH    16384
#define CAP   17408      // 16384 + 8*128 worst-case padding
#define NBX   136        // CAP/128
#define SEG_ALIGN 128
#define NCHUNK 64
#define CHUNK  256
#define NMAT 16
#define NSLICE 2
#define MSZ  (C_DIM*C_DIM)
#define ALPHA_C 0.8f
#define EPS_C   1e-6f
#define NIT 5            // total q-applications: 1 collapsed + 4 full (halved-t start)

typedef __attribute__((ext_vector_type(8))) __bf16 bfrag;
typedef __attribute__((ext_vector_type(4))) float f32x4;

__device__ inline float bf2f(ushort h){ return __uint_as_float(((unsigned)h)<<16); }
__device__ inline void split2(float v, ushort& h, ushort& l){
    unsigned u = __float_as_uint(v);
    h = (ushort)(u >> 16);
    float r = v - __uint_as_float(u & 0xffff0000u);
    l = (ushort)(__float_as_uint(r) >> 16);
}

__device__ __forceinline__ int xcd_swz(int bid, int nwg){
    int c = nwg >> 3;
    return (bid & 7)*c + (bid >> 3);
}

__device__ __forceinline__ void gload16(const void* g, void* l){
    __builtin_amdgcn_global_load_lds(
        (const __attribute__((address_space(1))) unsigned int*)g,
        (__attribute__((address_space(3))) unsigned int*)l, 16, 0, 0);
}

// stage one R x 64 bf16 panel (R = 64 or 128): LDS linear, source pre-swizzled
template<int R>
__device__ __forceinline__ void stage_panelR(const ushort* __restrict__ src,
        int stride, int i0, int k0, ushort* lds){
    int t = threadIdx.x;
    #pragma unroll
    for (int i = 0; i < R/32; ++i){
        int slot = t + i*256;
        int row = slot >> 3, c8 = slot & 7;
        const ushort* g = src + (size_t)(i0+row)*stride + k0 + ((c8 ^ (row&7))<<3);
        gload16((const void*)g, (void*)&lds[(size_t)(i*256 + (t & 192))*8]);
    }
}

// MFMA inner block: (2*MFR*16) x 128 tile, K=64 step, split-3 products
template<int MFR>
__device__ __forceinline__ void mfma_block(const ushort* As0, const ushort* As1,
        const ushort* Bs0, const ushort* Bs1, f32x4 (&acc)[MFR][4],
        int wm, int wn, int lr, int lk){
    #pragma unroll
    for (int kk = 0; kk < 64; kk += 32){
        bfrag ah[MFR], al[MFR], bh[4], bl[4];
        #pragma unroll
        for (int m = 0; m < MFR; ++m){
            int row = wm*(MFR*16) + m*16 + lr;
            int off = (row*64 + kk + lk*8) ^ ((row&7)<<3);
            ah[m] = *(const bfrag*)&As0[off];
            al[m] = *(const bfrag*)&As1[off];
        }
        #pragma unroll
        for (int n = 0; n < 4; ++n){
            int row = wn*64 + n*16 + lr;
            int off = (row*64 + kk + lk*8) ^ ((row&7)<<3);
            bh[n] = *(const bfrag*)&Bs0[off];
            bl[n] = *(const bfrag*)&Bs1[off];
        }
        #pragma unroll
        for (int m = 0; m < MFR; ++m)
            #pragma unroll
            for (int n = 0; n < 4; ++n){
                acc[m][n] = __builtin_amdgcn_mfma_f32_16x16x32_bf16(ah[m], bh[n], acc[m][n], 0,0,0);
                acc[m][n] = __builtin_amdgcn_mfma_f32_16x16x32_bf16(ah[m], bl[n], acc[m][n], 0,0,0);
                acc[m][n] = __builtin_amdgcn_mfma_f32_16x16x32_bf16(al[m], bh[n], acc[m][n], 0,0,0);
            }
    }
}

// unified K-loop: C((2*MFR*16)x128) += A * B^T on split planes
template<int MFR>
__device__ __forceinline__ void mm_coreT(const ushort* __restrict__ Am, size_t aPl, int aStr,
        const ushort* __restrict__ Bm, size_t bPl, int bStr,
        int i0, int j0, int kLo, int kHi,
        ushort (&As)[2][MFR*2048], ushort (&Bs)[2][8192], f32x4 (&acc)[MFR][4],
        int wm, int wn, int lr, int lk){
    for (int k0 = kLo; k0 < kHi; k0 += 64){
        stage_panelR<MFR*32>(Am,       aStr, i0, k0, As[0]);
        stage_panelR<MFR*32>(Am + aPl, aStr, i0, k0, As[1]);
        stage_panelR<128>(Bm,       bStr, j0, k0, Bs[0]);
        stage_panelR<128>(Bm + bPl, bStr, j0, k0, Bs[1]);
        __syncthreads();
        mfma_block<MFR>(As[0], As[1], Bs[0], Bs[1], acc, wm, wn, lr, lk);
        __syncthreads();
    }
}

// ---------- label bookkeeping (deterministic counting sort), content+style merged ----------

__global__ __launch_bounds__(256) void k_chunk_hist(const int* __restrict__ lab0,
        const int* __restrict__ lab1, int* __restrict__ ch0, int* __restrict__ ch1){
    __shared__ int h[8];
    int t = threadIdx.x;
    const int* labels = blockIdx.y ? lab1 : lab0;
    int* chunkCnt = blockIdx.y ? ch1 : ch0;
    if (t < 8) h[t] = 0;
    __syncthreads();
    int l = labels[blockIdx.x*CHUNK + t];
    atomicAdd(&h[l], 1);
    __syncthreads();
    if (t < 8) chunkCnt[blockIdx.x*8 + t] = h[t];
}

__global__ void k_scan(const int* __restrict__ ch0, const int* __restrict__ ch1,
                       int* __restrict__ cnt0, int* __restrict__ cnt1,
                       int* __restrict__ off0, int* __restrict__ off1,
                       int* __restrict__ base0, int* __restrict__ base1){
    int which = threadIdx.x;
    if (which >= 2) return;
    const int* chunkCnt = which ? ch1 : ch0;
    int* cnt = which ? cnt1 : cnt0;
    int* offPad = which ? off1 : off0;
    int* base = which ? base1 : base0;
    int c[8];
    for (int k=0;k<8;k++) c[k]=0;
    for (int ch=0; ch<NCHUNK; ch++)
        for (int k=0;k<8;k++) c[k] += chunkCnt[ch*8+k];
    int off = 0;
    for (int k=0;k<8;k++){
        cnt[k] = c[k];
        offPad[k] = off;
        off += ((c[k] + SEG_ALIGN - 1)/SEG_ALIGN)*SEG_ALIGN;
    }
    offPad[8] = off;
    for (int k=0;k<8;k++){
        int run = offPad[k];
        for (int ch=0; ch<NCHUNK; ch++){
            base[ch*8+k] = run;
            run += chunkCnt[ch*8+k];
        }
    }
}

__global__ void k_place(const int* __restrict__ lab0, const int* __restrict__ lab1,
        const int* __restrict__ base0, const int* __restrict__ base1,
        int* __restrict__ perm0, int* __restrict__ perm1, int* __restrict__ inv0){
    int t = threadIdx.x;
    if (t >= 8) return;
    const int* labels = blockIdx.y ? lab1 : lab0;
    const int* base = blockIdx.y ? base1 : base0;
    int* perm = blockIdx.y ? perm1 : perm0;
    int* inv = blockIdx.y ? nullptr : inv0;
    int ch = blockIdx.x;
    int pos = base[ch*8+t];
    int s = ch*CHUNK;
    for (int i=0;i<CHUNK;i++){
        if (labels[s+i] == t){
            perm[pos] = s+i;
            if (inv) inv[s+i] = pos;
            pos++;
        }
    }
}

// ---------- gather + split + fused per-cluster partial sums (content & style via z) ----------

__global__ __launch_bounds__(256) void k_gather2(const float* __restrict__ src0,
        const float* __restrict__ src1,
        const int* __restrict__ perm0, const int* __restrict__ perm1,
        const int* __restrict__ off0, const int* __restrict__ off1,
        const int* __restrict__ cnt0, const int* __restrict__ cnt1,
        ushort* __restrict__ dH0, ushort* __restrict__ dL0,
        ushort* __restrict__ dH1, ushort* __restrict__ dL1,
        float* __restrict__ ps0, float* __restrict__ ps1,
        int* __restrict__ sg0, int* __restrict__ sg1){
    int z = blockIdx.z;
    const float* src = z ? src1 : src0;
    const int* perm = z ? perm1 : perm0;
    const int* offPad = z ? off1 : off0;
    const int* cnt = z ? cnt1 : cnt0;
    ushort* dstH = z ? dH1 : dH0;
    ushort* dstL = z ? dL1 : dL0;
    float* psum = z ? ps1 : ps0;
    int* segOf = z ? sg1 : sg0;
    __shared__ int so[9], sc[8];
    __shared__ int pcache[128];
    int t = threadIdx.x;
    if (t < 9) so[t] = offPad[t];
    if (t < 8) sc[t] = cnt[t];
    __syncthreads();
    int bx = blockIdx.x;
    int i0 = bx*128;
    if (t < 128) pcache[t] = (i0 + t < so[8]) ? perm[i0 + t] : 0;
    __syncthreads();
    int k = 0;
    while (k < 7 && i0 >= so[k+1]) k++;
    int n = sc[k], s0 = so[k];
    int ch = t >> 4, px0 = (t & 15)*8;
    int c  = blockIdx.y*16 + ch;
    const float* row = src + (size_t)c*WH;
    float v[8];
    #pragma unroll
    for (int x=0;x<8;x++){
        int i = i0 + px0 + x;
        v[x] = (i - s0 < n) ? row[pcache[px0+x]] : 0.0f;
    }
    float s = 0.0f;
    ushort hv[8], lv[8];
    #pragma unroll
    for (int x=0;x<8;x++){
        s += v[x];
        split2(v[x], hv[x], lv[x]);
    }
    *(uint4*)&dstH[(size_t)c*CAP + i0 + px0] = *(uint4*)hv;
    *(uint4*)&dstL[(size_t)c*CAP + i0 + px0] = *(uint4*)lv;
    #pragma unroll
    for (int d=1; d<16; d<<=1) s += __shfl_xor(s, d, 16);
    if ((t & 15) == 0) psum[(size_t)c*NBX + bx] = s;
    if (t == 0) segOf[bx] = k;
}

// ---------- reduce partials -> per-cluster sums/means (z: 0=content mean, 1=style sum) ----------

__global__ __launch_bounds__(256) void k_meanred(const float* __restrict__ ps0,
        const float* __restrict__ ps1, const int* __restrict__ sg0,
        const int* __restrict__ sg1, const int* __restrict__ cnt0,
        float* __restrict__ out0, float* __restrict__ out1){
    int z = blockIdx.z;
    const float* psum = z ? ps1 : ps0;
    const int* segOf = z ? sg1 : sg0;
    float* out = z ? out1 : out0;
    int k = blockIdx.x;
    int c = blockIdx.y*256 + threadIdx.x;
    float s = 0.0f;
    for (int bx=0; bx<NBX; bx++)
        if (segOf[bx] == k) s += psum[(size_t)c*NBX + bx];
    out[k*C_DIM + c] = z ? s : s/(float)cnt0[k];
}

// ---------- transpose plane: [512][CAP] -> [CAP][512] ----------

__global__ __launch_bounds__(256) void k_transpose(const ushort* __restrict__ S,
                                                   ushort* __restrict__ D){
    __shared__ ushort tile[64][72];
    int p = blockIdx.z;
    const ushort* Sp = S + (size_t)p*C_DIM*CAP;
    ushort* Dp = D + (size_t)p*CAP*C_DIM;
    int cb = blockIdx.x*64;
    int rb = blockIdx.y*64;
    int t = threadIdx.x;
    int tr = t >> 3, tc = t & 7;
    #pragma unroll
    for (int i=0;i<2;i++){
        int r = tr + i*32;
        uint4 v = *(const uint4*)&Sp[(size_t)(rb+r)*CAP + cb + tc*8];
        ushort* u = (ushort*)&v;
        #pragma unroll
        for (int j=0;j<8;j++) tile[tc*8+j][r] = u[j];
    }
    __syncthreads();
    #pragma unroll
    for (int i=0;i<2;i++){
        int r = tr + i*32;
        uint4 v;
        ushort* u = (ushort*)&v;
        #pragma unroll
        for (int j=0;j<8;j++) u[j] = tile[r][tc*8+j];
        *(uint4*)&Dp[(size_t)(cb+r)*C_DIM + rb + tc*8] = v;
    }
}

__global__ __launch_bounds__(256) void k_style_mean(const float* __restrict__ scores,
        const int* __restrict__ cntS, const float* __restrict__ ssum,
        float* __restrict__ total, float* __restrict__ smean){
    int t = threadIdx.x;
    __shared__ float tot[8];
    if (t < 8){
        float s = 0.0f;
        for (int j=0;j<8;j++) s += scores[t*8+j]*(float)cntS[j];
        tot[t] = s; total[t] = s;
    }
    __syncthreads();
    for (int idx=t; idx<8*C_DIM; idx+=256){
        int k = idx / C_DIM, c = idx % C_DIM;
        float s = 0.0f;
        for (int j=0;j<8;j++) s += scores[k*8+j]*ssum[j*C_DIM+c];
        smean[idx] = s / tot[k];
    }
}

// ---------- MFMA SYRK: partial S2 = X X^T, triangular tiles, split-K=2 ----------

__global__ __launch_bounds__(256,2) void k_syrk_mfma(
        const ushort* __restrict__ Xc, const ushort* __restrict__ Xs,
        const int* __restrict__ offC, const int* __restrict__ offS,
        float* __restrict__ Pf){
    __shared__ ushort As[2][8192];
    __shared__ ushort Bs[2][8192];
    int wg = xcd_swz(blockIdx.x, NMAT*NSLICE*10);
    int mat = wg / (NSLICE*10);
    int rem = wg % (NSLICE*10);
    int slice = rem / 10, tt = rem % 10;
    int ti, tj;
    if (tt < 4){ ti=0; tj=tt; }
    else if (tt < 7){ ti=1; tj=tt-3; }
    else if (tt < 9){ ti=2; tj=tt-5; }
    else { ti=3; tj=3; }
    const ushort* X = (mat < 8) ? Xc : Xs;
    const int* offP = (mat < 8) ? offC : offS;
    int cl = mat & 7;
    int off = offP[cl], npad = offP[cl+1] - off;
    int i0 = ti*128, j0 = tj*128;
    int L = ((npad + NSLICE*64 - 1)/(NSLICE*64))*64;
    int k_lo = slice*L;
    int k_hi = min(k_lo + L, npad);
    int t = threadIdx.x;
    int lane = t & 63, wave = t >> 6;
    int wm = wave >> 1, wn = wave & 1;
    int lr = lane & 15, lk = lane >> 4;
    f32x4 zero = {0.f,0.f,0.f,0.f};
    f32x4 acc[4][4];
    #pragma unroll
    for (int m=0;m<4;m++)
        #pragma unroll
        for (int n=0;n<4;n++) acc[m][n] = zero;
    mm_coreT<4>(X + off, (size_t)C_DIM*CAP, CAP,
                X + off, (size_t)C_DIM*CAP, CAP,
                i0, j0, k_lo, k_hi, As, Bs, acc, wm, wn, lr, lk);
    float* O = Pf + ((size_t)(slice*16 + mat))*MSZ;
    #pragma unroll
    for (int m=0;m<4;m++)
        #pragma unroll
        for (int n=0;n<4;n++)
            #pragma unroll
            for (int j=0;j<4;j++){
                int gr = i0 + wm*64 + m*16 + lk*4 + j;
                int gc = j0 + wn*64 + n*16 + lr;
                O[(size_t)gr*C_DIM + gc] = acc[m][n][j];
            }
}

// ---------- assemble A (tile-based, coalesced, LDS mirror) -> split planes ----------

__global__ __launch_bounds__(256) void k_assemble(const float* __restrict__ P0,
        const float* __restrict__ scores, const float* __restrict__ total,
        const float* __restrict__ cmean, const float* __restrict__ smean,
        const int* __restrict__ cntC, ushort* __restrict__ bA){
    const size_t S = (size_t)NMAT*MSZ;
    __shared__ ushort tH[64][136];
    __shared__ ushort tL[64][136];
    int mat = blockIdx.y;
    int tt = blockIdx.x;
    int ti, tj;
    if (tt < 4){ ti=0; tj=tt; }
    else if (tt < 7){ ti=1; tj=tt-3; }
    else if (tt < 9){ ti=2; tj=tt-5; }
    else { ti=3; tj=3; }
    int i0 = ti*128, j0 = tj*128;
    int t = threadIdx.x;
    ushort* bm = bA + (size_t)mat*2*MSZ;
    int k = mat - 8;
    float nOrTot = (mat < 8) ? (float)cntC[mat] : total[k];
    float inv_nm1 = 1.0f/(nOrTot - 1.0f);
    const float* mrow = (mat < 8) ? (cmean + mat*C_DIM) : (smean + k*C_DIM);
    for (int h = 0; h < 2; ++h){
        #pragma unroll
        for (int rep = 0; rep < 4; ++rep){
            int lin = rep*2048 + t*8;
            int r = lin >> 7;
            int c = lin & 127;
            int gr = i0 + h*64 + r;
            int gc = j0 + c;
            size_t e = (size_t)gr*C_DIM + gc;
            float s2[8];
            if (mat < 8){
                size_t b = (size_t)mat*MSZ + e;
                #pragma unroll
                for (int x=0;x<8;x++)
                    s2[x] = P0[b+x] + P0[b+S+x];
            } else {
                #pragma unroll
                for (int x=0;x<8;x++) s2[x] = 0.0f;
                #pragma unroll
                for (int jj=0;jj<8;jj++){
                    float sc = scores[k*8+jj];
                    size_t b = (size_t)(8+jj)*MSZ + e;
                    #pragma unroll
                    for (int x=0;x<8;x++)
                        s2[x] += sc*(P0[b+x] + P0[b+S+x]);
                }
            }
            float mi = mrow[gr];
            #pragma unroll
            for (int x=0;x<8;x++){
                float v = (s2[x] - nOrTot*mi*mrow[gc+x])*inv_nm1;
                if (mat < 8 && gr == gc+x) v += EPS_C;
                ushort hh,ll; split2(v,hh,ll);
                bm[e+x] = hh; bm[MSZ+e+x] = ll;
                tH[r][c+x] = hh; tL[r][c+x] = ll;
            }
        }
        if (ti != tj){
            __syncthreads();
            #pragma unroll
            for (int rep = 0; rep < 4; ++rep){
                int lin = rep*2048 + t*8;
                int rr = lin >> 6;
                int cc0 = lin & 63;
                size_t eo = (size_t)(j0+rr)*C_DIM + i0 + h*64 + cc0;
                #pragma unroll
                for (int x=0;x<8;x++){
                    bm[eo+x]     = tH[cc0+x][rr];
                    bm[MSZ+eo+x] = tL[cc0+x][rr];
                }
            }
            __syncthreads();
        }
    }
}

// ---------- A^2 row abs-sums via MFMA (no C write), 64x128 tiles ----------

__global__ __launch_bounds__(256) void k_mm_rowsum(
        const ushort* __restrict__ A, float* __restrict__ rowpart){
    __shared__ ushort As[2][4096];
    __shared__ ushort Bs[2][8192];
    __shared__ float rs[64][2];
    int wg = xcd_swz(blockIdx.x, NMAT*32);
    int mat = wg >> 5, tile = wg & 31;
    int ti = tile >> 2, tj = tile & 3;
    int i0 = ti*64, j0 = tj*128;
    const ushort* Am = A + (size_t)mat*2*MSZ;
    int t = threadIdx.x;
    int lane = t & 63, wave = t >> 6;
    int wm = wave >> 1, wn = wave & 1;
    int lr = lane & 15, lk = lane >> 4;
    f32x4 zero = {0.f,0.f,0.f,0.f};
    f32x4 acc[2][4];
    #pragma unroll
    for (int m=0;m<2;m++)
        #pragma unroll
        for (int n=0;n<4;n++) acc[m][n] = zero;
    mm_coreT<2>(Am, MSZ, C_DIM, Am, MSZ, C_DIM, i0, j0, 0, C_DIM,
                As, Bs, acc, wm, wn, lr, lk);
    #pragma unroll
    for (int m=0;m<2;m++)
        #pragma unroll
        for (int j=0;j<4;j++){
            float s = 0.0f;
            #pragma unroll
            for (int n=0;n<4;n++) s += fabsf(acc[m][n][j]);
            #pragma unroll
            for (int d=1; d<16; d<<=1) s += __shfl_xor(s, d);
            if (lr == 0) rs[wm*32 + m*16 + lk*4 + j][wn] = s;
        }
    __syncthreads();
    if (t < 64)
        rowpart[((size_t)mat*4 + tj)*512 + i0 + t] = rs[t][0] + rs[t][1];
}

// ---------- t = 0.5*sqrt(max row sum of |A^2|); NS converges for p in (0,3) ----------

__global__ __launch_bounds__(256) void k_tmax(const float* __restrict__ rowpart,
                                              float* __restrict__ tvals){
    int mat = blockIdx.x, t = threadIdx.x;
    const float* rp = rowpart + (size_t)mat*4*512;
    float mx = 0.0f;
    for (int r = t; r < 512; r += 256){
        float s = rp[r] + rp[512+r] + rp[1024+r] + rp[1536+r];
        mx = fmaxf(mx, s);
    }
    __shared__ float red[256];
    red[t] = mx; __syncthreads();
    for (int s=128; s>0; s>>=1){ if (t<s) red[t]=fmaxf(red[t],red[t+s]); __syncthreads(); }
    if (t == 0) tvals[mat] = 0.5f*sqrtf(red[0]);
}

// ---------- P0 = q(A/t) = 1.5I - 0.5*A/t (Y0 never materialized) ----------

__global__ __launch_bounds__(256) void k_initP0(const ushort* __restrict__ bA,
        const float* __restrict__ tvals, ushort* __restrict__ P){
    int mat = blockIdx.y;
    int e = blockIdx.x*256 + threadIdx.x;
    size_t base = (size_t)mat*2*MSZ;
    float inv = 1.0f / tvals[mat];
    float a = (bf2f(bA[base+e]) + bf2f(bA[base+MSZ+e])) * inv;
    int i = e >> 9, j = e & 511;
    float p = ((i==j)?1.5f:0.0f) - 0.5f*a;
    ushort h,l; split2(p,h,l);
    P[base + e] = h;
    P[base + MSZ + e] = l;
}

// ---------- generic 64x128-tile batched mm on split planes ----------
// EPI 0: split write; EPI 1: q(X) then split write; EPI 3: fp32 T + split M(ascale,diag);
// EPI 4: split write of acc/tvals[mat]  (Y1 = (A*P0)/t)

template<int EPI>
__global__ __launch_bounds__(256) void k_mm_ns64(
        const ushort* __restrict__ A, const ushort* __restrict__ B,
        ushort* __restrict__ Co, float* __restrict__ Cf,
        const float* __restrict__ tvals, int nmat){
    __shared__ ushort As[2][4096];
    __shared__ ushort Bs[2][8192];
    int wg = xcd_swz(blockIdx.x, nmat*32);
    int mat = wg >> 5, tile = wg & 31;
    int i0 = (tile>>2)*64, j0 = (tile&3)*128;
    const ushort* Am = A + (size_t)mat*2*MSZ;
    const ushort* Bm = B + (size_t)mat*2*MSZ;
    int t = threadIdx.x;
    int lane = t & 63, wave = t >> 6;
    int wm = wave >> 1, wn = wave & 1;
    int lr = lane & 15, lk = lane >> 4;
    f32x4 zero = {0.f,0.f,0.f,0.f};
    f32x4 acc[2][4];
    #pragma unroll
    for (int m=0;m<2;m++)
        #pragma unroll
        for (int n=0;n<4;n++) acc[m][n] = zero;
    mm_coreT<2>(Am, MSZ, C_DIM, Bm, MSZ, C_DIM, i0, j0, 0, C_DIM,
                As, Bs, acc, wm, wn, lr, lk);
    if (EPI == 3){
        float* Cm = Cf + (size_t)mat*MSZ;
        ushort* Mh = Co + (size_t)mat*2*MSZ;
        ushort* Ml = Mh + MSZ;
        float ascale = ALPHA_C * sqrtf(tvals[8+mat]/tvals[mat]);
        #pragma unroll
        for (int m=0;m<2;m++)
            #pragma unroll
            for (int n=0;n<4;n++)
                #pragma unroll
                for (int j=0;j<4;j++){
                    int gr = i0 + wm*32 + m*16 + lk*4 + j;
                    int gc = j0 + wn*64 + n*16 + lr;
                    float v = acc[m][n][j];
                    size_t idx = (size_t)gr*C_DIM + gc;
                    Cm[idx] = v;
                    float mv = ascale*v + ((gr==gc)?(1.0f-ALPHA_C):0.0f);
                    ushort h,l; split2(mv,h,l);
                    Mh[idx] = h; Ml[idx] = l;
                }
    } else {
        float sc = (EPI == 4) ? 1.0f/tvals[mat] : 1.0f;
        ushort* Ch = Co + (size_t)mat*2*MSZ;
        ushort* Cl = Ch + MSZ;
        #pragma unroll
        for (int m=0;m<2;m++)
            #pragma unroll
            for (int n=0;n<4;n++)
                #pragma unroll
                for (int j=0;j<4;j++){
                    int gr = i0 + wm*32 + m*16 + lk*4 + j;
                    int gc = j0 + wn*64 + n*16 + lr;
                    float v = acc[m][n][j];
                    if (EPI == 1) v = ((gr==gc)?1.5f:0.0f) - 0.5f*v;
                    if (EPI == 4) v *= sc;
                    ushort h,l; split2(v,h,l);
                    size_t idx = (size_t)gr*C_DIM + gc;
                    Ch[idx] = h;
                    Cl[idx] = l;
                }
    }
}

// ---------- merged NS stage 2 (128x128 tiles, full chip): fy = Y*qP, fz = qP*Z ----------

__global__ __launch_bounds__(256,2) void k_mm_ns2(
        const ushort* __restrict__ Y, const ushort* __restrict__ P,
        const ushort* __restrict__ Z, ushort* __restrict__ fy,
        ushort* __restrict__ fz){
    __shared__ ushort As[2][8192];
    __shared__ ushort Bs[2][8192];
    int wg = xcd_swz(blockIdx.x, NMAT*32);
    int mat = wg >> 5;
    int r = wg & 31;
    int op = r >> 4, tile = r & 15;
    int i0 = (tile>>2)*128, j0 = (tile&3)*128;
    const ushort* Am = (op ? P : Y) + (size_t)mat*2*MSZ;
    const ushort* Bm = (op ? Z : P) + (size_t)mat*2*MSZ;
    ushort* Ch = (op ? fz : fy) + (size_t)mat*2*MSZ;
    ushort* Cl = Ch + MSZ;
    int t = threadIdx.x;
    int lane = t & 63, wave = t >> 6;
    int wm = wave >> 1, wn = wave & 1;
    int lr = lane & 15, lk = lane >> 4;
    f32x4 zero = {0.f,0.f,0.f,0.f};
    f32x4 acc[4][4];
    #pragma unroll
    for (int m=0;m<4;m++)
        #pragma unroll
        for (int n=0;n<4;n++) acc[m][n] = zero;
    mm_coreT<4>(Am, MSZ, C_DIM, Bm, MSZ, C_DIM, i0, j0, 0, C_DIM,
                As, Bs, acc, wm, wn, lr, lk);
    #pragma unroll
    for (int m=0;m<4;m++)
        #pragma unroll
        for (int n=0;n<4;n++)
            #pragma unroll
            for (int j=0;j<4;j++){
                int gr = i0 + wm*64 + m*16 + lk*4 + j;
                int gc = j0 + wn*64 + n*16 + lr;
                ushort h,l; split2(acc[m][n][j],h,l);
                size_t idx = (size_t)gr*C_DIM + gc;
                Ch[idx] = h;
                Cl[idx] = l;
            }
}

// ---------- last NS stage 2 (64x128 tiles): only consumed halves ----------

__global__ __launch_bounds__(256) void k_mm_ns2_last(
        const ushort* __restrict__ Y, const ushort* __restrict__ P,
        const ushort* __restrict__ Z, ushort* __restrict__ fy,
        ushort* __restrict__ fz){
    __shared__ ushort As[2][4096];
    __shared__ ushort Bs[2][8192];
    int wg = xcd_swz(blockIdx.x, NMAT*32);
    int mat = wg >> 5, tile = wg & 31;
    int op = (mat < 8) ? 1 : 0;         // content: fz = P*Z ; style: fy = Y*P
    int i0 = (tile>>2)*64, j0 = (tile&3)*128;
    const ushort* Am = (op ? P : Y) + (size_t)mat*2*MSZ;
    const ushort* Bm = (op ? Z : P) + (size_t)mat*2*MSZ;
    ushort* Ch = (op ? fz : fy) + (size_t)mat*2*MSZ;
    ushort* Cl = Ch + MSZ;
    int t = threadIdx.x;
    int lane = t & 63, wave = t >> 6;
    int wm = wave >> 1, wn = wave & 1;
    int lr = lane & 15, lk = lane >> 4;
    f32x4 zero = {0.f,0.f,0.f,0.f};
    f32x4 acc[2][4];
    #pragma unroll
    for (int m=0;m<2;m++)
        #pragma unroll
        for (int n=0;n<4;n++) acc[m][n] = zero;
    mm_coreT<2>(Am, MSZ, C_DIM, Bm, MSZ, C_DIM, i0, j0, 0, C_DIM,
                As, Bs, acc, wm, wn, lr, lk);
    #pragma unroll
    for (int m=0;m<2;m++)
        #pragma unroll
        for (int n=0;n<4;n++)
            #pragma unroll
            for (int j=0;j<4;j++){
                int gr = i0 + wm*32 + m*16 + lk*4 + j;
                int gc = j0 + wn*64 + n*16 + lr;
                ushort h,l; split2(acc[m][n][j],h,l);
                size_t idx = (size_t)gr*C_DIM + gc;
                Ch[idx] = h;
                Cl[idx] = l;
            }
}

// ---------- bias vector: vvec = alpha*smean - ascale*(T cmean) ----------

__global__ __launch_bounds__(256) void k_buildV(const float* __restrict__ T,
        const float* __restrict__ tvals, const float* __restrict__ cmean,
        const float* __restrict__ smean, float* __restrict__ vvec){
    __shared__ float cm[512];
    int k = blockIdx.x, t = threadIdx.x;
    cm[t] = cmean[k*C_DIM + t];
    cm[t+256] = cmean[k*C_DIM + t + 256];
    __syncthreads();
    float scale = ALPHA_C * sqrtf(tvals[8+k]/tvals[k]);
    int c = blockIdx.y*256 + t;
    const float* row = T + (size_t)k*MSZ + (size_t)c*C_DIM;
    float s = 0.0f;
    for (int d=0; d<C_DIM; d++) s = fmaf(row[d], cm[d], s);
    vvec[k*C_DIM + c] = ALPHA_C*smean[k*C_DIM + c] - scale*s;
}

// ---------- MFMA apply: Sg = M*Xc + v in gathered order (coalesced) ----------

__global__ __launch_bounds__(256,2) void k_apply_mfma(
        const ushort* __restrict__ Msp, const ushort* __restrict__ XT,
        const float* __restrict__ vvec, const int* __restrict__ offPad,
        float* __restrict__ Sg){
    __shared__ ushort As[2][8192];
    __shared__ ushort Bs[2][8192];
    __shared__ int so[9];
    int t = threadIdx.x;
    if (t < 9) so[t] = offPad[t];
    __syncthreads();
    int wg = xcd_swz(blockIdx.x, (CAP/128)*4);
    int j0 = (wg>>2)*128;
    int i0 = (wg&3)*128;
    if (j0 >= so[8]) return;
    int cl = 0;
    while (cl < 7 && j0 >= so[cl+1]) cl++;
    const ushort* Am = Msp + (size_t)cl*2*MSZ;
    int lane = t & 63, wave = t >> 6;
    int wm = wave >> 1, wn = wave & 1;
    int lr = lane & 15, lk = lane >> 4;
    f32x4 zero = {0.f,0.f,0.f,0.f};
    f32x4 acc[4][4];
    #pragma unroll
    for (int m=0;m<4;m++)
        #pragma unroll
        for (int n=0;n<4;n++) acc[m][n] = zero;
    mm_coreT<4>(Am, MSZ, C_DIM, XT, (size_t)CAP*C_DIM, C_DIM, i0, j0, 0, C_DIM,
                As, Bs, acc, wm, wn, lr, lk);
    #pragma unroll
    for (int m=0;m<4;m++)
        #pragma unroll
        for (int nn=0;nn<4;nn++)
            #pragma unroll
            for (int j=0;j<4;j++){
                int gr = i0 + wm*64 + m*16 + lk*4 + j;
                int gc = j0 + wn*64 + nn*16 + lr;
                Sg[(size_t)gr*CAP + gc] = acc[m][nn][j] + vvec[cl*C_DIM + gr];
            }
}

// ---------- scatter: out[c][p] = Sg[c][ginv[p]] (coalesced writes) ----------

__global__ __launch_bounds__(256) void k_scatter(const float* __restrict__ Sg,
        const int* __restrict__ ginv, float* __restrict__ out){
    size_t idx = (size_t)blockIdx.x*256 + threadIdx.x;
    int p = (int)(idx & (WH-1));
    int c = (int)(idx >> 14);
    out[idx] = Sg[(size_t)c*CAP + ginv[p]];
}

// ---------- host ----------

extern "C" void kernel_launch(void* const* d_in, const int* in_sizes, int n_in,
                              void* d_out, int out_size, void* d_ws, size_t ws_size,
                              hipStream_t stream) {
    (void)in_sizes; (void)n_in;
    const float* cf     = (const float*)d_in[0];
    const float* sf     = (const float*)d_in[1];
    const float* scores = (const float*)d_in[2];
    const int*   cl     = (const int*)d_in[3];
    const int*   sl     = (const int*)d_in[4];
    float* out = (float*)d_out;
    float* ws  = (float*)d_ws;

    size_t o = 0;
    ushort* XcH = (ushort*)(ws + o);
    float*  Sg  = ws + o;       o += (size_t)C_DIM*CAP;
    ushort* XcL = XcH + (size_t)C_DIM*CAP;
    ushort* XsH = (ushort*)(ws + o); o += (size_t)C_DIM*CAP;
    float* S4  = ws + o; o += (size_t)NMAT*MSZ;
    float* NS0 = ws + o; o += (size_t)4*NMAT*MSZ;
    float* cmean = ws + o; o += 8*C_DIM;
    float* ssum  = ws + o; o += 8*C_DIM;
    float* smean = ws + o; o += 8*C_DIM;
    float* vvec  = ws + o; o += 8*C_DIM;
    float* tvals = ws + o; o += 16;
    float* rowpart = ws + o; o += (size_t)NMAT*4*512;
    float* total = ws + o; o += 8;
    float* psumC = ws + o; o += (size_t)C_DIM*NBX;
    float* psumS = ws + o; o += (size_t)C_DIM*NBX;
    int* ip = (int*)(ws + o);
    int* permC    = ip; ip += CAP;
    int* permCinv = ip; ip += CAP;
    int* permS    = ip; ip += CAP;
    int* segOfC = ip; ip += NBX;
    int* segOfS = ip; ip += NBX;
    int* cntC  = ip; ip += 8;
    int* cntS  = ip; ip += 8;
    int* offC  = ip; ip += 9;
    int* offS  = ip; ip += 9;
    int* chC   = ip; ip += NCHUNK*8;
    int* chS   = ip; ip += NCHUNK*8;
    int* baseC = ip; ip += NCHUNK*8;
    int* baseS = ip; ip += NCHUNK*8;
    size_t need_bytes = (size_t)((char*)ip - (char*)d_ws);
    if (ws_size < need_bytes){
        hipMemcpyAsync(d_out, (const void*)cf, (size_t)out_size*sizeof(float),
                       hipMemcpyDeviceToDevice, stream);
        return;
    }
    float* Pf = NS0;
    ushort* s0 = (ushort*)(NS0 + 0*(size_t)NMAT*MSZ);
    ushort* s1 = (ushort*)(NS0 + 1*(size_t)NMAT*MSZ);
    ushort* s2 = (ushort*)(NS0 + 2*(size_t)NMAT*MSZ);
    ushort* s3 = (ushort*)(NS0 + 3*(size_t)NMAT*MSZ);
    ushort* s4 = (ushort*)S4;

    k_chunk_hist<<<dim3(NCHUNK,2),256,0,stream>>>(cl, sl, chC, chS);
    k_scan<<<1,64,0,stream>>>(chC, chS, cntC, cntS, offC, offS, baseC, baseS);
    k_place<<<dim3(NCHUNK,2),64,0,stream>>>(cl, sl, baseC, baseS, permC, permS, permCinv);

    // gather + split + fused cluster partial sums (content z=0, style z=1)
    dim3 gg(NBX, C_DIM/16, 2);
    k_gather2<<<gg,256,0,stream>>>(cf, sf, permC, permS, offC, offS, cntC, cntS,
                                   XcH, XcL, XsH, XsH + (size_t)C_DIM*CAP,
                                   psumC, psumS, segOfC, segOfS);

    k_meanred<<<dim3(8,2,2),256,0,stream>>>(psumC, psumS, segOfC, segOfS, cntC,
                                            cmean, ssum);
    k_style_mean<<<1,256,0,stream>>>(scores, cntS, ssum, total, smean);

    k_syrk_mfma<<<NMAT*NSLICE*10,256,0,stream>>>(XcH, XsH, offC, offS, Pf);

    k_transpose<<<dim3(CAP/64, C_DIM/64, 2),256,0,stream>>>(XcH, XsH);
    ushort* XT = XsH;

    ushort* bA = s4;
    k_assemble<<<dim3(10,16),256,0,stream>>>(Pf, scores, total, cmean, smean, cntC, bA);

    k_mm_rowsum<<<NMAT*32,256,0,stream>>>(bA, rowpart);
    k_tmax<<<NMAT,256,0,stream>>>(rowpart, tvals);

    // iteration 0 (collapsed): P0 = q(A/t) elementwise; Y1 = (A*P0)/t; Z1 = P0 (alias)
    k_initP0<<<dim3(MSZ/256,NMAT),256,0,stream>>>(bA, tvals, s1);
    k_mm_ns64<4><<<NMAT*32,256,0,stream>>>(bA, s1, s2, nullptr, tvals, NMAT);

    ushort* bY = s2;  ushort* bZ = s1;  ushort* bP = s3;
    ushort* fy = s4;  ushort* fz = s0;   // s4 = bA slot (dead after ns64<4>), s0 unused
    for (int it=0; it<NIT-1; ++it){
        k_mm_ns64<1><<<NMAT*32,256,0,stream>>>(bZ, bY, bP, nullptr, nullptr, NMAT); // P=q(Z*Y)
        if (it < NIT-2)
            k_mm_ns2<<<NMAT*32,256,0,stream>>>(bY, bP, bZ, fy, fz);
        else
            k_mm_ns2_last<<<NMAT*32,256,0,stream>>>(bY, bP, bZ, fy, fz);
        ushort* t1;
        t1 = bY; bY = fy; fy = t1;
        t1 = bZ; bZ = fz; fz = t1;
    }
    // T[k] = Y_style[8+k] * Z_content[k]: fp32 T + split M in one pass
    float* Tf = (float*)fy;
    ushort* Msp = fz;
    k_mm_ns64<3><<<8*32,256,0,stream>>>(bY + (size_t)8*2*MSZ, bZ, Msp, Tf, tvals, 8);

    k_buildV<<<dim3(8,2),256,0,stream>>>(Tf, tvals, cmean, smean, vvec);

    k_apply_mfma<<<(CAP/128)*4,256,0,stream>>>(Msp, XT, vvec, offC, Sg);
    k_scatter<<<(C_DIM*WH)/256,256,0,stream>>>(Sg, permCinv, out);
}